// Round 1
// baseline (429.818 us; speedup 1.0000x reference)
//
#include <hip/hip_runtime.h>
#include <hip/hip_bf16.h>
#include <math.h>

// Problem constants (b=2, n=2048, dim=512, h=8, dh=64, f=256, chunk=128)
#define NB    2
#define NSEQ  2048
#define DIMM  512
#define NH    8
#define DHd   64
#define FF    256
#define CHK   128
#define NCHK  16
#define NBH   16   // NB*NH

// ---------- float <-> orderable-uint for atomicMax on floats ----------
__device__ __forceinline__ unsigned enc_f(float x) {
    unsigned u = __float_as_uint(x);
    return (u & 0x80000000u) ? ~u : (u | 0x80000000u);
}
__device__ __forceinline__ float dec_f(unsigned e) {
    unsigned u = (e & 0x80000000u) ? (e & 0x7fffffffu) : ~e;
    return __uint_as_float(u);
}

__global__ void init_minmax(unsigned* mk_u) {
    if (threadIdx.x < NBH) mk_u[threadIdx.x] = 0u;  // encodes below any finite float
}

// ---------- Generic 4096x512x512 fp32 GEMM, 128x128 tile, 8x8/thread ----------
// z picks (W, O) among three — used for fused QKV; bias optional (final proj).
__global__ __launch_bounds__(256)
void gemm_4096_512_512(const float* __restrict__ A,
                       const float* __restrict__ W0, const float* __restrict__ W1,
                       const float* __restrict__ W2,
                       float* __restrict__ O0, float* __restrict__ O1, float* __restrict__ O2,
                       const float* __restrict__ bias)
{
    __shared__ alignas(16) float As[16][132];
    __shared__ alignas(16) float Bs[16][132];
    const int tid = threadIdx.x;
    const int tx = tid & 15, ty = tid >> 4;
    const int n0 = blockIdx.x * 128;
    const int m0 = blockIdx.y * 128;
    const float* W = (blockIdx.z == 0) ? W0 : ((blockIdx.z == 1) ? W1 : W2);
    float* Cm = (blockIdx.z == 0) ? O0 : ((blockIdx.z == 1) ? O1 : O2);

    float acc[8][8];
#pragma unroll
    for (int i = 0; i < 8; i++)
#pragma unroll
        for (int j = 0; j < 8; j++) acc[i][j] = 0.f;

    for (int k0 = 0; k0 < 512; k0 += 16) {
        // A tile 128x16 -> As[k][m] (transposed on store)
#pragma unroll
        for (int p = 0; p < 2; p++) {
            const int idx = tid + p * 256;
            const int r = idx >> 2, c4 = idx & 3;
            const float4 v = *(const float4*)(A + (size_t)(m0 + r) * 512 + k0 + c4 * 4);
            As[c4 * 4 + 0][r] = v.x; As[c4 * 4 + 1][r] = v.y;
            As[c4 * 4 + 2][r] = v.z; As[c4 * 4 + 3][r] = v.w;
        }
        // B tile 16x128 direct
#pragma unroll
        for (int p = 0; p < 2; p++) {
            const int idx = tid + p * 256;
            const int kr = idx >> 5, cc = idx & 31;
            *(float4*)&Bs[kr][cc * 4] = *(const float4*)(W + (size_t)(k0 + kr) * 512 + n0 + cc * 4);
        }
        __syncthreads();
#pragma unroll
        for (int kk = 0; kk < 16; kk++) {
            const float4 a0 = *(const float4*)&As[kk][ty * 8];
            const float4 a1 = *(const float4*)&As[kk][ty * 8 + 4];
            const float4 b0 = *(const float4*)&Bs[kk][tx * 4];        // cols tx*4..+3
            const float4 b1 = *(const float4*)&Bs[kk][tx * 4 + 64];   // cols 64+tx*4..+3
            const float av[8] = {a0.x, a0.y, a0.z, a0.w, a1.x, a1.y, a1.z, a1.w};
            const float bv[8] = {b0.x, b0.y, b0.z, b0.w, b1.x, b1.y, b1.z, b1.w};
#pragma unroll
            for (int i = 0; i < 8; i++)
#pragma unroll
                for (int j = 0; j < 8; j++)
                    acc[i][j] = fmaf(av[i], bv[j], acc[i][j]);
        }
        __syncthreads();
    }
    float4 bias0 = make_float4(0.f, 0.f, 0.f, 0.f);
    float4 bias1 = make_float4(0.f, 0.f, 0.f, 0.f);
    if (bias) {
        bias0 = *(const float4*)(bias + n0 + tx * 4);
        bias1 = *(const float4*)(bias + n0 + tx * 4 + 64);
    }
#pragma unroll
    for (int i = 0; i < 8; i++) {
        float4 o0, o1;
        o0.x = acc[i][0] + bias0.x; o0.y = acc[i][1] + bias0.y;
        o0.z = acc[i][2] + bias0.z; o0.w = acc[i][3] + bias0.w;
        o1.x = acc[i][4] + bias1.x; o1.y = acc[i][5] + bias1.y;
        o1.z = acc[i][6] + bias1.z; o1.w = acc[i][7] + bias1.w;
        *(float4*)(Cm + (size_t)(m0 + ty * 8 + i) * 512 + n0 + tx * 4) = o0;
        *(float4*)(Cm + (size_t)(m0 + ty * 8 + i) * 512 + n0 + tx * 4 + 64) = o1;
    }
}

// ---------- FAVOR feature GEMM: dd[b,h,n,f] = normalizer * (q_slice . proj[f,:]) ----------
// Also reduces per-(b,h) max of dd_k via atomicMax for the key branch.
__global__ __launch_bounds__(256)
void feat_gemm(const float* __restrict__ qmat, const float* __restrict__ kmat,
               const float* __restrict__ proj, float* __restrict__ ddq,
               float* __restrict__ ddk, unsigned* __restrict__ mk_u)
{
    __shared__ alignas(16) float As[16][132];
    __shared__ alignas(16) float Bst[16][68];
    __shared__ float red[256];
    const int tid = threadIdx.x;
    const int tx = tid & 15, ty = tid >> 4;
    const int f0 = blockIdx.x * 64;
    const int m0 = blockIdx.y * 128;
    const int src = blockIdx.z >> 3, h = blockIdx.z & 7;
    const float* Am = src ? kmat : qmat;
    float* dd = src ? ddk : ddq;

    float acc[8][4];
#pragma unroll
    for (int i = 0; i < 8; i++)
#pragma unroll
        for (int j = 0; j < 4; j++) acc[i][j] = 0.f;

    for (int k0 = 0; k0 < 64; k0 += 16) {
#pragma unroll
        for (int p = 0; p < 2; p++) {
            const int idx = tid + p * 256;
            const int r = idx >> 2, c4 = idx & 3;
            const float4 v = *(const float4*)(Am + (size_t)(m0 + r) * DIMM + h * 64 + k0 + c4 * 4);
            As[c4 * 4 + 0][r] = v.x; As[c4 * 4 + 1][r] = v.y;
            As[c4 * 4 + 2][r] = v.z; As[c4 * 4 + 3][r] = v.w;
        }
        {
            const int f = tid >> 2, c4 = tid & 3;
            const float4 v = *(const float4*)(proj + (size_t)(f0 + f) * 64 + k0 + c4 * 4);
            Bst[c4 * 4 + 0][f] = v.x; Bst[c4 * 4 + 1][f] = v.y;
            Bst[c4 * 4 + 2][f] = v.z; Bst[c4 * 4 + 3][f] = v.w;
        }
        __syncthreads();
#pragma unroll
        for (int kk = 0; kk < 16; kk++) {
            const float4 a0 = *(const float4*)&As[kk][ty * 8];
            const float4 a1 = *(const float4*)&As[kk][ty * 8 + 4];
            const float4 b0 = *(const float4*)&Bst[kk][tx * 4];
            const float av[8] = {a0.x, a0.y, a0.z, a0.w, a1.x, a1.y, a1.z, a1.w};
            const float bv[4] = {b0.x, b0.y, b0.z, b0.w};
#pragma unroll
            for (int i = 0; i < 8; i++)
#pragma unroll
                for (int j = 0; j < 4; j++)
                    acc[i][j] = fmaf(av[i], bv[j], acc[i][j]);
        }
        __syncthreads();
    }
    const float dn = 0.35355339059327379f;  // 64^-0.25
    float mloc = -3.0e38f;
    const int bb = m0 >> 11;       // 128-row tiles never straddle the batch boundary
    const int nbase = m0 & 2047;
    const size_t base = ((size_t)((bb * NH + h) * NSEQ + nbase)) * FF;
#pragma unroll
    for (int i = 0; i < 8; i++) {
        float4 o;
        o.x = acc[i][0] * dn; o.y = acc[i][1] * dn;
        o.z = acc[i][2] * dn; o.w = acc[i][3] * dn;
        mloc = fmaxf(mloc, fmaxf(fmaxf(o.x, o.y), fmaxf(o.z, o.w)));
        *(float4*)(dd + base + (size_t)(ty * 8 + i) * FF + f0 + tx * 4) = o;
    }
    if (src) {
        red[tid] = mloc;
        __syncthreads();
        for (int s = 128; s > 0; s >>= 1) {
            if (tid < s) red[tid] = fmaxf(red[tid], red[tid + s]);
            __syncthreads();
        }
        if (tid == 0) atomicMax(&mk_u[bb * NH + h], enc_f(red[0]));
    }
}

// ---------- exp/normalize: ff = ratio*(exp(dd - diag - m) + KERNEL_EPS), in place ----------
__global__ __launch_bounds__(256)
void exp_norm(float* __restrict__ ddq, float* __restrict__ ddk,
              const float* __restrict__ qmat, const float* __restrict__ kmat,
              const unsigned* __restrict__ mk_u)
{
    const int tid = threadIdx.x;
    const int lane = tid & 63;
    const int row = blockIdx.x * 4 + (tid >> 6);   // row = bh*2048 + n
    const int src = blockIdx.y;
    float* dd = src ? ddk : ddq;
    const float* qk = src ? kmat : qmat;
    const int bh = row >> 11;
    const int n = row & 2047;
    const int bb = bh >> 3, h = bh & 7;
    // diag = sum(q^2)/16  (= 0.5 * 64^-0.5 * sum)
    const float qv = qk[(size_t)(bb * NSEQ + n) * DIMM + h * 64 + lane];
    float ss = qv * qv;
#pragma unroll
    for (int off = 32; off > 0; off >>= 1) ss += __shfl_xor(ss, off);
    const float diag = ss * 0.0625f;

    float4 d4 = *(float4*)(dd + (size_t)row * FF + lane * 4);
    float m;
    if (src == 0) {
        float ml = fmaxf(fmaxf(d4.x, d4.y), fmaxf(d4.z, d4.w));
#pragma unroll
        for (int off = 32; off > 0; off >>= 1) ml = fmaxf(ml, __shfl_xor(ml, off));
        m = ml;                     // per-row max for queries
    } else {
        m = dec_f(mk_u[bh]);        // per-(b,h) global max for keys
    }
    const float cc = diag + m;
    float4 o;
    o.x = 0.0625f * (__expf(d4.x - cc) + 1.0e-4f);
    o.y = 0.0625f * (__expf(d4.y - cc) + 1.0e-4f);
    o.z = 0.0625f * (__expf(d4.z - cc) + 1.0e-4f);
    o.w = 0.0625f * (__expf(d4.w - cc) + 1.0e-4f);
    *(float4*)(dd + (size_t)row * FF + lane * 4) = o;
}

// ---------- per-chunk sums: Ksum[bh][c][f] = sum_i kf; CTX[bh][c][f][e] = kf^T @ v ----------
__global__ __launch_bounds__(256)
void chunk_sums(const float* __restrict__ kf, const float* __restrict__ vmat,
                float* __restrict__ Ksum, float* __restrict__ CTX)
{
    __shared__ alignas(16) float kfs[8][260];
    __shared__ alignas(16) float vs[8][68];
    const int tid = threadIdx.x;
    const int tx = tid & 15, ty = tid >> 4;
    const int bh = blockIdx.x >> 4, c = blockIdx.x & 15;
    const int bb = bh >> 3, h = bh & 7;
    const int n0 = c * CHK;
    float acc[16][4];
    float ks[16];
#pragma unroll
    for (int fi = 0; fi < 16; fi++) {
        ks[fi] = 0.f;
#pragma unroll
        for (int j = 0; j < 4; j++) acc[fi][j] = 0.f;
    }
    for (int i0 = 0; i0 < CHK; i0 += 8) {
#pragma unroll
        for (int p = 0; p < 2; p++) {
            const int idx = tid + p * 256;
            const int r = idx >> 6, c4 = idx & 63;
            *(float4*)&kfs[r][c4 * 4] =
                *(const float4*)(kf + ((size_t)(bh * NSEQ + n0 + i0 + r)) * FF + c4 * 4);
        }
        if (tid < 128) {
            const int r = tid >> 4, c4 = tid & 15;
            *(float4*)&vs[r][c4 * 4] =
                *(const float4*)(vmat + ((size_t)(bb * NSEQ + n0 + i0 + r)) * DIMM + h * 64 + c4 * 4);
        }
        __syncthreads();
#pragma unroll
        for (int kk = 0; kk < 8; kk++) {
            float a[16];
            *(float4*)&a[0]  = *(const float4*)&kfs[kk][ty * 16];
            *(float4*)&a[4]  = *(const float4*)&kfs[kk][ty * 16 + 4];
            *(float4*)&a[8]  = *(const float4*)&kfs[kk][ty * 16 + 8];
            *(float4*)&a[12] = *(const float4*)&kfs[kk][ty * 16 + 12];
            const float4 bv = *(const float4*)&vs[kk][tx * 4];
#pragma unroll
            for (int fi = 0; fi < 16; fi++) {
                acc[fi][0] = fmaf(a[fi], bv.x, acc[fi][0]);
                acc[fi][1] = fmaf(a[fi], bv.y, acc[fi][1]);
                acc[fi][2] = fmaf(a[fi], bv.z, acc[fi][2]);
                acc[fi][3] = fmaf(a[fi], bv.w, acc[fi][3]);
            }
            if (tx == 0) {
#pragma unroll
                for (int fi = 0; fi < 16; fi++) ks[fi] += a[fi];
            }
        }
        __syncthreads();
    }
    const size_t cbase = ((size_t)(bh * NCHK + c)) * FF;
#pragma unroll
    for (int fi = 0; fi < 16; fi++) {
        const int f = ty * 16 + fi;
        float4 o; o.x = acc[fi][0]; o.y = acc[fi][1]; o.z = acc[fi][2]; o.w = acc[fi][3];
        *(float4*)(CTX + (cbase + f) * 64 + tx * 4) = o;
    }
    if (tx == 0) {
#pragma unroll
        for (int fi = 0; fi < 16; fi++) Ksum[cbase + ty * 16 + fi] = ks[fi];
    }
}

// ---------- exclusive prefix over chunks (in place) + totals -> d_out (Z, S) ----------
__global__ void prefix_z(float* __restrict__ Ksum, float* __restrict__ Zout) {
    const int idx = blockIdx.x * 256 + threadIdx.x;   // 16*256
    const int bh = idx >> 8, f = idx & 255;
    float run = 0.f;
#pragma unroll
    for (int c = 0; c < NCHK; c++) {
        const size_t o = ((size_t)(bh * NCHK + c)) * FF + f;
        const float t = Ksum[o];
        Ksum[o] = run;
        run += t;
    }
    Zout[(size_t)bh * FF + f] = run;
}
__global__ void prefix_s(float* __restrict__ CTX, float* __restrict__ Sout) {
    const int idx = blockIdx.x * 256 + threadIdx.x;   // 1024*256
    const int bh = idx >> 14, fe = idx & 16383;
    float run = 0.f;
#pragma unroll
    for (int c = 0; c < NCHK; c++) {
        const size_t o = ((size_t)(bh * NCHK + c)) * 16384 + fe;
        const float t = CTX[o];
        CTX[o] = run;
        run += t;
    }
    Sout[(size_t)bh * 16384 + fe] = run;
}

// ---------- per-chunk output: out = (masked(qf kf^T) @ v + qf @ Sprev) / den ----------
__global__ __launch_bounds__(256)
void chunk_out(const float* __restrict__ qf, const float* __restrict__ kf,
               const float* __restrict__ vmat, const float* __restrict__ Zex,
               const float* __restrict__ Sex, float* __restrict__ attn_out)
{
    __shared__ alignas(16) float qt[16][132];
    __shared__ alignas(16) float kt[16][132];
    __shared__ alignas(8) __hip_bfloat16 A_lb[128][132];  // masked scores, bf16 to fit LDS
    __shared__ alignas(16) float v_t[16][68];
    __shared__ alignas(16) float s_l[16][68];
    __shared__ float zeps_l[16];
    __shared__ float rows_l[128];
    __shared__ float den_l[128];
    const int tid = threadIdx.x;
    const int tx = tid & 15, ty = tid >> 4;
    const int bh = blockIdx.x >> 4, c = blockIdx.x & 15;
    const int bb = bh >> 3, h = bh & 7;
    const int n0 = c * CHK;
    const size_t qkbase = (size_t)bh * NSEQ * FF;

    // ---- stage 1: A = qf_c @ kf_c^T over K=256 ----
    float acc[8][8];
#pragma unroll
    for (int i = 0; i < 8; i++)
#pragma unroll
        for (int j = 0; j < 8; j++) acc[i][j] = 0.f;

    for (int k0 = 0; k0 < FF; k0 += 16) {
#pragma unroll
        for (int p = 0; p < 2; p++) {
            const int idx = tid + p * 256;
            const int r = idx >> 2, c4 = idx & 3;
            const float4 v = *(const float4*)(qf + qkbase + (size_t)(n0 + r) * FF + k0 + c4 * 4);
            qt[c4 * 4 + 0][r] = v.x; qt[c4 * 4 + 1][r] = v.y;
            qt[c4 * 4 + 2][r] = v.z; qt[c4 * 4 + 3][r] = v.w;
            const float4 w = *(const float4*)(kf + qkbase + (size_t)(n0 + r) * FF + k0 + c4 * 4);
            kt[c4 * 4 + 0][r] = w.x; kt[c4 * 4 + 1][r] = w.y;
            kt[c4 * 4 + 2][r] = w.z; kt[c4 * 4 + 3][r] = w.w;
        }
        __syncthreads();
#pragma unroll
        for (int kk = 0; kk < 16; kk++) {
            const float4 a0 = *(const float4*)&qt[kk][ty * 8];
            const float4 a1 = *(const float4*)&qt[kk][ty * 8 + 4];
            const float4 b0 = *(const float4*)&kt[kk][tx * 4];
            const float4 b1 = *(const float4*)&kt[kk][tx * 4 + 64];
            const float av[8] = {a0.x, a0.y, a0.z, a0.w, a1.x, a1.y, a1.z, a1.w};
            const float bv[8] = {b0.x, b0.y, b0.z, b0.w, b1.x, b1.y, b1.z, b1.w};
#pragma unroll
            for (int i = 0; i < 8; i++)
#pragma unroll
                for (int j = 0; j < 8; j++)
                    acc[i][j] = fmaf(av[i], bv[j], acc[i][j]);
        }
        __syncthreads();
    }
    // ---- causal mask, bf16 store to LDS, fp32 rowsum via 16-lane shuffle ----
#pragma unroll
    for (int i = 0; i < 8; i++) {
        const int r = ty * 8 + i;
        float vals[8];
        float rs = 0.f;
#pragma unroll
        for (int j = 0; j < 8; j++) {
            const int col = (j < 4) ? (tx * 4 + j) : (64 + tx * 4 + (j - 4));
            const float v = (col <= r) ? acc[i][j] : 0.f;
            vals[j] = v;
            rs += v;
        }
        A_lb[r][tx * 4 + 0] = __float2bfloat16(vals[0]);
        A_lb[r][tx * 4 + 1] = __float2bfloat16(vals[1]);
        A_lb[r][tx * 4 + 2] = __float2bfloat16(vals[2]);
        A_lb[r][tx * 4 + 3] = __float2bfloat16(vals[3]);
        A_lb[r][64 + tx * 4 + 0] = __float2bfloat16(vals[4]);
        A_lb[r][64 + tx * 4 + 1] = __float2bfloat16(vals[5]);
        A_lb[r][64 + tx * 4 + 2] = __float2bfloat16(vals[6]);
        A_lb[r][64 + tx * 4 + 3] = __float2bfloat16(vals[7]);
        rs += __shfl_xor(rs, 1); rs += __shfl_xor(rs, 2);
        rs += __shfl_xor(rs, 4); rs += __shfl_xor(rs, 8);
        if (tx == 0) rows_l[r] = rs;
    }
    __syncthreads();

    // ---- part 1: num = maskedA @ v (v staged 16 rows at a time) ----
    float num[8][4];
#pragma unroll
    for (int i = 0; i < 8; i++)
#pragma unroll
        for (int j = 0; j < 4; j++) num[i][j] = 0.f;
    const int wmax = (tid >> 6) * 32 + 31;   // highest row index held by this wave
    for (int k0 = 0; k0 < CHK; k0 += 16) {
        {
            const int kk = tid >> 4, e4 = tid & 15;
            *(float4*)&v_t[kk][e4 * 4] =
                *(const float4*)(vmat + (size_t)(bb * NSEQ + n0 + k0 + kk) * DIMM + h * 64 + e4 * 4);
        }
        __syncthreads();
        if (k0 <= wmax) {   // causal: no contributions with k > row
#pragma unroll
            for (int kk = 0; kk < 16; kk++) {
                const float4 vv = *(const float4*)&v_t[kk][tx * 4];
                const int k = k0 + kk;
#pragma unroll
                for (int i = 0; i < 8; i++) {
                    const float a = __bfloat162float(A_lb[ty * 8 + i][k]);
                    num[i][0] = fmaf(a, vv.x, num[i][0]);
                    num[i][1] = fmaf(a, vv.y, num[i][1]);
                    num[i][2] = fmaf(a, vv.z, num[i][2]);
                    num[i][3] = fmaf(a, vv.w, num[i][3]);
                }
            }
        }
        __syncthreads();
    }

    // ---- part 2: num += qf @ Sprev ; den_acc = qf . (Zprev + EPS) ----
    float den_acc[8];
#pragma unroll
    for (int i = 0; i < 8; i++) den_acc[i] = 0.f;
    const size_t sbase = ((size_t)(bh * NCHK + c)) * FF;
    for (int k0 = 0; k0 < FF; k0 += 16) {
#pragma unroll
        for (int p = 0; p < 2; p++) {
            const int idx = tid + p * 256;
            const int r = idx >> 2, c4 = idx & 3;
            const float4 v = *(const float4*)(qf + qkbase + (size_t)(n0 + r) * FF + k0 + c4 * 4);
            qt[c4 * 4 + 0][r] = v.x; qt[c4 * 4 + 1][r] = v.y;
            qt[c4 * 4 + 2][r] = v.z; qt[c4 * 4 + 3][r] = v.w;
        }
        {
            const int kk = tid >> 4, e4 = tid & 15;
            *(float4*)&s_l[kk][e4 * 4] =
                *(const float4*)(Sex + (sbase + k0 + kk) * 64 + e4 * 4);
        }
        if (tid < 16) zeps_l[tid] = Zex[sbase + k0 + tid] + 1.0e-6f;
        __syncthreads();
#pragma unroll
        for (int kk = 0; kk < 16; kk++) {
            const float4 a0 = *(const float4*)&qt[kk][ty * 8];
            const float4 a1 = *(const float4*)&qt[kk][ty * 8 + 4];
            const float av[8] = {a0.x, a0.y, a0.z, a0.w, a1.x, a1.y, a1.z, a1.w};
            const float4 sv = *(const float4*)&s_l[kk][tx * 4];
#pragma unroll
            for (int i = 0; i < 8; i++) {
                num[i][0] = fmaf(av[i], sv.x, num[i][0]);
                num[i][1] = fmaf(av[i], sv.y, num[i][1]);
                num[i][2] = fmaf(av[i], sv.z, num[i][2]);
                num[i][3] = fmaf(av[i], sv.w, num[i][3]);
            }
            if (tx == 0) {
                const float z = zeps_l[kk];
#pragma unroll
                for (int i = 0; i < 8; i++) den_acc[i] = fmaf(av[i], z, den_acc[i]);
            }
        }
        __syncthreads();
    }
    if (tx == 0) {
#pragma unroll
        for (int i = 0; i < 8; i++) den_l[ty * 8 + i] = rows_l[ty * 8 + i] + den_acc[i];
    }
    __syncthreads();
#pragma unroll
    for (int i = 0; i < 8; i++) {
        const float dinv = 1.0f / den_l[ty * 8 + i];
        float4 o;
        o.x = num[i][0] * dinv; o.y = num[i][1] * dinv;
        o.z = num[i][2] * dinv; o.w = num[i][3] * dinv;
        // write directly in [b, n, h*64+e] layout for the final projection GEMM
        *(float4*)(attn_out + (size_t)(bb * NSEQ + n0 + ty * 8 + i) * DIMM + h * 64 + tx * 4) = o;
    }
}

extern "C" void kernel_launch(void* const* d_in, const int* in_sizes, int n_in,
                              void* d_out, int out_size, void* d_ws, size_t ws_size,
                              hipStream_t stream)
{
    (void)in_sizes; (void)n_in; (void)out_size; (void)ws_size;
    const float* x    = (const float*)d_in[0];
    const float* proj = (const float*)d_in[1];
    const float* Wq   = (const float*)d_in[2];
    const float* Wk   = (const float*)d_in[3];
    const float* Wv   = (const float*)d_in[4];
    const float* Wo   = (const float*)d_in[5];
    const float* bo   = (const float*)d_in[6];
    float* out = (float*)d_out;

    // workspace layout (floats); total ~104 MiB
    float* ws = (float*)d_ws;
    float* qmat = ws;                                   // 4096*512
    float* kmat = qmat + (size_t)4096 * 512;
    float* vmat = kmat + (size_t)4096 * 512;
    float* ddq  = vmat + (size_t)4096 * 512;            // [bh, n, f] = 16*2048*256
    float* ddk  = ddq + (size_t)NBH * NSEQ * FF;
    unsigned* mk_u = (unsigned*)(ddk + (size_t)NBH * NSEQ * FF);   // 16
    float* Ksum = (float*)(mk_u + 16);                  // [bh][chunk][f]
    float* CTX  = Ksum + (size_t)NBH * NCHK * FF;       // [bh][chunk][f][e]
    float* attn = qmat;                                 // alias: qmat dead after exp_norm

    float* Zout = out + (size_t)4096 * 512;             // [b,h,f]
    float* Sout = Zout + (size_t)NBH * FF;              // [b,h,f,e]

    hipLaunchKernelGGL(init_minmax, dim3(1), dim3(64), 0, stream, mk_u);
    hipLaunchKernelGGL(gemm_4096_512_512, dim3(4, 32, 3), dim3(256), 0, stream,
                       x, Wq, Wk, Wv, qmat, kmat, vmat, (const float*)nullptr);
    hipLaunchKernelGGL(feat_gemm, dim3(4, 32, 16), dim3(256), 0, stream,
                       qmat, kmat, proj, ddq, ddk, mk_u);
    hipLaunchKernelGGL(exp_norm, dim3(8192, 2), dim3(256), 0, stream,
                       ddq, ddk, qmat, kmat, mk_u);
    hipLaunchKernelGGL(chunk_sums, dim3(256), dim3(256), 0, stream, ddk, vmat, Ksum, CTX);
    hipLaunchKernelGGL(prefix_z, dim3(16), dim3(256), 0, stream, Ksum, Zout);
    hipLaunchKernelGGL(prefix_s, dim3(1024), dim3(256), 0, stream, CTX, Sout);
    hipLaunchKernelGGL(chunk_out, dim3(256), dim3(256), 0, stream,
                       ddq, ddk, vmat, Ksum, CTX, attn);
    hipLaunchKernelGGL(gemm_4096_512_512, dim3(4, 32, 1), dim3(256), 0, stream,
                       attn, Wo, Wo, Wo, out, out, out, bo);
}

// Round 2
// 262.890 us; speedup vs baseline: 1.6350x; 1.6350x over previous
//
#include <hip/hip_runtime.h>
#include <hip/hip_bf16.h>
#include <math.h>

// Problem constants (b=2, n=2048, dim=512, h=8, dh=64, f=256, chunk=128)
#define NB    2
#define NSEQ  2048
#define DIMM  512
#define NH    8
#define DHd   64
#define FF    256
#define CHK   128
#define NCHK  16
#define NBH   16   // NB*NH

typedef unsigned short ushort_t;
typedef __attribute__((ext_vector_type(8))) __bf16 bf16x8;
typedef __attribute__((ext_vector_type(4))) float floatx4;

// ---------- bf16 <-> fp32 helpers (bit-level, avoids __hip_bfloat16 member names) ----------
__device__ __forceinline__ unsigned short f2bf(float x) {
    union { __hip_bfloat16 h; unsigned short u; } v;
    v.h = __float2bfloat16(x);
    return v.u;
}
__device__ __forceinline__ float bf2f(unsigned short u) {
    union { unsigned short u2[2]; float f; } v;
    v.u2[0] = 0; v.u2[1] = u;
    return v.f;
}

// ---------- float <-> orderable-uint for atomicMax on floats ----------
__device__ __forceinline__ unsigned enc_f(float x) {
    unsigned u = __float_as_uint(x);
    return (u & 0x80000000u) ? ~u : (u | 0x80000000u);
}
__device__ __forceinline__ float dec_f(unsigned e) {
    unsigned u = (e & 0x80000000u) ? (e & 0x7fffffffu) : ~e;
    return __uint_as_float(u);
}

__global__ void init_minmax(unsigned* mk_u) {
    if (threadIdx.x < NBH) mk_u[threadIdx.x] = 0u;  // encodes below any finite float
}

// ---------- async global->LDS, 16B per lane ----------
__device__ __forceinline__ void gload16(const void* g, void* l) {
    __builtin_amdgcn_global_load_lds(
        (const __attribute__((address_space(1))) void*)g,
        (__attribute__((address_space(3))) void*)l, 16, 0, 0);
}

// =====================================================================
// MFMA main loop: C[128x128] += A[128xK] * B[128xK]^T  (both row-major-by-K)
// A tile rows = output rows (m), B tile rows = output cols (n).
// LDS layout: granule(row, kb) at index row*8 + (kb ^ (row&7)); granule = 8 bf16 = 16B.
// Swizzle keeps global_load_lds lane-contiguous AND ds_read_b128 conflict-free.
// =====================================================================
__device__ __forceinline__ void mfma_mainloop(
    const ushort_t* __restrict__ AG,   // already offset to tile: + m0*ldA
    const ushort_t* __restrict__ BG,   // already offset to tile: + n0*ldB
    ushort_t* As, ushort_t* Bs,        // 8192 ushorts each (16KB)
    int ldA, int ldB, int K,
    floatx4 acc[4][4], int tid)
{
    const int lane = tid & 63, wid = tid >> 6;
    const int q = lane >> 4, c = lane & 15;
    const int wm = (wid >> 1) * 64, wn = (wid & 1) * 64;

    const ushort_t* ga[4];
    const ushort_t* gb[4];
#pragma unroll
    for (int t = 0; t < 4; t++) {
        const int g = (wid * 4 + t) * 64 + lane;     // granule index in 128x8 tile
        const int r = g >> 3, kbs = g & 7;
        const int kb = kbs ^ (r & 7);                // global granule for swizzled slot
        ga[t] = AG + (size_t)r * ldA + kb * 8;
        gb[t] = BG + (size_t)r * ldB + kb * 8;
    }

    for (int k0 = 0; k0 < K; k0 += 64) {
#pragma unroll
        for (int t = 0; t < 4; t++) {
            gload16(ga[t] + k0, (char*)As + ((wid * 4 + t) << 10));
            gload16(gb[t] + k0, (char*)Bs + ((wid * 4 + t) << 10));
        }
        __syncthreads();   // compiler drains vmcnt before s_barrier (m97 structure)
#pragma unroll
        for (int ks = 0; ks < 2; ks++) {
            bf16x8 af[4], bfr[4];
#pragma unroll
            for (int i = 0; i < 4; i++) {
                const int m = wm + i * 16 + c;
                af[i] = *((const bf16x8*)As + m * 8 + ((ks * 4 + q) ^ (m & 7)));
                const int n = wn + i * 16 + c;
                bfr[i] = *((const bf16x8*)Bs + n * 8 + ((ks * 4 + q) ^ (n & 7)));
            }
#pragma unroll
            for (int i = 0; i < 4; i++)
#pragma unroll
                for (int j = 0; j < 4; j++)
                    acc[i][j] = __builtin_amdgcn_mfma_f32_16x16x32_bf16(
                        af[i], bfr[j], acc[i][j], 0, 0, 0);
        }
        __syncthreads();
    }
}

// ---------- QKV projection: z=0 -> qb (bf16), z=1 -> kb (bf16), z=2 -> vmat (fp32) ----------
__global__ __launch_bounds__(256)
void gemm_qkv(const ushort_t* __restrict__ xb,
              const ushort_t* __restrict__ Wtq, const ushort_t* __restrict__ Wtk,
              const ushort_t* __restrict__ Wtv,
              ushort_t* __restrict__ qb, ushort_t* __restrict__ kb,
              float* __restrict__ vmat)
{
    __shared__ alignas(16) ushort_t As[8192];
    __shared__ alignas(16) ushort_t Bs[8192];
    const int tid = threadIdx.x;
    const int n0 = blockIdx.x * 128, m0 = blockIdx.y * 128, z = blockIdx.z;
    const ushort_t* Bt = (z == 0) ? Wtq : ((z == 1) ? Wtk : Wtv);

    floatx4 zero = {0.f, 0.f, 0.f, 0.f};
    floatx4 acc[4][4];
#pragma unroll
    for (int i = 0; i < 4; i++)
#pragma unroll
        for (int j = 0; j < 4; j++) acc[i][j] = zero;

    mfma_mainloop(xb + (size_t)m0 * DIMM, Bt + (size_t)n0 * DIMM, As, Bs,
                  DIMM, DIMM, DIMM, acc, tid);

    const int lane = tid & 63, wid = tid >> 6;
    const int q = lane >> 4, c = lane & 15;
    const int wm = (wid >> 1) * 64, wn = (wid & 1) * 64;
    ushort_t* ob = (z == 0) ? qb : kb;
#pragma unroll
    for (int i = 0; i < 4; i++)
#pragma unroll
        for (int j = 0; j < 4; j++) {
            const int col = n0 + wn + j * 16 + c;
#pragma unroll
            for (int r = 0; r < 4; r++) {
                const int row = m0 + wm + i * 16 + q * 4 + r;
                const float v = acc[i][j][r];
                if (z < 2) ob[(size_t)row * DIMM + col] = f2bf(v);
                else       vmat[(size_t)row * DIMM + col] = v;
            }
        }
}

// ---------- output projection: out = attnb @ Wo + bias (fp32 out) ----------
__global__ __launch_bounds__(256)
void gemm_out(const ushort_t* __restrict__ attnb, const ushort_t* __restrict__ Wto,
              float* __restrict__ out, const float* __restrict__ bias)
{
    __shared__ alignas(16) ushort_t As[8192];
    __shared__ alignas(16) ushort_t Bs[8192];
    const int tid = threadIdx.x;
    const int n0 = blockIdx.x * 128, m0 = blockIdx.y * 128;

    floatx4 zero = {0.f, 0.f, 0.f, 0.f};
    floatx4 acc[4][4];
#pragma unroll
    for (int i = 0; i < 4; i++)
#pragma unroll
        for (int j = 0; j < 4; j++) acc[i][j] = zero;

    mfma_mainloop(attnb + (size_t)m0 * DIMM, Wto + (size_t)n0 * DIMM, As, Bs,
                  DIMM, DIMM, DIMM, acc, tid);

    const int lane = tid & 63, wid = tid >> 6;
    const int q = lane >> 4, c = lane & 15;
    const int wm = (wid >> 1) * 64, wn = (wid & 1) * 64;
#pragma unroll
    for (int i = 0; i < 4; i++)
#pragma unroll
        for (int j = 0; j < 4; j++) {
            const int col = n0 + wn + j * 16 + c;
            const float bv = bias[col];
#pragma unroll
            for (int r = 0; r < 4; r++) {
                const int row = m0 + wm + i * 16 + q * 4 + r;
                out[(size_t)row * DIMM + col] = acc[i][j][r] + bv;
            }
        }
}

// ---------- FAVOR feature GEMM via MFMA: dd = (q|k slice) @ (dn*proj)^T, K=64 ----------
__global__ __launch_bounds__(256)
void feat_mfma(const ushort_t* __restrict__ qb, const ushort_t* __restrict__ kb,
               const ushort_t* __restrict__ projb,
               float* __restrict__ ddq, float* __restrict__ ddk,
               unsigned* __restrict__ mk_u)
{
    __shared__ alignas(16) ushort_t As[8192];
    __shared__ alignas(16) ushort_t Bs[8192];
    __shared__ float red[256];
    const int tid = threadIdx.x;
    const int f0 = blockIdx.x * 128, m0 = blockIdx.y * 128;
    const int src = blockIdx.z >> 3, h = blockIdx.z & 7;
    const ushort_t* Am = (src ? kb : qb) + (size_t)m0 * DIMM + h * 64;

    floatx4 zero = {0.f, 0.f, 0.f, 0.f};
    floatx4 acc[4][4];
#pragma unroll
    for (int i = 0; i < 4; i++)
#pragma unroll
        for (int j = 0; j < 4; j++) acc[i][j] = zero;

    mfma_mainloop(Am, projb + (size_t)f0 * 64, As, Bs, DIMM, 64, 64, acc, tid);

    const int lane = tid & 63, wid = tid >> 6;
    const int q = lane >> 4, c = lane & 15;
    const int wm = (wid >> 1) * 64, wn = (wid & 1) * 64;
    float* dd = src ? ddk : ddq;
    const int bb = m0 >> 11;            // 128-row tiles never straddle the batch boundary
    float mloc = -3.0e38f;
#pragma unroll
    for (int i = 0; i < 4; i++)
#pragma unroll
        for (int j = 0; j < 4; j++) {
            const int f = f0 + wn + j * 16 + c;
#pragma unroll
            for (int r = 0; r < 4; r++) {
                const int row = m0 + wm + i * 16 + q * 4 + r;
                const int nn = row & 2047;
                const float v = acc[i][j][r];
                mloc = fmaxf(mloc, v);
                dd[((size_t)(bb * NH + h) * NSEQ + nn) * FF + f] = v;
            }
        }
    if (src) {
        red[tid] = mloc;
        __syncthreads();
        for (int s = 128; s > 0; s >>= 1) {
            if (tid < s) red[tid] = fmaxf(red[tid], red[tid + s]);
            __syncthreads();
        }
        if (tid == 0) atomicMax(&mk_u[bb * NH + h], enc_f(red[0]));
    }
}

// ---------- exp/normalize: ff = ratio*(exp(dd - diag - m) + KERNEL_EPS), in place ----------
__global__ __launch_bounds__(256)
void exp_norm(float* __restrict__ ddq, float* __restrict__ ddk,
              const ushort_t* __restrict__ qb, const ushort_t* __restrict__ kb,
              const unsigned* __restrict__ mk_u)
{
    const int tid = threadIdx.x;
    const int lane = tid & 63;
    const int row = blockIdx.x * 4 + (tid >> 6);   // row = bh*2048 + n
    const int src = blockIdx.y;
    float* dd = src ? ddk : ddq;
    const ushort_t* qk = src ? kb : qb;
    const int bh = row >> 11;
    const int n = row & 2047;
    const int bb = bh >> 3, h = bh & 7;
    // diag = sum(q^2)/16  (= 0.5 * 64^-0.5 * sum), from the same bf16 q the GEMM used
    const float qv = bf2f(qk[(size_t)(bb * NSEQ + n) * DIMM + h * 64 + lane]);
    float ss = qv * qv;
#pragma unroll
    for (int off = 32; off > 0; off >>= 1) ss += __shfl_xor(ss, off);
    const float diag = ss * 0.0625f;

    float4 d4 = *(float4*)(dd + (size_t)row * FF + lane * 4);
    float m;
    if (src == 0) {
        float ml = fmaxf(fmaxf(d4.x, d4.y), fmaxf(d4.z, d4.w));
#pragma unroll
        for (int off = 32; off > 0; off >>= 1) ml = fmaxf(ml, __shfl_xor(ml, off));
        m = ml;                     // per-row max for queries
    } else {
        m = dec_f(mk_u[bh]);        // per-(b,h) global max for keys
    }
    const float cc = diag + m;
    float4 o;
    o.x = 0.0625f * (__expf(d4.x - cc) + 1.0e-4f);
    o.y = 0.0625f * (__expf(d4.y - cc) + 1.0e-4f);
    o.z = 0.0625f * (__expf(d4.z - cc) + 1.0e-4f);
    o.w = 0.0625f * (__expf(d4.w - cc) + 1.0e-4f);
    *(float4*)(dd + (size_t)row * FF + lane * 4) = o;
}

// ---------- per-chunk sums: Ksum[bh][c][f] = sum_i kf; CTX[bh][c][f][e] = kf^T @ v ----------
__global__ __launch_bounds__(256)
void chunk_sums(const float* __restrict__ kf, const float* __restrict__ vmat,
                float* __restrict__ Ksum, float* __restrict__ CTX)
{
    __shared__ alignas(16) float kfs[8][260];
    __shared__ alignas(16) float vs[8][68];
    const int tid = threadIdx.x;
    const int tx = tid & 15, ty = tid >> 4;
    const int bh = blockIdx.x >> 4, c = blockIdx.x & 15;
    const int bb = bh >> 3, h = bh & 7;
    const int n0 = c * CHK;
    float acc[16][4];
    float ks[16];
#pragma unroll
    for (int fi = 0; fi < 16; fi++) {
        ks[fi] = 0.f;
#pragma unroll
        for (int j = 0; j < 4; j++) acc[fi][j] = 0.f;
    }
    for (int i0 = 0; i0 < CHK; i0 += 8) {
#pragma unroll
        for (int p = 0; p < 2; p++) {
            const int idx = tid + p * 256;
            const int r = idx >> 6, c4 = idx & 63;
            *(float4*)&kfs[r][c4 * 4] =
                *(const float4*)(kf + ((size_t)(bh * NSEQ + n0 + i0 + r)) * FF + c4 * 4);
        }
        if (tid < 128) {
            const int r = tid >> 4, c4 = tid & 15;
            *(float4*)&vs[r][c4 * 4] =
                *(const float4*)(vmat + ((size_t)(bb * NSEQ + n0 + i0 + r)) * DIMM + h * 64 + c4 * 4);
        }
        __syncthreads();
#pragma unroll
        for (int kk = 0; kk < 8; kk++) {
            float a[16];
            *(float4*)&a[0]  = *(const float4*)&kfs[kk][ty * 16];
            *(float4*)&a[4]  = *(const float4*)&kfs[kk][ty * 16 + 4];
            *(float4*)&a[8]  = *(const float4*)&kfs[kk][ty * 16 + 8];
            *(float4*)&a[12] = *(const float4*)&kfs[kk][ty * 16 + 12];
            const float4 bv = *(const float4*)&vs[kk][tx * 4];
#pragma unroll
            for (int fi = 0; fi < 16; fi++) {
                acc[fi][0] = fmaf(a[fi], bv.x, acc[fi][0]);
                acc[fi][1] = fmaf(a[fi], bv.y, acc[fi][1]);
                acc[fi][2] = fmaf(a[fi], bv.z, acc[fi][2]);
                acc[fi][3] = fmaf(a[fi], bv.w, acc[fi][3]);
            }
            if (tx == 0) {
#pragma unroll
                for (int fi = 0; fi < 16; fi++) ks[fi] += a[fi];
            }
        }
        __syncthreads();
    }
    const size_t cbase = ((size_t)(bh * NCHK + c)) * FF;
#pragma unroll
    for (int fi = 0; fi < 16; fi++) {
        const int f = ty * 16 + fi;
        float4 o; o.x = acc[fi][0]; o.y = acc[fi][1]; o.z = acc[fi][2]; o.w = acc[fi][3];
        *(float4*)(CTX + (cbase + f) * 64 + tx * 4) = o;
    }
    if (tx == 0) {
#pragma unroll
        for (int fi = 0; fi < 16; fi++) Ksum[cbase + ty * 16 + fi] = ks[fi];
    }
}

// ---------- exclusive prefix over chunks (in place) + totals -> d_out (Z, S) ----------
__global__ void prefix_z(float* __restrict__ Ksum, float* __restrict__ Zout) {
    const int idx = blockIdx.x * 256 + threadIdx.x;   // 16*256
    const int bh = idx >> 8, f = idx & 255;
    float run = 0.f;
#pragma unroll
    for (int c = 0; c < NCHK; c++) {
        const size_t o = ((size_t)(bh * NCHK + c)) * FF + f;
        const float t = Ksum[o];
        Ksum[o] = run;
        run += t;
    }
    Zout[(size_t)bh * FF + f] = run;
}
__global__ void prefix_s(float* __restrict__ CTX, float* __restrict__ Sout) {
    const int idx = blockIdx.x * 256 + threadIdx.x;   // 1024*256
    const int bh = idx >> 14, fe = idx & 16383;
    float run = 0.f;
#pragma unroll
    for (int c = 0; c < NCHK; c++) {
        const size_t o = ((size_t)(bh * NCHK + c)) * 16384 + fe;
        const float t = CTX[o];
        CTX[o] = run;
        run += t;
    }
    Sout[(size_t)bh * 16384 + fe] = run;
}

// ---------- per-chunk output: out = (masked(qf kf^T) @ v + qf @ Sprev) / den ----------
__global__ __launch_bounds__(256)
void chunk_out(const float* __restrict__ qf, const float* __restrict__ kf,
               const float* __restrict__ vmat, const float* __restrict__ Zex,
               const float* __restrict__ Sex, ushort_t* __restrict__ attnb)
{
    __shared__ alignas(16) float qt[16][132];
    __shared__ alignas(16) float kt[16][132];
    __shared__ alignas(8) ushort_t A_lb[128][132];  // masked scores, bf16 to fit LDS
    __shared__ alignas(16) float v_t[16][68];
    __shared__ alignas(16) float s_l[16][68];
    __shared__ float zeps_l[16];
    __shared__ float rows_l[128];
    __shared__ float den_l[128];
    const int tid = threadIdx.x;
    const int tx = tid & 15, ty = tid >> 4;
    const int bh = blockIdx.x >> 4, c = blockIdx.x & 15;
    const int bb = bh >> 3, h = bh & 7;
    const int n0 = c * CHK;
    const size_t qkbase = (size_t)bh * NSEQ * FF;

    // ---- stage 1: A = qf_c @ kf_c^T over K=256 ----
    float acc[8][8];
#pragma unroll
    for (int i = 0; i < 8; i++)
#pragma unroll
        for (int j = 0; j < 8; j++) acc[i][j] = 0.f;

    for (int k0 = 0; k0 < FF; k0 += 16) {
#pragma unroll
        for (int p = 0; p < 2; p++) {
            const int idx = tid + p * 256;
            const int r = idx >> 2, c4 = idx & 3;
            const float4 v = *(const float4*)(qf + qkbase + (size_t)(n0 + r) * FF + k0 + c4 * 4);
            qt[c4 * 4 + 0][r] = v.x; qt[c4 * 4 + 1][r] = v.y;
            qt[c4 * 4 + 2][r] = v.z; qt[c4 * 4 + 3][r] = v.w;
            const float4 w = *(const float4*)(kf + qkbase + (size_t)(n0 + r) * FF + k0 + c4 * 4);
            kt[c4 * 4 + 0][r] = w.x; kt[c4 * 4 + 1][r] = w.y;
            kt[c4 * 4 + 2][r] = w.z; kt[c4 * 4 + 3][r] = w.w;
        }
        __syncthreads();
#pragma unroll
        for (int kk = 0; kk < 16; kk++) {
            const float4 a0 = *(const float4*)&qt[kk][ty * 8];
            const float4 a1 = *(const float4*)&qt[kk][ty * 8 + 4];
            const float4 b0 = *(const float4*)&kt[kk][tx * 4];
            const float4 b1 = *(const float4*)&kt[kk][tx * 4 + 64];
            const float av[8] = {a0.x, a0.y, a0.z, a0.w, a1.x, a1.y, a1.z, a1.w};
            const float bv[8] = {b0.x, b0.y, b0.z, b0.w, b1.x, b1.y, b1.z, b1.w};
#pragma unroll
            for (int i = 0; i < 8; i++)
#pragma unroll
                for (int j = 0; j < 8; j++)
                    acc[i][j] = fmaf(av[i], bv[j], acc[i][j]);
        }
        __syncthreads();
    }
    // ---- causal mask, bf16 store to LDS, fp32 rowsum via 16-lane shuffle ----
#pragma unroll
    for (int i = 0; i < 8; i++) {
        const int r = ty * 8 + i;
        float vals[8];
        float rs = 0.f;
#pragma unroll
        for (int j = 0; j < 8; j++) {
            const int col = (j < 4) ? (tx * 4 + j) : (64 + tx * 4 + (j - 4));
            const float v = (col <= r) ? acc[i][j] : 0.f;
            vals[j] = v;
            rs += v;
        }
        A_lb[r][tx * 4 + 0] = f2bf(vals[0]);
        A_lb[r][tx * 4 + 1] = f2bf(vals[1]);
        A_lb[r][tx * 4 + 2] = f2bf(vals[2]);
        A_lb[r][tx * 4 + 3] = f2bf(vals[3]);
        A_lb[r][64 + tx * 4 + 0] = f2bf(vals[4]);
        A_lb[r][64 + tx * 4 + 1] = f2bf(vals[5]);
        A_lb[r][64 + tx * 4 + 2] = f2bf(vals[6]);
        A_lb[r][64 + tx * 4 + 3] = f2bf(vals[7]);
        rs += __shfl_xor(rs, 1); rs += __shfl_xor(rs, 2);
        rs += __shfl_xor(rs, 4); rs += __shfl_xor(rs, 8);
        if (tx == 0) rows_l[r] = rs;
    }
    __syncthreads();

    // ---- part 1: num = maskedA @ v (v staged 16 rows at a time) ----
    float num[8][4];
#pragma unroll
    for (int i = 0; i < 8; i++)
#pragma unroll
        for (int j = 0; j < 4; j++) num[i][j] = 0.f;
    const int wmax = (tid >> 6) * 32 + 31;   // highest row index held by this wave
    for (int k0 = 0; k0 < CHK; k0 += 16) {
        {
            const int kk = tid >> 4, e4 = tid & 15;
            *(float4*)&v_t[kk][e4 * 4] =
                *(const float4*)(vmat + (size_t)(bb * NSEQ + n0 + k0 + kk) * DIMM + h * 64 + e4 * 4);
        }
        __syncthreads();
        if (k0 <= wmax) {   // causal: no contributions with k > row
#pragma unroll
            for (int kk = 0; kk < 16; kk++) {
                const float4 vv = *(const float4*)&v_t[kk][tx * 4];
                const int k = k0 + kk;
#pragma unroll
                for (int i = 0; i < 8; i++) {
                    const float a = bf2f(A_lb[ty * 8 + i][k]);
                    num[i][0] = fmaf(a, vv.x, num[i][0]);
                    num[i][1] = fmaf(a, vv.y, num[i][1]);
                    num[i][2] = fmaf(a, vv.z, num[i][2]);
                    num[i][3] = fmaf(a, vv.w, num[i][3]);
                }
            }
        }
        __syncthreads();
    }

    // ---- part 2: num += qf @ Sprev ; den_acc = qf . (Zprev + EPS) ----
    float den_acc[8];
#pragma unroll
    for (int i = 0; i < 8; i++) den_acc[i] = 0.f;
    const size_t sbase = ((size_t)(bh * NCHK + c)) * FF;
    for (int k0 = 0; k0 < FF; k0 += 16) {
#pragma unroll
        for (int p = 0; p < 2; p++) {
            const int idx = tid + p * 256;
            const int r = idx >> 2, c4 = idx & 3;
            const float4 v = *(const float4*)(qf + qkbase + (size_t)(n0 + r) * FF + k0 + c4 * 4);
            qt[c4 * 4 + 0][r] = v.x; qt[c4 * 4 + 1][r] = v.y;
            qt[c4 * 4 + 2][r] = v.z; qt[c4 * 4 + 3][r] = v.w;
        }
        {
            const int kk = tid >> 4, e4 = tid & 15;
            *(float4*)&s_l[kk][e4 * 4] =
                *(const float4*)(Sex + (sbase + k0 + kk) * 64 + e4 * 4);
        }
        if (tid < 16) zeps_l[tid] = Zex[sbase + k0 + tid] + 1.0e-6f;
        __syncthreads();
#pragma unroll
        for (int kk = 0; kk < 16; kk++) {
            const float4 a0 = *(const float4*)&qt[kk][ty * 8];
            const float4 a1 = *(const float4*)&qt[kk][ty * 8 + 4];
            const float av[8] = {a0.x, a0.y, a0.z, a0.w, a1.x, a1.y, a1.z, a1.w};
            const float4 sv = *(const float4*)&s_l[kk][tx * 4];
#pragma unroll
            for (int i = 0; i < 8; i++) {
                num[i][0] = fmaf(av[i], sv.x, num[i][0]);
                num[i][1] = fmaf(av[i], sv.y, num[i][1]);
                num[i][2] = fmaf(av[i], sv.z, num[i][2]);
                num[i][3] = fmaf(av[i], sv.w, num[i][3]);
            }
            if (tx == 0) {
                const float z = zeps_l[kk];
#pragma unroll
                for (int i = 0; i < 8; i++) den_acc[i] = fmaf(av[i], z, den_acc[i]);
            }
        }
        __syncthreads();
    }
    if (tx == 0) {
#pragma unroll
        for (int i = 0; i < 8; i++) den_l[ty * 8 + i] = rows_l[ty * 8 + i] + den_acc[i];
    }
    __syncthreads();
#pragma unroll
    for (int i = 0; i < 8; i++) {
        const float dinv = 1.0f / den_l[ty * 8 + i];
        union { ushort4 v4; unsigned short s[4]; } pk;
        pk.s[0] = f2bf(num[i][0] * dinv);
        pk.s[1] = f2bf(num[i][1] * dinv);
        pk.s[2] = f2bf(num[i][2] * dinv);
        pk.s[3] = f2bf(num[i][3] * dinv);
        // write bf16 in [b, n, h*64+e] layout — A operand of the final MFMA GEMM
        *(ushort4*)(attnb + (size_t)(bb * NSEQ + n0 + ty * 8 + i) * DIMM + h * 64 + tx * 4) = pk.v4;
    }
}

// ---------- conversions ----------
__global__ void conv_x(const float* __restrict__ x, ushort_t* __restrict__ xb) {
    const int gid = blockIdx.x * 256 + threadIdx.x;   // 2048*256 threads, 4 elems each
    const float4 v = *(const float4*)(x + (size_t)gid * 4);
    union { ushort4 v4; unsigned short s[4]; } pk;
    pk.s[0] = f2bf(v.x); pk.s[1] = f2bf(v.y); pk.s[2] = f2bf(v.z); pk.s[3] = f2bf(v.w);
    ((ushort4*)xb)[gid] = pk.v4;
}
__global__ void conv_proj(const float* __restrict__ proj, ushort_t* __restrict__ projb) {
    const int gid = blockIdx.x * 256 + threadIdx.x;   // 16*256 threads, 4 elems each
    const float dn = 0.35355339059327379f;            // 64^-0.25, folded into proj
    const float4 v = *(const float4*)(proj + (size_t)gid * 4);
    union { ushort4 v4; unsigned short s[4]; } pk;
    pk.s[0] = f2bf(v.x * dn); pk.s[1] = f2bf(v.y * dn);
    pk.s[2] = f2bf(v.z * dn); pk.s[3] = f2bf(v.w * dn);
    ((ushort4*)projb)[gid] = pk.v4;
}
// W[512][512] -> Wt[n][k] bf16, z picks among 4 matrices
__global__ void transpose_w(const float* __restrict__ W0, const float* __restrict__ W1,
                            const float* __restrict__ W2, const float* __restrict__ W3,
                            ushort_t* __restrict__ T0, ushort_t* __restrict__ T1,
                            ushort_t* __restrict__ T2, ushort_t* __restrict__ T3)
{
    __shared__ float t[32][33];
    const int z = blockIdx.z;
    const float* W = (z == 0) ? W0 : (z == 1) ? W1 : (z == 2) ? W2 : W3;
    ushort_t* T = (z == 0) ? T0 : (z == 1) ? T1 : (z == 2) ? T2 : T3;
    const int x0 = blockIdx.x * 32, y0 = blockIdx.y * 32;
    const int tx = threadIdx.x, ty = threadIdx.y;
#pragma unroll
    for (int i = 0; i < 4; i++)
        t[ty + i * 8][tx] = W[(size_t)(y0 + ty + i * 8) * DIMM + x0 + tx];
    __syncthreads();
#pragma unroll
    for (int i = 0; i < 4; i++)
        T[(size_t)(x0 + ty + i * 8) * DIMM + y0 + tx] = f2bf(t[tx][ty + i * 8]);
}

extern "C" void kernel_launch(void* const* d_in, const int* in_sizes, int n_in,
                              void* d_out, int out_size, void* d_ws, size_t ws_size,
                              hipStream_t stream)
{
    (void)in_sizes; (void)n_in; (void)out_size; (void)ws_size;
    const float* x    = (const float*)d_in[0];
    const float* proj = (const float*)d_in[1];
    const float* Wq   = (const float*)d_in[2];
    const float* Wk   = (const float*)d_in[3];
    const float* Wv   = (const float*)d_in[4];
    const float* Wo   = (const float*)d_in[5];
    const float* bo   = (const float*)d_in[6];
    float* out = (float*)d_out;

    // workspace layout (~103 MiB, fits the footprint round 1 already used)
    float* ws = (float*)d_ws;
    float* vmat = ws;                                    // 4096*512 fp32
    float* ddq  = vmat + (size_t)4096 * 512;             // 16*2048*256 fp32
    float* ddk  = ddq + (size_t)NBH * NSEQ * FF;
    float* CTX  = ddk + (size_t)NBH * NSEQ * FF;         // 16*16*256*64 fp32
    float* Ksum = CTX + (size_t)NBH * NCHK * FF * 64;    // 16*16*256 fp32
    unsigned* mk_u = (unsigned*)(Ksum + (size_t)NBH * NCHK * FF);   // 16
    ushort_t* qb    = (ushort_t*)(mk_u + 16);            // 4096*512 bf16
    ushort_t* kb    = qb + (size_t)4096 * 512;
    ushort_t* xb    = kb + (size_t)4096 * 512;           // also reused as attnb (x dead)
    ushort_t* Wtq   = xb + (size_t)4096 * 512;           // 512*512 bf16 each
    ushort_t* Wtk   = Wtq + (size_t)512 * 512;
    ushort_t* Wtv   = Wtk + (size_t)512 * 512;
    ushort_t* Wto   = Wtv + (size_t)512 * 512;
    ushort_t* projb = Wto + (size_t)512 * 512;           // 256*64 bf16
    ushort_t* attnb = xb;                                // alias: xb dead after gemm_qkv

    float* Zout = out + (size_t)4096 * 512;              // [b,h,f]
    float* Sout = Zout + (size_t)NBH * FF;               // [b,h,f,e]

    hipLaunchKernelGGL(init_minmax, dim3(1), dim3(64), 0, stream, mk_u);
    hipLaunchKernelGGL(conv_x, dim3(2048), dim3(256), 0, stream, x, xb);
    hipLaunchKernelGGL(conv_proj, dim3(16), dim3(256), 0, stream, proj, projb);
    hipLaunchKernelGGL(transpose_w, dim3(16, 16, 4), dim3(32, 8), 0, stream,
                       Wq, Wk, Wv, Wo, Wtq, Wtk, Wtv, Wto);
    hipLaunchKernelGGL(gemm_qkv, dim3(4, 32, 3), dim3(256), 0, stream,
                       xb, Wtq, Wtk, Wtv, qb, kb, vmat);
    hipLaunchKernelGGL(feat_mfma, dim3(2, 32, 16), dim3(256), 0, stream,
                       qb, kb, projb, ddq, ddk, mk_u);
    hipLaunchKernelGGL(exp_norm, dim3(8192, 2), dim3(256), 0, stream,
                       ddq, ddk, qb, kb, mk_u);
    hipLaunchKernelGGL(chunk_sums, dim3(256), dim3(256), 0, stream, ddk, vmat, Ksum, CTX);
    hipLaunchKernelGGL(prefix_z, dim3(16), dim3(256), 0, stream, Ksum, Zout);
    hipLaunchKernelGGL(prefix_s, dim3(1024), dim3(256), 0, stream, CTX, Sout);
    hipLaunchKernelGGL(chunk_out, dim3(256), dim3(256), 0, stream,
                       ddq, ddk, vmat, Ksum, CTX, attnb);
    hipLaunchKernelGGL(gemm_out, dim3(4, 32), dim3(256), 0, stream, attnb, Wto, out, bo);
}

// Round 3
// 185.612 us; speedup vs baseline: 2.3157x; 1.4163x over previous
//
#include <hip/hip_runtime.h>
#include <hip/hip_bf16.h>
#include <math.h>

// Problem constants (b=2, n=2048, dim=512, h=8, dh=64, f=256, chunk=128)
#define NB    2
#define NSEQ  2048
#define DIMM  512
#define NH    8
#define DHd   64
#define FF    256
#define CHK   128
#define NCHK  16
#define NBH   16   // NB*NH

typedef unsigned short ushort_t;
typedef __attribute__((ext_vector_type(8))) __bf16 bf16x8;
typedef __attribute__((ext_vector_type(4))) float floatx4;

__device__ __forceinline__ unsigned short f2bf(float x) {
    union { __hip_bfloat16 h; unsigned short u; } v;
    v.h = __float2bfloat16(x);
    return v.u;
}
__device__ __forceinline__ float bf2f(unsigned short u) {
    union { unsigned short u2[2]; float f; } v;
    v.u2[0] = 0; v.u2[1] = u;
    return v.f;
}
__device__ __forceinline__ unsigned enc_f(float x) {
    unsigned u = __float_as_uint(x);
    return (u & 0x80000000u) ? ~u : (u | 0x80000000u);
}
__device__ __forceinline__ float dec_f(unsigned e) {
    unsigned u = (e & 0x80000000u) ? (e & 0x7fffffffu) : ~e;
    return __uint_as_float(u);
}

__global__ void init_minmax(unsigned* mk_u) {
    if (threadIdx.x < NBH) mk_u[threadIdx.x] = 0u;
}

__device__ __forceinline__ void gload16(const void* g, void* l) {
    __builtin_amdgcn_global_load_lds(
        (const __attribute__((address_space(1))) void*)g,
        (__attribute__((address_space(3))) void*)l, 16, 0, 0);
}

// frag read from a 64-k-step tile (8 granules/row, xor-swizzled)
__device__ __forceinline__ bf16x8 frag8(const ushort_t* lds, int row, int kb) {
    return *((const bf16x8*)lds + row * 8 + (kb ^ (row & 7)));
}
// frag read from the 128-k S tile (16 granules/row)
__device__ __forceinline__ bf16x8 fragS(const ushort_t* lds, int row, int kb) {
    return *((const bf16x8*)lds + row * 16 + (kb ^ (row & 15)));
}

// =====================================================================
// MFMA main loop (round-2): C[128x128] += A[128xK] * B[128xK]^T
// =====================================================================
__device__ __forceinline__ void mfma_mainloop(
    const ushort_t* __restrict__ AG, const ushort_t* __restrict__ BG,
    ushort_t* As, ushort_t* Bs, int ldA, int ldB, int K,
    floatx4 acc[4][4], int tid)
{
    const int lane = tid & 63, wid = tid >> 6;
    const int q = lane >> 4, c = lane & 15;
    const int wm = (wid >> 1) * 64, wn = (wid & 1) * 64;

    for (int k0 = 0; k0 < K; k0 += 64) {
#pragma unroll
        for (int t = 0; t < 4; t++) {
            const int g = t * 256 + tid, r = g >> 3, kb = (g & 7) ^ (r & 7);
            gload16(AG + (size_t)r * ldA + k0 + kb * 8, As + (size_t)g * 8);
        }
#pragma unroll
        for (int t = 0; t < 4; t++) {
            const int g = t * 256 + tid, r = g >> 3, kb = (g & 7) ^ (r & 7);
            gload16(BG + (size_t)r * ldB + k0 + kb * 8, Bs + (size_t)g * 8);
        }
        __syncthreads();
#pragma unroll
        for (int ks = 0; ks < 2; ks++) {
            bf16x8 af[4], bfr[4];
#pragma unroll
            for (int i = 0; i < 4; i++) {
                af[i]  = frag8(As, wm + i * 16 + c, ks * 4 + q);
                bfr[i] = frag8(Bs, wn + i * 16 + c, ks * 4 + q);
            }
#pragma unroll
            for (int i = 0; i < 4; i++)
#pragma unroll
                for (int j = 0; j < 4; j++)
                    acc[i][j] = __builtin_amdgcn_mfma_f32_16x16x32_bf16(
                        af[i], bfr[j], acc[i][j], 0, 0, 0);
        }
        __syncthreads();
    }
}

// ---------- QKV projection: all outputs bf16 ----------
__global__ __launch_bounds__(256)
void gemm_qkv(const ushort_t* __restrict__ xb,
              const ushort_t* __restrict__ Wtq, const ushort_t* __restrict__ Wtk,
              const ushort_t* __restrict__ Wtv,
              ushort_t* __restrict__ qb, ushort_t* __restrict__ kb,
              ushort_t* __restrict__ vb)
{
    __shared__ alignas(16) ushort_t As[8192];
    __shared__ alignas(16) ushort_t Bs[8192];
    const int tid = threadIdx.x;
    const int n0 = blockIdx.x * 128, m0 = blockIdx.y * 128, z = blockIdx.z;
    const ushort_t* Bt = (z == 0) ? Wtq : ((z == 1) ? Wtk : Wtv);
    ushort_t* ob = (z == 0) ? qb : ((z == 1) ? kb : vb);

    floatx4 zero = {0.f, 0.f, 0.f, 0.f};
    floatx4 acc[4][4];
#pragma unroll
    for (int i = 0; i < 4; i++)
#pragma unroll
        for (int j = 0; j < 4; j++) acc[i][j] = zero;

    mfma_mainloop(xb + (size_t)m0 * DIMM, Bt + (size_t)n0 * DIMM, As, Bs,
                  DIMM, DIMM, DIMM, acc, tid);

    const int lane = tid & 63, wid = tid >> 6;
    const int q = lane >> 4, c = lane & 15;
    const int wm = (wid >> 1) * 64, wn = (wid & 1) * 64;
#pragma unroll
    for (int i = 0; i < 4; i++)
#pragma unroll
        for (int j = 0; j < 4; j++) {
            const int col = n0 + wn + j * 16 + c;
#pragma unroll
            for (int r = 0; r < 4; r++) {
                const int row = m0 + wm + i * 16 + q * 4 + r;
                ob[(size_t)row * DIMM + col] = f2bf(acc[i][j][r]);
            }
        }
}

// ---------- output projection ----------
__global__ __launch_bounds__(256)
void gemm_out(const ushort_t* __restrict__ attnb, const ushort_t* __restrict__ Wto,
              float* __restrict__ out, const float* __restrict__ bias)
{
    __shared__ alignas(16) ushort_t As[8192];
    __shared__ alignas(16) ushort_t Bs[8192];
    const int tid = threadIdx.x;
    const int n0 = blockIdx.x * 128, m0 = blockIdx.y * 128;

    floatx4 zero = {0.f, 0.f, 0.f, 0.f};
    floatx4 acc[4][4];
#pragma unroll
    for (int i = 0; i < 4; i++)
#pragma unroll
        for (int j = 0; j < 4; j++) acc[i][j] = zero;

    mfma_mainloop(attnb + (size_t)m0 * DIMM, Wto + (size_t)n0 * DIMM, As, Bs,
                  DIMM, DIMM, DIMM, acc, tid);

    const int lane = tid & 63, wid = tid >> 6;
    const int q = lane >> 4, c = lane & 15;
    const int wm = (wid >> 1) * 64, wn = (wid & 1) * 64;
#pragma unroll
    for (int i = 0; i < 4; i++)
#pragma unroll
        for (int j = 0; j < 4; j++) {
            const int col = n0 + wn + j * 16 + c;
            const float bv = bias[col];
#pragma unroll
            for (int r = 0; r < 4; r++) {
                const int row = m0 + wm + i * 16 + q * 4 + r;
                out[(size_t)row * DIMM + col] = acc[i][j][r] + bv;
            }
        }
}

// ---------- fused query features: dd = q@(dn proj)^T, exp-normalized in-block ----------
__global__ __launch_bounds__(256)
void feat_q(const ushort_t* __restrict__ qb_, const ushort_t* __restrict__ projb,
            ushort_t* __restrict__ qfb)
{
    __shared__ alignas(16) ushort_t As[8192];    // 128 rows x 64k
    __shared__ alignas(16) ushort_t Bs[16384];   // 256 rows x 64k
    __shared__ float dtmp[256];
    __shared__ float diag_l[128];
    __shared__ float mx2[2][128];
    const int tid = threadIdx.x, lane = tid & 63, wid = tid >> 6;
    const int q = lane >> 4, cl = lane & 15;
    const int m0 = blockIdx.x * 128, h = blockIdx.y;
    const int bb = m0 >> 11, nloc = m0 & 2047;
    const ushort_t* Aq = qb_ + (size_t)m0 * DIMM + h * 64;

    // diag[row] = sum(q^2)/16 (from the same bf16 q the GEMM uses)
    {
        const int row = tid >> 1, half = tid & 1;
        float s = 0.f;
        const ushort_t* p = Aq + (size_t)row * DIMM + half * 32;
#pragma unroll
        for (int d = 0; d < 32; d += 4) {
            ushort4 w = *(const ushort4*)(p + d);
            float a = bf2f(w.x), b2 = bf2f(w.y), c2 = bf2f(w.z), d2 = bf2f(w.w);
            s += a * a + b2 * b2 + c2 * c2 + d2 * d2;
        }
        dtmp[tid] = s;
    }
    __syncthreads();
    if (tid < 128) diag_l[tid] = (dtmp[tid * 2] + dtmp[tid * 2 + 1]) * 0.0625f;

    floatx4 zero = {0.f, 0.f, 0.f, 0.f};
    floatx4 acc[4][8];
#pragma unroll
    for (int i = 0; i < 4; i++)
#pragma unroll
        for (int j = 0; j < 8; j++) acc[i][j] = zero;

    const int wm = (wid >> 1) * 64, wn = (wid & 1) * 128;
    // K = 64: single staging step
#pragma unroll
    for (int t = 0; t < 4; t++) {
        const int g = t * 256 + tid, r = g >> 3, kb = (g & 7) ^ (r & 7);
        gload16(Aq + (size_t)r * DIMM + kb * 8, As + (size_t)g * 8);
    }
#pragma unroll
    for (int t = 0; t < 8; t++) {
        const int g = t * 256 + tid, r = g >> 3, kb = (g & 7) ^ (r & 7);
        gload16(projb + (size_t)r * 64 + kb * 8, Bs + (size_t)g * 8);
    }
    __syncthreads();
#pragma unroll
    for (int ks = 0; ks < 2; ks++) {
        bf16x8 af[4], bfr[8];
#pragma unroll
        for (int i = 0; i < 4; i++) af[i] = frag8(As, wm + i * 16 + cl, ks * 4 + q);
#pragma unroll
        for (int j = 0; j < 8; j++) bfr[j] = frag8(Bs, wn + j * 16 + cl, ks * 4 + q);
#pragma unroll
        for (int i = 0; i < 4; i++)
#pragma unroll
            for (int j = 0; j < 8; j++)
                acc[i][j] = __builtin_amdgcn_mfma_f32_16x16x32_bf16(
                    af[i], bfr[j], acc[i][j], 0, 0, 0);
    }
    // per-row max (across both n-halves)
#pragma unroll
    for (int i = 0; i < 4; i++)
#pragma unroll
        for (int r = 0; r < 4; r++) {
            const int row = wm + i * 16 + q * 4 + r;
            float mx = -3.0e38f;
#pragma unroll
            for (int j = 0; j < 8; j++) mx = fmaxf(mx, acc[i][j][r]);
            mx = fmaxf(mx, __shfl_xor(mx, 1)); mx = fmaxf(mx, __shfl_xor(mx, 2));
            mx = fmaxf(mx, __shfl_xor(mx, 4)); mx = fmaxf(mx, __shfl_xor(mx, 8));
            if (cl == 0) mx2[wid & 1][row] = mx;
        }
    __syncthreads();
#pragma unroll
    for (int i = 0; i < 4; i++)
#pragma unroll
        for (int r = 0; r < 4; r++) {
            const int row = wm + i * 16 + q * 4 + r;
            const float cc = diag_l[row] + fmaxf(mx2[0][row], mx2[1][row]);
#pragma unroll
            for (int j = 0; j < 8; j++) {
                const int col = wn + j * 16 + cl;
                const float v = 0.0625f * (__expf(acc[i][j][r] - cc) + 1.0e-4f);
                qfb[((size_t)(bb * NH + h) * NSEQ + (nloc + row)) * FF + col] = f2bf(v);
            }
        }
}

// ---------- key features GEMM (fp32 out + global max) ----------
__global__ __launch_bounds__(256)
void feat_k(const ushort_t* __restrict__ kb_, const ushort_t* __restrict__ projb,
            float* __restrict__ ddk, unsigned* __restrict__ mk_u)
{
    __shared__ alignas(16) ushort_t As[8192];
    __shared__ alignas(16) ushort_t Bs[8192];
    __shared__ float red[256];
    const int tid = threadIdx.x;
    const int f0 = blockIdx.x * 128, m0 = blockIdx.y * 128, h = blockIdx.z;
    const ushort_t* Am = kb_ + (size_t)m0 * DIMM + h * 64;

    floatx4 zero = {0.f, 0.f, 0.f, 0.f};
    floatx4 acc[4][4];
#pragma unroll
    for (int i = 0; i < 4; i++)
#pragma unroll
        for (int j = 0; j < 4; j++) acc[i][j] = zero;

    mfma_mainloop(Am, projb + (size_t)f0 * 64, As, Bs, DIMM, 64, 64, acc, tid);

    const int lane = tid & 63, wid = tid >> 6;
    const int q = lane >> 4, c = lane & 15;
    const int wm = (wid >> 1) * 64, wn = (wid & 1) * 64;
    const int bb = m0 >> 11;
    float mloc = -3.0e38f;
#pragma unroll
    for (int i = 0; i < 4; i++)
#pragma unroll
        for (int j = 0; j < 4; j++) {
            const int f = f0 + wn + j * 16 + c;
#pragma unroll
            for (int r = 0; r < 4; r++) {
                const int row = m0 + wm + i * 16 + q * 4 + r;
                const int nn = row & 2047;
                const float v = acc[i][j][r];
                mloc = fmaxf(mloc, v);
                ddk[((size_t)(bb * NH + h) * NSEQ + nn) * FF + f] = v;
            }
        }
    red[tid] = mloc;
    __syncthreads();
    for (int s = 128; s > 0; s >>= 1) {
        if (tid < s) red[tid] = fmaxf(red[tid], red[tid + s]);
        __syncthreads();
    }
    if (tid == 0) atomicMax(&mk_u[bb * NH + h], enc_f(red[0]));
}

// ---------- key exp: kfb = ratio*(exp(ddk - diag - m)+eps) bf16 ----------
__global__ __launch_bounds__(256)
void exp_k(const float* __restrict__ ddk, const ushort_t* __restrict__ kb_,
           const unsigned* __restrict__ mk_u, ushort_t* __restrict__ kfb)
{
    const int tid = threadIdx.x, lane = tid & 63;
    const int row = blockIdx.x * 4 + (tid >> 6);
    const int bh = row >> 11, n = row & 2047;
    const int bb = bh >> 3, h = bh & 7;
    const float qv = bf2f(kb_[(size_t)(bb * NSEQ + n) * DIMM + h * 64 + lane]);
    float ss = qv * qv;
#pragma unroll
    for (int off = 32; off > 0; off >>= 1) ss += __shfl_xor(ss, off);
    const float cc = ss * 0.0625f + dec_f(mk_u[bh]);

    float4 d4 = *(const float4*)(ddk + (size_t)row * FF + lane * 4);
    union { ushort4 v4; unsigned short s[4]; } pk;
    pk.s[0] = f2bf(0.0625f * (__expf(d4.x - cc) + 1.0e-4f));
    pk.s[1] = f2bf(0.0625f * (__expf(d4.y - cc) + 1.0e-4f));
    pk.s[2] = f2bf(0.0625f * (__expf(d4.z - cc) + 1.0e-4f));
    pk.s[3] = f2bf(0.0625f * (__expf(d4.w - cc) + 1.0e-4f));
    *(ushort4*)(kfb + (size_t)row * FF + lane * 4) = pk.v4;
}

// ---------- vb [n][dim] -> vTb [bh][e][n] ----------
__global__ __launch_bounds__(256)
void transpose_v(const ushort_t* __restrict__ vb, ushort_t* __restrict__ vTb)
{
    __shared__ ushort_t t[64][68];
    const int tid = threadIdx.x;
    const int n0 = blockIdx.x * 64, bh = blockIdx.y;
    const int bb = bh >> 3, h = bh & 7;
#pragma unroll
    for (int p = 0; p < 4; p++) {
        const int idx = p * 256 + tid;
        const int row = idx >> 4, c4 = idx & 15;
        ushort4 w = *(const ushort4*)(vb + ((size_t)(bb * NSEQ + n0 + row)) * DIMM + h * 64 + c4 * 4);
        t[c4 * 4 + 0][row] = w.x; t[c4 * 4 + 1][row] = w.y;
        t[c4 * 4 + 2][row] = w.z; t[c4 * 4 + 3][row] = w.w;
    }
    __syncthreads();
#pragma unroll
    for (int p = 0; p < 4; p++) {
        const int idx = p * 256 + tid;
        const int e = idx >> 4, n4 = idx & 15;
        ushort4 o = *(const ushort4*)&t[e][n4 * 4];
        *(ushort4*)(vTb + ((size_t)(bh * 64 + e)) * NSEQ + n0 + n4 * 4) = o;
    }
}

// ---------- kfb [bh][n][f] -> kfTb [bh][f][n] + per-chunk Ksum ----------
__global__ __launch_bounds__(256)
void transpose_kf(const ushort_t* __restrict__ kfb, ushort_t* __restrict__ kfTb,
                  float* __restrict__ Ksum)
{
    __shared__ ushort_t t[64][136];
    __shared__ float red[4][64];
    const int tid = threadIdx.x;
    const int f0 = blockIdx.x * 64, c = blockIdx.y, bh = blockIdx.z;
    const int n0 = c * CHK;
#pragma unroll
    for (int p = 0; p < 8; p++) {
        const int idx = p * 256 + tid;
        const int row = idx >> 4, c4 = idx & 15;
        ushort4 w = *(const ushort4*)(kfb + ((size_t)(bh * NSEQ + n0 + row)) * FF + f0 + c4 * 4);
        t[c4 * 4 + 0][row] = w.x; t[c4 * 4 + 1][row] = w.y;
        t[c4 * 4 + 2][row] = w.z; t[c4 * 4 + 3][row] = w.w;
    }
    __syncthreads();
    {
        const int f = tid & 63, grp = tid >> 6;
        float s = 0.f;
#pragma unroll
        for (int n = 0; n < 32; n++) s += bf2f(t[f][grp * 32 + n]);
        red[grp][f] = s;
    }
    __syncthreads();
    if (tid < 64)
        Ksum[((size_t)bh * NCHK + c) * FF + f0 + tid] =
            red[0][tid] + red[1][tid] + red[2][tid] + red[3][tid];
#pragma unroll
    for (int p = 0; p < 8; p++) {
        const int idx = p * 256 + tid;
        const int f = idx >> 5, n4 = idx & 31;
        ushort4 o = *(const ushort4*)&t[f][n4 * 4];
        *(ushort4*)(kfTb + ((size_t)(bh * FF + f0 + f)) * NSEQ + n0 + n4 * 4) = o;
    }
}

// ---------- CTXT[bh][c][e][f] = sum_n vT[e][n] kfT[f][n]  (= S^T per chunk) ----------
__global__ __launch_bounds__(256)
void ctx_mfma(const ushort_t* __restrict__ vTb, const ushort_t* __restrict__ kfTb,
              float* __restrict__ CTXT)
{
    __shared__ alignas(16) ushort_t As[4096];    // 64 rows x 64k
    __shared__ alignas(16) ushort_t Bs[16384];   // 256 rows x 64k
    const int tid = threadIdx.x, lane = tid & 63, wid = tid >> 6;
    const int q = lane >> 4, cl = lane & 15;
    const int bh = blockIdx.x >> 4, c = blockIdx.x & 15;
    const ushort_t* A = vTb + ((size_t)bh * 64) * NSEQ + c * CHK;
    const ushort_t* B = kfTb + ((size_t)bh * FF) * NSEQ + c * CHK;
    const int fw = wid * 64;

    floatx4 zero = {0.f, 0.f, 0.f, 0.f};
    floatx4 acc[4][4];
#pragma unroll
    for (int i = 0; i < 4; i++)
#pragma unroll
        for (int j = 0; j < 4; j++) acc[i][j] = zero;

    for (int k0 = 0; k0 < CHK; k0 += 64) {
#pragma unroll
        for (int t = 0; t < 2; t++) {
            const int g = t * 256 + tid, r = g >> 3, kb = (g & 7) ^ (r & 7);
            gload16(A + (size_t)r * NSEQ + k0 + kb * 8, As + (size_t)g * 8);
        }
#pragma unroll
        for (int t = 0; t < 8; t++) {
            const int g = t * 256 + tid, r = g >> 3, kb = (g & 7) ^ (r & 7);
            gload16(B + (size_t)r * NSEQ + k0 + kb * 8, Bs + (size_t)g * 8);
        }
        __syncthreads();
#pragma unroll
        for (int ks = 0; ks < 2; ks++) {
            bf16x8 af[4], bfr[4];
#pragma unroll
            for (int i = 0; i < 4; i++) {
                af[i]  = frag8(As, i * 16 + cl, ks * 4 + q);
                bfr[i] = frag8(Bs, fw + i * 16 + cl, ks * 4 + q);
            }
#pragma unroll
            for (int i = 0; i < 4; i++)
#pragma unroll
                for (int j = 0; j < 4; j++)
                    acc[i][j] = __builtin_amdgcn_mfma_f32_16x16x32_bf16(
                        af[i], bfr[j], acc[i][j], 0, 0, 0);
        }
        __syncthreads();
    }
#pragma unroll
    for (int i = 0; i < 4; i++)
#pragma unroll
        for (int j = 0; j < 4; j++) {
            const int f = fw + j * 16 + cl;
#pragma unroll
            for (int r = 0; r < 4; r++) {
                const int e = i * 16 + q * 4 + r;
                CTXT[(((size_t)bh * NCHK + c) * 64 + e) * FF + f] = acc[i][j][r];
            }
        }
}

// ---------- exclusive prefix over chunks ----------
__global__ void prefix_z(float* __restrict__ Ksum, float* __restrict__ Zout) {
    const int idx = blockIdx.x * 256 + threadIdx.x;   // 16*256
    const int bh = idx >> 8, f = idx & 255;
    float run = 0.f;
#pragma unroll
    for (int c = 0; c < NCHK; c++) {
        const size_t o = ((size_t)(bh * NCHK + c)) * FF + f;
        const float t = Ksum[o];
        Ksum[o] = run;
        run += t;
    }
    Zout[(size_t)bh * FF + f] = run;
}
__global__ void prefix_s2(const float* __restrict__ CTXT, ushort_t* __restrict__ ctxp,
                          float* __restrict__ Sout) {
    const int idx = blockIdx.x * 256 + threadIdx.x;   // 1024*256
    const int bh = idx >> 14, ef = idx & 16383;
    const int e = ef >> 8, f = ef & 255;
    float run = 0.f;
#pragma unroll
    for (int c = 0; c < NCHK; c++) {
        const size_t o = (((size_t)bh * NCHK + c) * 64 + e) * FF + f;
        const float t = CTXT[o];
        ctxp[o] = f2bf(run);
        run += t;
    }
    Sout[((size_t)bh * FF + f) * 64 + e] = run;   // S[b,h,f,e]
}

// ---------- chunk output, full MFMA ----------
__global__ __launch_bounds__(256)
void chunk_out_mfma(const ushort_t* __restrict__ qfb, const ushort_t* __restrict__ kfb,
                    const ushort_t* __restrict__ vTb, const float* __restrict__ Zex,
                    const ushort_t* __restrict__ ctxp, ushort_t* __restrict__ attnb)
{
    __shared__ alignas(16) ushort_t Sld[16384];  // 32 KB: S (128x128) / out-tile reuse
    __shared__ alignas(16) ushort_t As[8192];    // 16 KB
    __shared__ alignas(16) ushort_t Bs[8192];    // 16 KB
    __shared__ float zeps[256];
    __shared__ float rows_part[2][128];
    __shared__ float denp[256];
    __shared__ float den_l[128];

    const int tid = threadIdx.x, lane = tid & 63, wid = tid >> 6;
    const int q = lane >> 4, cl = lane & 15;
    const int bh = blockIdx.x >> 4, c = blockIdx.x & 15;
    const int bb = bh >> 3, h = bh & 7;
    const int n0 = c * CHK;
    const ushort_t* Q  = qfb + ((size_t)bh * NSEQ + n0) * FF;
    const ushort_t* Kf = kfb + ((size_t)bh * NSEQ + n0) * FF;

    zeps[tid] = Zex[((size_t)bh * NCHK + c) * FF + tid] + 1.0e-6f;

    // ---- stage 1: S = Q @ Kf^T (K=256), wave-grid 2x2 ----
    floatx4 zero = {0.f, 0.f, 0.f, 0.f};
    floatx4 acc1[4][4];
#pragma unroll
    for (int i = 0; i < 4; i++)
#pragma unroll
        for (int j = 0; j < 4; j++) acc1[i][j] = zero;
    const int wm = (wid >> 1) * 64, wn = (wid & 1) * 64;
    for (int k0 = 0; k0 < FF; k0 += 64) {
#pragma unroll
        for (int t = 0; t < 4; t++) {
            const int g = t * 256 + tid, r = g >> 3, kb = (g & 7) ^ (r & 7);
            gload16(Q + (size_t)r * FF + k0 + kb * 8, As + (size_t)g * 8);
        }
#pragma unroll
        for (int t = 0; t < 4; t++) {
            const int g = t * 256 + tid, r = g >> 3, kb = (g & 7) ^ (r & 7);
            gload16(Kf + (size_t)r * FF + k0 + kb * 8, Bs + (size_t)g * 8);
        }
        __syncthreads();
#pragma unroll
        for (int ks = 0; ks < 2; ks++) {
            bf16x8 af[4], bfr[4];
#pragma unroll
            for (int i = 0; i < 4; i++) {
                af[i]  = frag8(As, wm + i * 16 + cl, ks * 4 + q);
                bfr[i] = frag8(Bs, wn + i * 16 + cl, ks * 4 + q);
            }
#pragma unroll
            for (int i = 0; i < 4; i++)
#pragma unroll
                for (int j = 0; j < 4; j++)
                    acc1[i][j] = __builtin_amdgcn_mfma_f32_16x16x32_bf16(
                        af[i], bfr[j], acc1[i][j], 0, 0, 0);
        }
        __syncthreads();
    }
    // ---- causal mask + rowsum(fp32) + S -> LDS (bf16, swizzled granules) ----
#pragma unroll
    for (int i = 0; i < 4; i++)
#pragma unroll
        for (int r = 0; r < 4; r++) {
            const int row = wm + i * 16 + q * 4 + r;
            float part = 0.f;
#pragma unroll
            for (int j = 0; j < 4; j++) {
                const int col = wn + j * 16 + cl;
                const float v = (col <= row) ? acc1[i][j][r] : 0.f;
                part += v;
                Sld[(row * 16 + ((col >> 3) ^ (row & 15))) * 8 + (col & 7)] = f2bf(v);
            }
            part += __shfl_xor(part, 1); part += __shfl_xor(part, 2);
            part += __shfl_xor(part, 4); part += __shfl_xor(part, 8);
            if (cl == 0) rows_part[wid & 1][row] = part;
        }
    __syncthreads();

    // ---- stage 3: acc2[e][row] += vT (x) S  (K = 128 seq) ----
    floatx4 acc2[4][2];
#pragma unroll
    for (int i = 0; i < 4; i++)
#pragma unroll
        for (int j = 0; j < 2; j++) acc2[i][j] = zero;
    const ushort_t* Vt = vTb + ((size_t)bh * 64) * NSEQ + n0;
    for (int k0 = 0; k0 < CHK; k0 += 64) {
#pragma unroll
        for (int t = 0; t < 2; t++) {
            const int g = t * 256 + tid, r = g >> 3, kb = (g & 7) ^ (r & 7);
            gload16(Vt + (size_t)r * NSEQ + k0 + kb * 8, As + (size_t)g * 8);
        }
        __syncthreads();
#pragma unroll
        for (int ks = 0; ks < 2; ks++) {
            bf16x8 af[4], bfr[2];
            const int kbS = (k0 >> 3) + ks * 4 + q;
#pragma unroll
            for (int i = 0; i < 4; i++) af[i] = frag8(As, i * 16 + cl, ks * 4 + q);
#pragma unroll
            for (int j = 0; j < 2; j++) bfr[j] = fragS(Sld, wid * 32 + j * 16 + cl, kbS);
#pragma unroll
            for (int i = 0; i < 4; i++)
#pragma unroll
                for (int j = 0; j < 2; j++)
                    acc2[i][j] = __builtin_amdgcn_mfma_f32_16x16x32_bf16(
                        af[i], bfr[j], acc2[i][j], 0, 0, 0);
        }
        __syncthreads();
    }

    // ---- stage 4: acc2 += ctxp (x) Q  (K = 256 features); den from staged Q ----
    const ushort_t* Cp = ctxp + ((size_t)bh * NCHK + c) * 64 * FF;
    float dacc = 0.f;
    const int drow = tid & 127, dhalf = tid >> 7;
    for (int k0 = 0; k0 < FF; k0 += 64) {
#pragma unroll
        for (int t = 0; t < 2; t++) {
            const int g = t * 256 + tid, r = g >> 3, kb = (g & 7) ^ (r & 7);
            gload16(Cp + (size_t)r * FF + k0 + kb * 8, As + (size_t)g * 8);
        }
#pragma unroll
        for (int t = 0; t < 4; t++) {
            const int g = t * 256 + tid, r = g >> 3, kb = (g & 7) ^ (r & 7);
            gload16(Q + (size_t)r * FF + k0 + kb * 8, Bs + (size_t)g * 8);
        }
        __syncthreads();
#pragma unroll
        for (int ks = 0; ks < 2; ks++) {
            bf16x8 af[4], bfr[2];
#pragma unroll
            for (int i = 0; i < 4; i++) af[i] = frag8(As, i * 16 + cl, ks * 4 + q);
#pragma unroll
            for (int j = 0; j < 2; j++) bfr[j] = frag8(Bs, wid * 32 + j * 16 + cl, ks * 4 + q);
#pragma unroll
            for (int i = 0; i < 4; i++)
#pragma unroll
                for (int j = 0; j < 2; j++)
                    acc2[i][j] = __builtin_amdgcn_mfma_f32_16x16x32_bf16(
                        af[i], bfr[j], acc2[i][j], 0, 0, 0);
        }
        // den partial: this thread's row, its 32-feature half of this k-step
#pragma unroll
        for (int gi = 0; gi < 4; gi++) {
            const int kb = dhalf * 4 + gi;                         // global granule
            const ushort_t* gp = Bs + ((size_t)drow * 8 + (kb ^ (drow & 7))) * 8;
            const int kbase = k0 + kb * 8;
#pragma unroll
            for (int e2 = 0; e2 < 8; e2++)
                dacc = fmaf(bf2f(gp[e2]), zeps[kbase + e2], dacc);
        }
        __syncthreads();
    }
    denp[tid] = dacc;
    __syncthreads();
    if (tid < 128)
        den_l[tid] = rows_part[0][tid] + rows_part[1][tid] + denp[tid] + denp[tid + 128];
    __syncthreads();

    // ---- epilogue: divide, transpose via LDS, coalesced bf16 store ----
#pragma unroll
    for (int j = 0; j < 2; j++) {
        const int row = wid * 32 + j * 16 + cl;
        const float dinv = 1.0f / den_l[row];
#pragma unroll
        for (int i = 0; i < 4; i++)
#pragma unroll
            for (int r = 0; r < 4; r++) {
                const int e = i * 16 + q * 4 + r;
                Sld[row * 68 + e] = f2bf(acc2[i][j][r] * dinv);
            }
    }
    __syncthreads();
#pragma unroll
    for (int p = 0; p < 8; p++) {
        const int idx = p * 256 + tid;
        const int row = idx >> 4, e4 = idx & 15;
        ushort4 o = *(const ushort4*)&Sld[row * 68 + e4 * 4];
        *(ushort4*)(attnb + ((size_t)(bb * NSEQ + n0 + row)) * DIMM + h * 64 + e4 * 4) = o;
    }
}

// ---------- conversions ----------
__global__ void conv_x(const float* __restrict__ x, ushort_t* __restrict__ xb) {
    const int gid = blockIdx.x * 256 + threadIdx.x;
    const float4 v = *(const float4*)(x + (size_t)gid * 4);
    union { ushort4 v4; unsigned short s[4]; } pk;
    pk.s[0] = f2bf(v.x); pk.s[1] = f2bf(v.y); pk.s[2] = f2bf(v.z); pk.s[3] = f2bf(v.w);
    ((ushort4*)xb)[gid] = pk.v4;
}
__global__ void conv_proj(const float* __restrict__ proj, ushort_t* __restrict__ projb) {
    const int gid = blockIdx.x * 256 + threadIdx.x;
    const float dn = 0.35355339059327379f;   // 64^-0.25 folded into proj
    const float4 v = *(const float4*)(proj + (size_t)gid * 4);
    union { ushort4 v4; unsigned short s[4]; } pk;
    pk.s[0] = f2bf(v.x * dn); pk.s[1] = f2bf(v.y * dn);
    pk.s[2] = f2bf(v.z * dn); pk.s[3] = f2bf(v.w * dn);
    ((ushort4*)projb)[gid] = pk.v4;
}
__global__ void transpose_w(const float* __restrict__ W0, const float* __restrict__ W1,
                            const float* __restrict__ W2, const float* __restrict__ W3,
                            ushort_t* __restrict__ T0, ushort_t* __restrict__ T1,
                            ushort_t* __restrict__ T2, ushort_t* __restrict__ T3)
{
    __shared__ float t[32][33];
    const int z = blockIdx.z;
    const float* W = (z == 0) ? W0 : (z == 1) ? W1 : (z == 2) ? W2 : W3;
    ushort_t* T = (z == 0) ? T0 : (z == 1) ? T1 : (z == 2) ? T2 : T3;
    const int x0 = blockIdx.x * 32, y0 = blockIdx.y * 32;
    const int tx = threadIdx.x, ty = threadIdx.y;
#pragma unroll
    for (int i = 0; i < 4; i++)
        t[ty + i * 8][tx] = W[(size_t)(y0 + ty + i * 8) * DIMM + x0 + tx];
    __syncthreads();
#pragma unroll
    for (int i = 0; i < 4; i++)
        T[(size_t)(x0 + ty + i * 8) * DIMM + y0 + tx] = f2bf(t[tx][ty + i * 8]);
}

extern "C" void kernel_launch(void* const* d_in, const int* in_sizes, int n_in,
                              void* d_out, int out_size, void* d_ws, size_t ws_size,
                              hipStream_t stream)
{
    (void)in_sizes; (void)n_in; (void)out_size; (void)ws_size;
    const float* x    = (const float*)d_in[0];
    const float* proj = (const float*)d_in[1];
    const float* Wq   = (const float*)d_in[2];
    const float* Wk   = (const float*)d_in[3];
    const float* Wv   = (const float*)d_in[4];
    const float* Wo   = (const float*)d_in[5];
    const float* bo   = (const float*)d_in[6];
    float* out = (float*)d_out;

    // ---- workspace carve (~90.5 MB; round-1/2 used ~106 MB successfully) ----
    char* W = (char*)d_ws;
    float*    ddk  = (float*)W;              W += (size_t)33554432;   // [bh][n][f] fp32
    ushort_t* qfb  = (ushort_t*)W;           W += (size_t)16777216;   // [bh][n][f] bf16
    ushort_t* kfb  = (ushort_t*)W;           W += (size_t)16777216;
    ushort_t* qb   = (ushort_t*)W;           W += (size_t)4194304;    // [n][dim] bf16
    ushort_t* kb   = (ushort_t*)W;           W += (size_t)4194304;    // contiguous after qb
    ushort_t* vb   = (ushort_t*)W;           W += (size_t)4194304;
    ushort_t* xb   = (ushort_t*)W;           W += (size_t)4194304;    // reused as attnb
    ushort_t* vTb  = (ushort_t*)W;           W += (size_t)4194304;    // [bh][e][n]
    ushort_t* Wtq  = (ushort_t*)W;           W += (size_t)524288;
    ushort_t* Wtk  = (ushort_t*)W;           W += (size_t)524288;
    ushort_t* Wtv  = (ushort_t*)W;           W += (size_t)524288;
    ushort_t* Wto  = (ushort_t*)W;           W += (size_t)524288;
    ushort_t* projb = (ushort_t*)W;          W += (size_t)32768;
    float*    Ksum = (float*)W;              W += (size_t)262144;     // [bh][c][f]
    unsigned* mk_u = (unsigned*)W;           W += (size_t)256;

    // aliases (lifetime-disjoint)
    float*    CTXT = ddk;                                   // after exp_k
    ushort_t* kfTb = (ushort_t*)((char*)ddk + 16777216);    // after exp_k
    ushort_t* ctxp = qb;                                    // after feat_q/exp_k (qb+kb region)
    ushort_t* attnb = xb;                                   // after gemm_qkv

    float* Zout = out + (size_t)4096 * 512;
    float* Sout = Zout + (size_t)NBH * FF;

    hipLaunchKernelGGL(init_minmax, dim3(1), dim3(64), 0, stream, mk_u);
    hipLaunchKernelGGL(conv_x, dim3(2048), dim3(256), 0, stream, x, xb);
    hipLaunchKernelGGL(conv_proj, dim3(16), dim3(256), 0, stream, proj, projb);
    hipLaunchKernelGGL(transpose_w, dim3(16, 16, 4), dim3(32, 8), 0, stream,
                       Wq, Wk, Wv, Wo, Wtq, Wtk, Wtv, Wto);
    hipLaunchKernelGGL(gemm_qkv, dim3(4, 32, 3), dim3(256), 0, stream,
                       xb, Wtq, Wtk, Wtv, qb, kb, vb);
    hipLaunchKernelGGL(transpose_v, dim3(32, 16), dim3(256), 0, stream, vb, vTb);
    hipLaunchKernelGGL(feat_q, dim3(32, 8), dim3(256), 0, stream, qb, projb, qfb);
    hipLaunchKernelGGL(feat_k, dim3(2, 32, 8), dim3(256), 0, stream, kb, projb, ddk, mk_u);
    hipLaunchKernelGGL(exp_k, dim3(8192), dim3(256), 0, stream, ddk, kb, mk_u, kfb);
    hipLaunchKernelGGL(transpose_kf, dim3(4, 16, 16), dim3(256), 0, stream, kfb, kfTb, Ksum);
    hipLaunchKernelGGL(ctx_mfma, dim3(256), dim3(256), 0, stream, vTb, kfTb, CTXT);
    hipLaunchKernelGGL(prefix_z, dim3(16), dim3(256), 0, stream, Ksum, Zout);
    hipLaunchKernelGGL(prefix_s2, dim3(1024), dim3(256), 0, stream, CTXT, ctxp, Sout);
    hipLaunchKernelGGL(chunk_out_mfma, dim3(256), dim3(256), 0, stream,
                       qfb, kfb, vTb, Ksum, ctxp, attnb);
    hipLaunchKernelGGL(gemm_out, dim3(4, 32), dim3(256), 0, stream, attnb, Wto, out, bo);
}

// Round 5
// 168.600 us; speedup vs baseline: 2.5493x; 1.1009x over previous
//
#include <hip/hip_runtime.h>
#include <hip/hip_bf16.h>
#include <math.h>

// Problem constants (b=2, n=2048, dim=512, h=8, dh=64, f=256, chunk=128)
#define NB    2
#define NSEQ  2048
#define DIMM  512
#define NH    8
#define DHd   64
#define FF    256
#define CHK   128
#define NCHK  16
#define NBH   16   // NB*NH

typedef unsigned short ushort_t;
typedef __attribute__((ext_vector_type(8))) __bf16 bf16x8;
typedef __attribute__((ext_vector_type(4))) float floatx4;

__device__ __forceinline__ unsigned short f2bf(float x) {
    union { __hip_bfloat16 h; unsigned short u; } v;
    v.h = __float2bfloat16(x);
    return v.u;
}
__device__ __forceinline__ float bf2f(unsigned short u) {
    union { unsigned short u2[2]; float f; } v;
    v.u2[0] = 0; v.u2[1] = u;
    return v.f;
}
__device__ __forceinline__ unsigned enc_f(float x) {
    unsigned u = __float_as_uint(x);
    return (u & 0x80000000u) ? ~u : (u | 0x80000000u);
}
__device__ __forceinline__ float dec_f(unsigned e) {
    unsigned u = (e & 0x80000000u) ? (e & 0x7fffffffu) : ~e;
    return __uint_as_float(u);
}

__device__ __forceinline__ void gload16(const void* g, void* l) {
    __builtin_amdgcn_global_load_lds(
        (const __attribute__((address_space(1))) void*)g,
        (__attribute__((address_space(3))) void*)l, 16, 0, 0);
}

// frag read from a 64-k-step tile (8 granules/row, xor-swizzled)
__device__ __forceinline__ bf16x8 frag8(const ushort_t* lds, int row, int kb) {
    return *((const bf16x8*)lds + row * 8 + (kb ^ (row & 7)));
}
// frag read from the 128-k S tile (16 granules/row)
__device__ __forceinline__ bf16x8 fragS(const ushort_t* lds, int row, int kb) {
    return *((const bf16x8*)lds + row * 16 + (kb ^ (row & 15)));
}

// =====================================================================
// prep: init mk_u + conv x->bf16 + conv proj->bf16(*dn) + transpose W's
// grid.x ranges: [0,2048) conv_x | [2048,2064) conv_proj |
//                [2064,3088) transpose_w | 3088 init
// =====================================================================
__global__ __launch_bounds__(256)
void prep(const float* __restrict__ x, const float* __restrict__ proj,
          const float* __restrict__ W0, const float* __restrict__ W1,
          const float* __restrict__ W2, const float* __restrict__ W3,
          ushort_t* __restrict__ xb, ushort_t* __restrict__ projb,
          ushort_t* __restrict__ T0, ushort_t* __restrict__ T1,
          ushort_t* __restrict__ T2, ushort_t* __restrict__ T3,
          unsigned* __restrict__ mk_u)
{
    __shared__ float t[32][33];
    const int b = blockIdx.x, tid = threadIdx.x;
    if (b < 2048) {
        const int gid = b * 256 + tid;
        const float4 v = *(const float4*)(x + (size_t)gid * 4);
        union { ushort4 v4; unsigned short s[4]; } pk;
        pk.s[0] = f2bf(v.x); pk.s[1] = f2bf(v.y); pk.s[2] = f2bf(v.z); pk.s[3] = f2bf(v.w);
        ((ushort4*)xb)[gid] = pk.v4;
    } else if (b < 2064) {
        const int gid = (b - 2048) * 256 + tid;
        const float dn = 0.35355339059327379f;   // 64^-0.25 folded into proj
        const float4 v = *(const float4*)(proj + (size_t)gid * 4);
        union { ushort4 v4; unsigned short s[4]; } pk;
        pk.s[0] = f2bf(v.x * dn); pk.s[1] = f2bf(v.y * dn);
        pk.s[2] = f2bf(v.z * dn); pk.s[3] = f2bf(v.w * dn);
        ((ushort4*)projb)[gid] = pk.v4;
    } else if (b < 3088) {
        const int idx = b - 2064;                // 0..1023
        const int z = idx >> 8, rem = idx & 255;
        const int bx = rem & 15, by = rem >> 4;
        const float* W = (z == 0) ? W0 : (z == 1) ? W1 : (z == 2) ? W2 : W3;
        ushort_t* T = (z == 0) ? T0 : (z == 1) ? T1 : (z == 2) ? T2 : T3;
        const int x0 = bx * 32, y0 = by * 32;
        const int tx = tid & 31, ty = tid >> 5;  // 32 x 8
#pragma unroll
        for (int i = 0; i < 4; i++)
            t[ty + i * 8][tx] = W[(size_t)(y0 + ty + i * 8) * DIMM + x0 + tx];
        __syncthreads();
#pragma unroll
        for (int i = 0; i < 4; i++)
            T[(size_t)(x0 + ty + i * 8) * DIMM + y0 + tx] = f2bf(t[tx][ty + i * 8]);
    } else {
        if (tid < NBH) mk_u[tid] = 0u;
    }
}

// =====================================================================
// MFMA main loop: C[128x128] += A[128xK] * B[128xK]^T
// =====================================================================
__device__ __forceinline__ void mfma_mainloop(
    const ushort_t* __restrict__ AG, const ushort_t* __restrict__ BG,
    ushort_t* As, ushort_t* Bs, int ldA, int ldB, int K,
    floatx4 acc[4][4], int tid)
{
    const int lane = tid & 63, wid = tid >> 6;
    const int q = lane >> 4, c = lane & 15;
    const int wm = (wid >> 1) * 64, wn = (wid & 1) * 64;

    for (int k0 = 0; k0 < K; k0 += 64) {
#pragma unroll
        for (int t = 0; t < 4; t++) {
            const int g = t * 256 + tid, r = g >> 3, kb = (g & 7) ^ (r & 7);
            gload16(AG + (size_t)r * ldA + k0 + kb * 8, As + (size_t)g * 8);
        }
#pragma unroll
        for (int t = 0; t < 4; t++) {
            const int g = t * 256 + tid, r = g >> 3, kb = (g & 7) ^ (r & 7);
            gload16(BG + (size_t)r * ldB + k0 + kb * 8, Bs + (size_t)g * 8);
        }
        __syncthreads();
#pragma unroll
        for (int ks = 0; ks < 2; ks++) {
            bf16x8 af[4], bfr[4];
#pragma unroll
            for (int i = 0; i < 4; i++) {
                af[i]  = frag8(As, wm + i * 16 + c, ks * 4 + q);
                bfr[i] = frag8(Bs, wn + i * 16 + c, ks * 4 + q);
            }
#pragma unroll
            for (int i = 0; i < 4; i++)
#pragma unroll
                for (int j = 0; j < 4; j++)
                    acc[i][j] = __builtin_amdgcn_mfma_f32_16x16x32_bf16(
                        af[i], bfr[j], acc[i][j], 0, 0, 0);
        }
        __syncthreads();
    }
}

// ---------- QKV projection: z=0 -> qb, z=1 -> kb, z=2 -> vTb (LDS-transposed) ----------
__global__ __launch_bounds__(256)
void gemm_qkv(const ushort_t* __restrict__ xb,
              const ushort_t* __restrict__ Wtq, const ushort_t* __restrict__ Wtk,
              const ushort_t* __restrict__ Wtv,
              ushort_t* __restrict__ qb, ushort_t* __restrict__ kb,
              ushort_t* __restrict__ vTb)
{
    __shared__ alignas(16) ushort_t SM[16640];   // As/Bs (2x8192) and v-transpose (128x130)
    ushort_t* As = SM;
    ushort_t* Bs = SM + 8192;
    const int tid = threadIdx.x;
    const int n0 = blockIdx.x * 128, m0 = blockIdx.y * 128, z = blockIdx.z;
    const ushort_t* Bt = (z == 0) ? Wtq : ((z == 1) ? Wtk : Wtv);

    floatx4 zero = {0.f, 0.f, 0.f, 0.f};
    floatx4 acc[4][4];
#pragma unroll
    for (int i = 0; i < 4; i++)
#pragma unroll
        for (int j = 0; j < 4; j++) acc[i][j] = zero;

    mfma_mainloop(xb + (size_t)m0 * DIMM, Bt + (size_t)n0 * DIMM, As, Bs,
                  DIMM, DIMM, DIMM, acc, tid);

    const int lane = tid & 63, wid = tid >> 6;
    const int q = lane >> 4, c = lane & 15;
    const int wm = (wid >> 1) * 64, wn = (wid & 1) * 64;
    if (z < 2) {
        ushort_t* ob = (z == 0) ? qb : kb;
#pragma unroll
        for (int i = 0; i < 4; i++)
#pragma unroll
            for (int j = 0; j < 4; j++) {
                const int col = n0 + wn + j * 16 + c;
#pragma unroll
                for (int r = 0; r < 4; r++) {
                    const int row = m0 + wm + i * 16 + q * 4 + r;
                    ob[(size_t)row * DIMM + col] = f2bf(acc[i][j][r]);
                }
            }
    } else {
        // v: write C tile to LDS then emit vTb[bh][e][n] coalesced
#pragma unroll
        for (int i = 0; i < 4; i++)
#pragma unroll
            for (int j = 0; j < 4; j++) {
                const int col = wn + j * 16 + c;
#pragma unroll
                for (int r = 0; r < 4; r++) {
                    const int row = wm + i * 16 + q * 4 + r;
                    SM[row * 130 + col] = f2bf(acc[i][j][r]);
                }
            }
        __syncthreads();
        const int bb = m0 >> 11, nbase = m0 & 2047;
        // FULL 128x128 tile: 16 passes x 256 threads x 4 elems = 16384
#pragma unroll
        for (int p = 0; p < 16; p++) {
            const int idx = p * 256 + tid;
            const int cl2 = idx >> 5, n4 = idx & 31;   // cl2: local dim col (0..127), n4: 4-row group (0..31)
            const int C = n0 + cl2;
            const int h = C >> 6, e = C & 63;
            union { ushort4 v4; unsigned short s[4]; } pk;
#pragma unroll
            for (int k = 0; k < 4; k++) pk.s[k] = SM[(n4 * 4 + k) * 130 + cl2];
            *(ushort4*)(vTb + (((size_t)(bb * NH + h) * 64 + e)) * NSEQ + nbase + n4 * 4) = pk.v4;
        }
    }
}

// ---------- output projection ----------
__global__ __launch_bounds__(256)
void gemm_out(const ushort_t* __restrict__ attnb, const ushort_t* __restrict__ Wto,
              float* __restrict__ out, const float* __restrict__ bias)
{
    __shared__ alignas(16) ushort_t As[8192];
    __shared__ alignas(16) ushort_t Bs[8192];
    const int tid = threadIdx.x;
    const int n0 = blockIdx.x * 128, m0 = blockIdx.y * 128;

    floatx4 zero = {0.f, 0.f, 0.f, 0.f};
    floatx4 acc[4][4];
#pragma unroll
    for (int i = 0; i < 4; i++)
#pragma unroll
        for (int j = 0; j < 4; j++) acc[i][j] = zero;

    mfma_mainloop(attnb + (size_t)m0 * DIMM, Wto + (size_t)n0 * DIMM, As, Bs,
                  DIMM, DIMM, DIMM, acc, tid);

    const int lane = tid & 63, wid = tid >> 6;
    const int q = lane >> 4, c = lane & 15;
    const int wm = (wid >> 1) * 64, wn = (wid & 1) * 64;
#pragma unroll
    for (int i = 0; i < 4; i++)
#pragma unroll
        for (int j = 0; j < 4; j++) {
            const int col = n0 + wn + j * 16 + c;
            const float bv = bias[col];
#pragma unroll
            for (int r = 0; r < 4; r++) {
                const int row = m0 + wm + i * 16 + q * 4 + r;
                out[(size_t)row * DIMM + col] = acc[i][j][r] + bv;
            }
        }
}

// =====================================================================
// feat_qk: dd = (q|k head-slice) @ (dn proj)^T, K=64, 128n x 256f per block.
//  z=0 (query): exp-normalize in-block (per-row max + diag), write qfb bf16
//  z=1 (key):   write ddk fp32 + per-(b,h) atomicMax
// =====================================================================
__global__ __launch_bounds__(256)
void feat_qk(const ushort_t* __restrict__ qb_, const ushort_t* __restrict__ kb_,
             const ushort_t* __restrict__ projb,
             ushort_t* __restrict__ qfb, float* __restrict__ ddk,
             unsigned* __restrict__ mk_u)
{
    __shared__ alignas(16) ushort_t As[8192];    // 128 rows x 64k
    __shared__ alignas(16) ushort_t Bs[16384];   // 256 rows x 64k
    __shared__ float dtmp[256];
    __shared__ float diag_l[128];
    __shared__ float mx2[2][128];
    __shared__ float red[256];
    const int tid = threadIdx.x, lane = tid & 63, wid = tid >> 6;
    const int q = lane >> 4, cl = lane & 15;
    const int m0 = blockIdx.x * 128, h = blockIdx.y, src = blockIdx.z;
    const int bb = m0 >> 11, nloc = m0 & 2047;
    const ushort_t* Aq = (src ? kb_ : qb_) + (size_t)m0 * DIMM + h * 64;

    if (src == 0) {
        // diag[row] = sum(q^2)/16 (from the same bf16 q the GEMM uses)
        const int row = tid >> 1, half = tid & 1;
        float s = 0.f;
        const ushort_t* p = Aq + (size_t)row * DIMM + half * 32;
#pragma unroll
        for (int d = 0; d < 32; d += 4) {
            ushort4 w = *(const ushort4*)(p + d);
            float a = bf2f(w.x), b2 = bf2f(w.y), c2 = bf2f(w.z), d2 = bf2f(w.w);
            s += a * a + b2 * b2 + c2 * c2 + d2 * d2;
        }
        dtmp[tid] = s;
        __syncthreads();
        if (tid < 128) diag_l[tid] = (dtmp[tid * 2] + dtmp[tid * 2 + 1]) * 0.0625f;
    }

    floatx4 zero = {0.f, 0.f, 0.f, 0.f};
    floatx4 acc[4][8];
#pragma unroll
    for (int i = 0; i < 4; i++)
#pragma unroll
        for (int j = 0; j < 8; j++) acc[i][j] = zero;

    const int wm = (wid >> 1) * 64, wn = (wid & 1) * 128;
    // K = 64: single staging step
#pragma unroll
    for (int t = 0; t < 4; t++) {
        const int g = t * 256 + tid, r = g >> 3, kb = (g & 7) ^ (r & 7);
        gload16(Aq + (size_t)r * DIMM + kb * 8, As + (size_t)g * 8);
    }
#pragma unroll
    for (int t = 0; t < 8; t++) {
        const int g = t * 256 + tid, r = g >> 3, kb = (g & 7) ^ (r & 7);
        gload16(projb + (size_t)r * 64 + kb * 8, Bs + (size_t)g * 8);
    }
    __syncthreads();
#pragma unroll
    for (int ks = 0; ks < 2; ks++) {
        bf16x8 af[4], bfr[8];
#pragma unroll
        for (int i = 0; i < 4; i++) af[i] = frag8(As, wm + i * 16 + cl, ks * 4 + q);
#pragma unroll
        for (int j = 0; j < 8; j++) bfr[j] = frag8(Bs, wn + j * 16 + cl, ks * 4 + q);
#pragma unroll
        for (int i = 0; i < 4; i++)
#pragma unroll
            for (int j = 0; j < 8; j++)
                acc[i][j] = __builtin_amdgcn_mfma_f32_16x16x32_bf16(
                    af[i], bfr[j], acc[i][j], 0, 0, 0);
    }

    if (src == 0) {
        // per-row max across both n-halves, then exp-normalize and emit qfb
#pragma unroll
        for (int i = 0; i < 4; i++)
#pragma unroll
            for (int r = 0; r < 4; r++) {
                const int row = wm + i * 16 + q * 4 + r;
                float mx = -3.0e38f;
#pragma unroll
                for (int j = 0; j < 8; j++) mx = fmaxf(mx, acc[i][j][r]);
                mx = fmaxf(mx, __shfl_xor(mx, 1)); mx = fmaxf(mx, __shfl_xor(mx, 2));
                mx = fmaxf(mx, __shfl_xor(mx, 4)); mx = fmaxf(mx, __shfl_xor(mx, 8));
                if (cl == 0) mx2[wid & 1][row] = mx;
            }
        __syncthreads();
#pragma unroll
        for (int i = 0; i < 4; i++)
#pragma unroll
            for (int r = 0; r < 4; r++) {
                const int row = wm + i * 16 + q * 4 + r;
                const float cc = diag_l[row] + fmaxf(mx2[0][row], mx2[1][row]);
#pragma unroll
                for (int j = 0; j < 8; j++) {
                    const int col = wn + j * 16 + cl;
                    const float v = 0.0625f * (__expf(acc[i][j][r] - cc) + 1.0e-4f);
                    qfb[((size_t)(bb * NH + h) * NSEQ + (nloc + row)) * FF + col] = f2bf(v);
                }
            }
    } else {
        float mloc = -3.0e38f;
#pragma unroll
        for (int i = 0; i < 4; i++)
#pragma unroll
            for (int j = 0; j < 8; j++) {
                const int f = wn + j * 16 + cl;
#pragma unroll
                for (int r = 0; r < 4; r++) {
                    const int row = wm + i * 16 + q * 4 + r;
                    const float v = acc[i][j][r];
                    mloc = fmaxf(mloc, v);
                    ddk[((size_t)(bb * NH + h) * NSEQ + (nloc + row)) * FF + f] = v;
                }
            }
        red[tid] = mloc;
        __syncthreads();
        for (int s = 128; s > 0; s >>= 1) {
            if (tid < s) red[tid] = fmaxf(red[tid], red[tid + s]);
            __syncthreads();
        }
        if (tid == 0) atomicMax(&mk_u[bb * NH + h], enc_f(red[0]));
    }
}

// =====================================================================
// exp_tk: kf = ratio*(exp(ddk - diag - m)+eps); write kfb [n][f],
//         kfTb [f][n], and per-chunk Ksum. 64f x 128n per block.
// =====================================================================
__global__ __launch_bounds__(256)
void exp_tk(const float* __restrict__ ddk, const ushort_t* __restrict__ kb_,
            const unsigned* __restrict__ mk_u,
            ushort_t* __restrict__ kfb, ushort_t* __restrict__ kfTb,
            float* __restrict__ Ksum)
{
    __shared__ ushort_t t[64][136];
    __shared__ float red[4][64];
    __shared__ float dtmp[256];
    __shared__ float diag_l[128];
    const int tid = threadIdx.x;
    const int f0 = blockIdx.x * 64, c = blockIdx.y, bh = blockIdx.z;
    const int bb = bh >> 3, h = bh & 7;
    const int n0 = c * CHK;
    const float m = dec_f(mk_u[bh]);

    // diag for this block's 128 rows
    {
        const int row = tid >> 1, half = tid & 1;
        float s = 0.f;
        const ushort_t* p = kb_ + (size_t)(bb * NSEQ + n0 + row) * DIMM + h * 64 + half * 32;
#pragma unroll
        for (int d = 0; d < 32; d += 4) {
            ushort4 w = *(const ushort4*)(p + d);
            float a = bf2f(w.x), b2 = bf2f(w.y), c2 = bf2f(w.z), d2 = bf2f(w.w);
            s += a * a + b2 * b2 + c2 * c2 + d2 * d2;
        }
        dtmp[tid] = s;
    }
    __syncthreads();
    if (tid < 128) diag_l[tid] = (dtmp[tid * 2] + dtmp[tid * 2 + 1]) * 0.0625f;
    __syncthreads();

#pragma unroll
    for (int p = 0; p < 8; p++) {
        const int idx = p * 256 + tid;
        const int row = idx >> 4, c4 = idx & 15;
        const float4 d4 = *(const float4*)(ddk + ((size_t)(bh * NSEQ + n0 + row)) * FF + f0 + c4 * 4);
        const float cc = diag_l[row] + m;
        union { ushort4 v4; unsigned short s[4]; } pk;
        pk.s[0] = f2bf(0.0625f * (__expf(d4.x - cc) + 1.0e-4f));
        pk.s[1] = f2bf(0.0625f * (__expf(d4.y - cc) + 1.0e-4f));
        pk.s[2] = f2bf(0.0625f * (__expf(d4.z - cc) + 1.0e-4f));
        pk.s[3] = f2bf(0.0625f * (__expf(d4.w - cc) + 1.0e-4f));
        *(ushort4*)(kfb + ((size_t)(bh * NSEQ + n0 + row)) * FF + f0 + c4 * 4) = pk.v4;
        t[c4 * 4 + 0][row] = pk.s[0]; t[c4 * 4 + 1][row] = pk.s[1];
        t[c4 * 4 + 2][row] = pk.s[2]; t[c4 * 4 + 3][row] = pk.s[3];
    }
    __syncthreads();
    {
        const int f = tid & 63, grp = tid >> 6;
        float s = 0.f;
#pragma unroll
        for (int n = 0; n < 32; n++) s += bf2f(t[f][grp * 32 + n]);
        red[grp][f] = s;
    }
    __syncthreads();
    if (tid < 64)
        Ksum[((size_t)bh * NCHK + c) * FF + f0 + tid] =
            red[0][tid] + red[1][tid] + red[2][tid] + red[3][tid];
#pragma unroll
    for (int p = 0; p < 8; p++) {
        const int idx = p * 256 + tid;
        const int f = idx >> 5, n4 = idx & 31;
        ushort4 o = *(const ushort4*)&t[f][n4 * 4];
        *(ushort4*)(kfTb + ((size_t)(bh * FF + f0 + f)) * NSEQ + n0 + n4 * 4) = o;
    }
}

// ---------- CTXT[bh][c][e][f] = sum_n vT[e][n] kfT[f][n]  (= S^T per chunk) ----------
__global__ __launch_bounds__(256)
void ctx_mfma(const ushort_t* __restrict__ vTb, const ushort_t* __restrict__ kfTb,
              float* __restrict__ CTXT)
{
    __shared__ alignas(16) ushort_t As[4096];    // 64 rows x 64k
    __shared__ alignas(16) ushort_t Bs[16384];   // 256 rows x 64k
    const int tid = threadIdx.x, lane = tid & 63, wid = tid >> 6;
    const int q = lane >> 4, cl = lane & 15;
    const int bh = blockIdx.x >> 4, c = blockIdx.x & 15;
    const ushort_t* A = vTb + ((size_t)bh * 64) * NSEQ + c * CHK;
    const ushort_t* B = kfTb + ((size_t)bh * FF) * NSEQ + c * CHK;
    const int fw = wid * 64;

    floatx4 zero = {0.f, 0.f, 0.f, 0.f};
    floatx4 acc[4][4];
#pragma unroll
    for (int i = 0; i < 4; i++)
#pragma unroll
        for (int j = 0; j < 4; j++) acc[i][j] = zero;

    for (int k0 = 0; k0 < CHK; k0 += 64) {
#pragma unroll
        for (int t = 0; t < 2; t++) {
            const int g = t * 256 + tid, r = g >> 3, kb = (g & 7) ^ (r & 7);
            gload16(A + (size_t)r * NSEQ + k0 + kb * 8, As + (size_t)g * 8);
        }
#pragma unroll
        for (int t = 0; t < 8; t++) {
            const int g = t * 256 + tid, r = g >> 3, kb = (g & 7) ^ (r & 7);
            gload16(B + (size_t)r * NSEQ + k0 + kb * 8, Bs + (size_t)g * 8);
        }
        __syncthreads();
#pragma unroll
        for (int ks = 0; ks < 2; ks++) {
            bf16x8 af[4], bfr[4];
#pragma unroll
            for (int i = 0; i < 4; i++) {
                af[i]  = frag8(As, i * 16 + cl, ks * 4 + q);
                bfr[i] = frag8(Bs, fw + i * 16 + cl, ks * 4 + q);
            }
#pragma unroll
            for (int i = 0; i < 4; i++)
#pragma unroll
                for (int j = 0; j < 4; j++)
                    acc[i][j] = __builtin_amdgcn_mfma_f32_16x16x32_bf16(
                        af[i], bfr[j], acc[i][j], 0, 0, 0);
        }
        __syncthreads();
    }
#pragma unroll
    for (int i = 0; i < 4; i++)
#pragma unroll
        for (int j = 0; j < 4; j++) {
            const int f = fw + j * 16 + cl;
#pragma unroll
            for (int r = 0; r < 4; r++) {
                const int e = i * 16 + q * 4 + r;
                CTXT[(((size_t)bh * NCHK + c) * 64 + e) * FF + f] = acc[i][j][r];
            }
        }
}

// ---------- merged exclusive prefixes: blocks [0,1024) S-path, [1024,1040) Z-path ----------
__global__ void prefix_zs(float* __restrict__ Ksum, float* __restrict__ Zout,
                          const float* __restrict__ CTXT, ushort_t* __restrict__ ctxp,
                          float* __restrict__ Sout)
{
    const int b = blockIdx.x;
    if (b < 1024) {
        const int idx = b * 256 + threadIdx.x;
        const int bh = idx >> 14, ef = idx & 16383;
        const int e = ef >> 8, f = ef & 255;
        float run = 0.f;
#pragma unroll
        for (int c = 0; c < NCHK; c++) {
            const size_t o = (((size_t)bh * NCHK + c) * 64 + e) * FF + f;
            const float t = CTXT[o];
            ctxp[o] = f2bf(run);
            run += t;
        }
        Sout[((size_t)bh * FF + f) * 64 + e] = run;   // S[b,h,f,e]
    } else {
        const int idx = (b - 1024) * 256 + threadIdx.x;
        const int bh = idx >> 8, f = idx & 255;
        float run = 0.f;
#pragma unroll
        for (int c = 0; c < NCHK; c++) {
            const size_t o = ((size_t)(bh * NCHK + c)) * FF + f;
            const float t = Ksum[o];
            Ksum[o] = run;
            run += t;
        }
        Zout[(size_t)bh * FF + f] = run;
    }
}

// ---------- chunk output, full MFMA ----------
__global__ __launch_bounds__(256)
void chunk_out_mfma(const ushort_t* __restrict__ qfb, const ushort_t* __restrict__ kfb,
                    const ushort_t* __restrict__ vTb, const float* __restrict__ Zex,
                    const ushort_t* __restrict__ ctxp, ushort_t* __restrict__ attnb)
{
    __shared__ alignas(16) ushort_t Sld[16384];  // 32 KB: S (128x128) / out-tile reuse
    __shared__ alignas(16) ushort_t As[8192];    // 16 KB
    __shared__ alignas(16) ushort_t Bs[8192];    // 16 KB
    __shared__ float zeps[256];
    __shared__ float rows_part[2][128];
    __shared__ float denp[256];
    __shared__ float den_l[128];

    const int tid = threadIdx.x, lane = tid & 63, wid = tid >> 6;
    const int q = lane >> 4, cl = lane & 15;
    const int bh = blockIdx.x >> 4, c = blockIdx.x & 15;
    const int bb = bh >> 3, h = bh & 7;
    const int n0 = c * CHK;
    const ushort_t* Q  = qfb + ((size_t)bh * NSEQ + n0) * FF;
    const ushort_t* Kf = kfb + ((size_t)bh * NSEQ + n0) * FF;

    zeps[tid] = Zex[((size_t)bh * NCHK + c) * FF + tid] + 1.0e-6f;

    // ---- stage 1: S = Q @ Kf^T (K=256), wave-grid 2x2 ----
    floatx4 zero = {0.f, 0.f, 0.f, 0.f};
    floatx4 acc1[4][4];
#pragma unroll
    for (int i = 0; i < 4; i++)
#pragma unroll
        for (int j = 0; j < 4; j++) acc1[i][j] = zero;
    const int wm = (wid >> 1) * 64, wn = (wid & 1) * 64;
    for (int k0 = 0; k0 < FF; k0 += 64) {
#pragma unroll
        for (int t = 0; t < 4; t++) {
            const int g = t * 256 + tid, r = g >> 3, kb = (g & 7) ^ (r & 7);
            gload16(Q + (size_t)r * FF + k0 + kb * 8, As + (size_t)g * 8);
        }
#pragma unroll
        for (int t = 0; t < 4; t++) {
            const int g = t * 256 + tid, r = g >> 3, kb = (g & 7) ^ (r & 7);
            gload16(Kf + (size_t)r * FF + k0 + kb * 8, Bs + (size_t)g * 8);
        }
        __syncthreads();
#pragma unroll
        for (int ks = 0; ks < 2; ks++) {
            bf16x8 af[4], bfr[4];
#pragma unroll
            for (int i = 0; i < 4; i++) {
                af[i]  = frag8(As, wm + i * 16 + cl, ks * 4 + q);
                bfr[i] = frag8(Bs, wn + i * 16 + cl, ks * 4 + q);
            }
#pragma unroll
            for (int i = 0; i < 4; i++)
#pragma unroll
                for (int j = 0; j < 4; j++)
                    acc1[i][j] = __builtin_amdgcn_mfma_f32_16x16x32_bf16(
                        af[i], bfr[j], acc1[i][j], 0, 0, 0);
        }
        __syncthreads();
    }
    // ---- causal mask + rowsum(fp32) + S -> LDS (bf16, swizzled granules) ----
#pragma unroll
    for (int i = 0; i < 4; i++)
#pragma unroll
        for (int r = 0; r < 4; r++) {
            const int row = wm + i * 16 + q * 4 + r;
            float part = 0.f;
#pragma unroll
            for (int j = 0; j < 4; j++) {
                const int col = wn + j * 16 + cl;
                const float v = (col <= row) ? acc1[i][j][r] : 0.f;
                part += v;
                Sld[(row * 16 + ((col >> 3) ^ (row & 15))) * 8 + (col & 7)] = f2bf(v);
            }
            part += __shfl_xor(part, 1); part += __shfl_xor(part, 2);
            part += __shfl_xor(part, 4); part += __shfl_xor(part, 8);
            if (cl == 0) rows_part[wid & 1][row] = part;
        }
    __syncthreads();

    // ---- stage 3: acc2[e][row] += vT (x) S  (K = 128 seq) ----
    floatx4 acc2[4][2];
#pragma unroll
    for (int i = 0; i < 4; i++)
#pragma unroll
        for (int j = 0; j < 2; j++) acc2[i][j] = zero;
    const ushort_t* Vt = vTb + ((size_t)bh * 64) * NSEQ + n0;
    for (int k0 = 0; k0 < CHK; k0 += 64) {
#pragma unroll
        for (int t = 0; t < 2; t++) {
            const int g = t * 256 + tid, r = g >> 3, kb = (g & 7) ^ (r & 7);
            gload16(Vt + (size_t)r * NSEQ + k0 + kb * 8, As + (size_t)g * 8);
        }
        __syncthreads();
#pragma unroll
        for (int ks = 0; ks < 2; ks++) {
            bf16x8 af[4], bfr[2];
            const int kbS = (k0 >> 3) + ks * 4 + q;
#pragma unroll
            for (int i = 0; i < 4; i++) af[i] = frag8(As, i * 16 + cl, ks * 4 + q);
#pragma unroll
            for (int j = 0; j < 2; j++) bfr[j] = fragS(Sld, wid * 32 + j * 16 + cl, kbS);
#pragma unroll
            for (int i = 0; i < 4; i++)
#pragma unroll
                for (int j = 0; j < 2; j++)
                    acc2[i][j] = __builtin_amdgcn_mfma_f32_16x16x32_bf16(
                        af[i], bfr[j], acc2[i][j], 0, 0, 0);
        }
        __syncthreads();
    }

    // ---- stage 4: acc2 += ctxp (x) Q  (K = 256 features); den from staged Q ----
    const ushort_t* Cp = ctxp + ((size_t)bh * NCHK + c) * 64 * FF;
    float dacc = 0.f;
    const int drow = tid & 127, dhalf = tid >> 7;
    for (int k0 = 0; k0 < FF; k0 += 64) {
#pragma unroll
        for (int t = 0; t < 2; t++) {
            const int g = t * 256 + tid, r = g >> 3, kb = (g & 7) ^ (r & 7);
            gload16(Cp + (size_t)r * FF + k0 + kb * 8, As + (size_t)g * 8);
        }
#pragma unroll
        for (int t = 0; t < 4; t++) {
            const int g = t * 256 + tid, r = g >> 3, kb = (g & 7) ^ (r & 7);
            gload16(Q + (size_t)r * FF + k0 + kb * 8, Bs + (size_t)g * 8);
        }
        __syncthreads();
#pragma unroll
        for (int ks = 0; ks < 2; ks++) {
            bf16x8 af[4], bfr[2];
#pragma unroll
            for (int i = 0; i < 4; i++) af[i] = frag8(As, i * 16 + cl, ks * 4 + q);
#pragma unroll
            for (int j = 0; j < 2; j++) bfr[j] = frag8(Bs, wid * 32 + j * 16 + cl, ks * 4 + q);
#pragma unroll
            for (int i = 0; i < 4; i++)
#pragma unroll
                for (int j = 0; j < 2; j++)
                    acc2[i][j] = __builtin_amdgcn_mfma_f32_16x16x32_bf16(
                        af[i], bfr[j], acc2[i][j], 0, 0, 0);
        }
        // den partial: this thread's row, its 32-feature half of this k-step
#pragma unroll
        for (int gi = 0; gi < 4; gi++) {
            const int kb = dhalf * 4 + gi;
            const ushort_t* gp = Bs + ((size_t)drow * 8 + (kb ^ (drow & 7))) * 8;
            const int kbase = k0 + kb * 8;
#pragma unroll
            for (int e2 = 0; e2 < 8; e2++)
                dacc = fmaf(bf2f(gp[e2]), zeps[kbase + e2], dacc);
        }
        __syncthreads();
    }
    denp[tid] = dacc;
    __syncthreads();
    if (tid < 128)
        den_l[tid] = rows_part[0][tid] + rows_part[1][tid] + denp[tid] + denp[tid + 128];
    __syncthreads();

    // ---- epilogue: divide, transpose via LDS, coalesced bf16 store ----
#pragma unroll
    for (int j = 0; j < 2; j++) {
        const int row = wid * 32 + j * 16 + cl;
        const float dinv = 1.0f / den_l[row];
#pragma unroll
        for (int i = 0; i < 4; i++)
#pragma unroll
            for (int r = 0; r < 4; r++) {
                const int e = i * 16 + q * 4 + r;
                Sld[row * 68 + e] = f2bf(acc2[i][j][r] * dinv);
            }
    }
    __syncthreads();
#pragma unroll
    for (int p = 0; p < 8; p++) {
        const int idx = p * 256 + tid;
        const int row = idx >> 4, e4 = idx & 15;
        ushort4 o = *(const ushort4*)&Sld[row * 68 + e4 * 4];
        *(ushort4*)(attnb + ((size_t)(bb * NSEQ + n0 + row)) * DIMM + h * 64 + e4 * 4) = o;
    }
}

extern "C" void kernel_launch(void* const* d_in, const int* in_sizes, int n_in,
                              void* d_out, int out_size, void* d_ws, size_t ws_size,
                              hipStream_t stream)
{
    (void)in_sizes; (void)n_in; (void)out_size; (void)ws_size;
    const float* x    = (const float*)d_in[0];
    const float* proj = (const float*)d_in[1];
    const float* Wq   = (const float*)d_in[2];
    const float* Wk   = (const float*)d_in[3];
    const float* Wv   = (const float*)d_in[4];
    const float* Wo   = (const float*)d_in[5];
    const float* bo   = (const float*)d_in[6];
    float* out = (float*)d_out;

    // ---- workspace carve (~103 MB) ----
    char* W = (char*)d_ws;
    float*    ddk  = (float*)W;              W += (size_t)33554432;   // [bh][n][f] fp32
    ushort_t* kfTb = (ushort_t*)W;           W += (size_t)16777216;   // [bh][f][n] bf16
    ushort_t* qfb  = (ushort_t*)W;           W += (size_t)16777216;   // [bh][n][f] bf16
    ushort_t* kfb  = (ushort_t*)W;           W += (size_t)16777216;
    ushort_t* qb   = (ushort_t*)W;           W += (size_t)4194304;    // [n][dim] bf16
    ushort_t* kb   = (ushort_t*)W;           W += (size_t)4194304;    // contiguous after qb
    ushort_t* xb   = (ushort_t*)W;           W += (size_t)4194304;    // reused as attnb
    ushort_t* vTb  = (ushort_t*)W;           W += (size_t)4194304;    // [bh][e][n]
    ushort_t* Wtq  = (ushort_t*)W;           W += (size_t)524288;
    ushort_t* Wtk  = (ushort_t*)W;           W += (size_t)524288;
    ushort_t* Wtv  = (ushort_t*)W;           W += (size_t)524288;
    ushort_t* Wto  = (ushort_t*)W;           W += (size_t)524288;
    ushort_t* projb = (ushort_t*)W;          W += (size_t)32768;
    float*    Ksum = (float*)W;              W += (size_t)262144;     // [bh][c][f]
    unsigned* mk_u = (unsigned*)W;           W += (size_t)256;

    // aliases (lifetime-disjoint)
    float*    CTXT = ddk;          // ctx_mfma writes after exp_tk consumed ddk
    ushort_t* ctxp = qb;           // prefix writes bf16 prefix into qb+kb (8.4 MB), dead by then
    ushort_t* attnb = xb;          // xb dead after gemm_qkv

    float* Zout = out + (size_t)4096 * 512;
    float* Sout = Zout + (size_t)NBH * FF;

    hipLaunchKernelGGL(prep, dim3(3089), dim3(256), 0, stream,
                       x, proj, Wq, Wk, Wv, Wo, xb, projb, Wtq, Wtk, Wtv, Wto, mk_u);
    hipLaunchKernelGGL(gemm_qkv, dim3(4, 32, 3), dim3(256), 0, stream,
                       xb, Wtq, Wtk, Wtv, qb, kb, vTb);
    hipLaunchKernelGGL(feat_qk, dim3(32, 8, 2), dim3(256), 0, stream,
                       qb, kb, projb, qfb, ddk, mk_u);
    hipLaunchKernelGGL(exp_tk, dim3(4, 16, 16), dim3(256), 0, stream,
                       ddk, kb, mk_u, kfb, kfTb, Ksum);
    hipLaunchKernelGGL(ctx_mfma, dim3(256), dim3(256), 0, stream, vTb, kfTb, CTXT);
    hipLaunchKernelGGL(prefix_zs, dim3(1040), dim3(256), 0, stream,
                       Ksum, Zout, CTXT, ctxp, Sout);
    hipLaunchKernelGGL(chunk_out_mfma, dim3(256), dim3(256), 0, stream,
                       qfb, kfb, vTb, Ksum, ctxp, attnb);
    hipLaunchKernelGGL(gemm_out, dim3(4, 32), dim3(256), 0, stream, attnb, Wto, out, bo);
}

// Round 6
// 165.710 us; speedup vs baseline: 2.5938x; 1.0174x over previous
//
#include <hip/hip_runtime.h>
#include <hip/hip_bf16.h>
#include <math.h>

// Problem constants (b=2, n=2048, dim=512, h=8, dh=64, f=256, chunk=128)
#define NB    2
#define NSEQ  2048
#define DIMM  512
#define NH    8
#define DHd   64
#define FF    256
#define CHK   128
#define NCHK  16
#define NBH   16   // NB*NH

typedef unsigned short ushort_t;
typedef __attribute__((ext_vector_type(8))) __bf16 bf16x8;
typedef __attribute__((ext_vector_type(4))) float floatx4;

__device__ __forceinline__ unsigned short f2bf(float x) {
    union { __hip_bfloat16 h; unsigned short u; } v;
    v.h = __float2bfloat16(x);
    return v.u;
}
__device__ __forceinline__ float bf2f(unsigned short u) {
    union { unsigned short u2[2]; float f; } v;
    v.u2[0] = 0; v.u2[1] = u;
    return v.f;
}
__device__ __forceinline__ unsigned enc_f(float x) {
    unsigned u = __float_as_uint(x);
    return (u & 0x80000000u) ? ~u : (u | 0x80000000u);
}
__device__ __forceinline__ float dec_f(unsigned e) {
    unsigned u = (e & 0x80000000u) ? (e & 0x7fffffffu) : ~e;
    return __uint_as_float(u);
}

__device__ __forceinline__ void gload16(const void* g, void* l) {
    __builtin_amdgcn_global_load_lds(
        (const __attribute__((address_space(1))) void*)g,
        (__attribute__((address_space(3))) void*)l, 16, 0, 0);
}

// frag read from a 64-k-step tile (8 granules/row, xor-swizzled)
__device__ __forceinline__ bf16x8 frag8(const ushort_t* lds, int row, int kb) {
    return *((const bf16x8*)lds + row * 8 + (kb ^ (row & 7)));
}
// frag read from the 128-k S tile (16 granules/row)
__device__ __forceinline__ bf16x8 fragS(const ushort_t* lds, int row, int kb) {
    return *((const bf16x8*)lds + row * 16 + (kb ^ (row & 15)));
}

// =====================================================================
// prep: init mk_u + conv x->bf16 + conv proj->bf16(*dn) + transpose W's
// =====================================================================
__global__ __launch_bounds__(256)
void prep(const float* __restrict__ x, const float* __restrict__ proj,
          const float* __restrict__ W0, const float* __restrict__ W1,
          const float* __restrict__ W2, const float* __restrict__ W3,
          ushort_t* __restrict__ xb, ushort_t* __restrict__ projb,
          ushort_t* __restrict__ T0, ushort_t* __restrict__ T1,
          ushort_t* __restrict__ T2, ushort_t* __restrict__ T3,
          unsigned* __restrict__ mk_u)
{
    __shared__ float t[32][33];
    const int b = blockIdx.x, tid = threadIdx.x;
    if (b < 2048) {
        const int gid = b * 256 + tid;
        const float4 v = *(const float4*)(x + (size_t)gid * 4);
        union { ushort4 v4; unsigned short s[4]; } pk;
        pk.s[0] = f2bf(v.x); pk.s[1] = f2bf(v.y); pk.s[2] = f2bf(v.z); pk.s[3] = f2bf(v.w);
        ((ushort4*)xb)[gid] = pk.v4;
    } else if (b < 2064) {
        const int gid = (b - 2048) * 256 + tid;
        const float dn = 0.35355339059327379f;   // 64^-0.25 folded into proj
        const float4 v = *(const float4*)(proj + (size_t)gid * 4);
        union { ushort4 v4; unsigned short s[4]; } pk;
        pk.s[0] = f2bf(v.x * dn); pk.s[1] = f2bf(v.y * dn);
        pk.s[2] = f2bf(v.z * dn); pk.s[3] = f2bf(v.w * dn);
        ((ushort4*)projb)[gid] = pk.v4;
    } else if (b < 3088) {
        const int idx = b - 2064;                // 0..1023
        const int z = idx >> 8, rem = idx & 255;
        const int bx = rem & 15, by = rem >> 4;
        const float* W = (z == 0) ? W0 : (z == 1) ? W1 : (z == 2) ? W2 : W3;
        ushort_t* T = (z == 0) ? T0 : (z == 1) ? T1 : (z == 2) ? T2 : T3;
        const int x0 = bx * 32, y0 = by * 32;
        const int tx = tid & 31, ty = tid >> 5;  // 32 x 8
#pragma unroll
        for (int i = 0; i < 4; i++)
            t[ty + i * 8][tx] = W[(size_t)(y0 + ty + i * 8) * DIMM + x0 + tx];
        __syncthreads();
#pragma unroll
        for (int i = 0; i < 4; i++)
            T[(size_t)(x0 + ty + i * 8) * DIMM + y0 + tx] = f2bf(t[tx][ty + i * 8]);
    } else {
        if (tid < NBH) mk_u[tid] = 0u;
    }
}

// =====================================================================
// MFMA main loop: C[128x128] += A[128xK] * B[128xK]^T
// =====================================================================
__device__ __forceinline__ void mfma_mainloop(
    const ushort_t* __restrict__ AG, const ushort_t* __restrict__ BG,
    ushort_t* As, ushort_t* Bs, int ldA, int ldB, int K,
    floatx4 acc[4][4], int tid)
{
    const int lane = tid & 63, wid = tid >> 6;
    const int q = lane >> 4, c = lane & 15;
    const int wm = (wid >> 1) * 64, wn = (wid & 1) * 64;

    for (int k0 = 0; k0 < K; k0 += 64) {
#pragma unroll
        for (int t = 0; t < 4; t++) {
            const int g = t * 256 + tid, r = g >> 3, kb = (g & 7) ^ (r & 7);
            gload16(AG + (size_t)r * ldA + k0 + kb * 8, As + (size_t)g * 8);
        }
#pragma unroll
        for (int t = 0; t < 4; t++) {
            const int g = t * 256 + tid, r = g >> 3, kb = (g & 7) ^ (r & 7);
            gload16(BG + (size_t)r * ldB + k0 + kb * 8, Bs + (size_t)g * 8);
        }
        __syncthreads();
#pragma unroll
        for (int ks = 0; ks < 2; ks++) {
            bf16x8 af[4], bfr[4];
#pragma unroll
            for (int i = 0; i < 4; i++) {
                af[i]  = frag8(As, wm + i * 16 + c, ks * 4 + q);
                bfr[i] = frag8(Bs, wn + i * 16 + c, ks * 4 + q);
            }
#pragma unroll
            for (int i = 0; i < 4; i++)
#pragma unroll
                for (int j = 0; j < 4; j++)
                    acc[i][j] = __builtin_amdgcn_mfma_f32_16x16x32_bf16(
                        af[i], bfr[j], acc[i][j], 0, 0, 0);
        }
        __syncthreads();
    }
}

// ---------- QKV projection: z=0 -> qb, z=1 -> kb, z=2 -> vTb; ALL epilogues via LDS ----------
__global__ __launch_bounds__(256)
void gemm_qkv(const ushort_t* __restrict__ xb,
              const ushort_t* __restrict__ Wtq, const ushort_t* __restrict__ Wtk,
              const ushort_t* __restrict__ Wtv,
              ushort_t* __restrict__ qb, ushort_t* __restrict__ kb,
              ushort_t* __restrict__ vTb)
{
    __shared__ alignas(16) ushort_t SM[16896];   // As(8192)+Bs(8192) staging; reuse as tile[128][132]
    ushort_t* As = SM;
    ushort_t* Bs = SM + 8192;
    const int tid = threadIdx.x;
    const int n0 = blockIdx.x * 128, m0 = blockIdx.y * 128, z = blockIdx.z;
    const ushort_t* Bt = (z == 0) ? Wtq : ((z == 1) ? Wtk : Wtv);

    floatx4 zero = {0.f, 0.f, 0.f, 0.f};
    floatx4 acc[4][4];
#pragma unroll
    for (int i = 0; i < 4; i++)
#pragma unroll
        for (int j = 0; j < 4; j++) acc[i][j] = zero;

    mfma_mainloop(xb + (size_t)m0 * DIMM, Bt + (size_t)n0 * DIMM, As, Bs,
                  DIMM, DIMM, DIMM, acc, tid);

    const int lane = tid & 63, wid = tid >> 6;
    const int q = lane >> 4, c = lane & 15;
    const int wm = (wid >> 1) * 64, wn = (wid & 1) * 64;

    // C tile -> LDS (conflict-free: quads land on disjoint bank octets)
#pragma unroll
    for (int i = 0; i < 4; i++)
#pragma unroll
        for (int j = 0; j < 4; j++) {
            const int col = wn + j * 16 + c;
#pragma unroll
            for (int r = 0; r < 4; r++) {
                const int row = wm + i * 16 + q * 4 + r;
                SM[row * 132 + col] = f2bf(acc[i][j][r]);
            }
        }
    __syncthreads();

    if (z < 2) {
        ushort_t* ob = (z == 0) ? qb : kb;
#pragma unroll
        for (int p = 0; p < 16; p++) {
            const int idx = p * 256 + tid;
            const int row = idx >> 5, c4 = idx & 31;
            ushort4 o = *(const ushort4*)&SM[row * 132 + c4 * 4];
            *(ushort4*)(ob + (size_t)(m0 + row) * DIMM + n0 + c4 * 4) = o;
        }
    } else {
        const int bb = m0 >> 11, nbase = m0 & 2047;
#pragma unroll
        for (int p = 0; p < 16; p++) {
            const int idx = p * 256 + tid;
            const int cl2 = idx >> 5, n4 = idx & 31;
            const int C = n0 + cl2;
            const int h = C >> 6, e = C & 63;
            union { ushort4 v4; unsigned short s[4]; } pk;
#pragma unroll
            for (int k = 0; k < 4; k++) pk.s[k] = SM[(n4 * 4 + k) * 132 + cl2];
            *(ushort4*)(vTb + (((size_t)(bb * NH + h) * 64 + e)) * NSEQ + nbase + n4 * 4) = pk.v4;
        }
    }
}

// ---------- output projection ----------
__global__ __launch_bounds__(256)
void gemm_out(const ushort_t* __restrict__ attnb, const ushort_t* __restrict__ Wto,
              float* __restrict__ out, const float* __restrict__ bias)
{
    __shared__ alignas(16) ushort_t As[8192];
    __shared__ alignas(16) ushort_t Bs[8192];
    const int tid = threadIdx.x;
    const int n0 = blockIdx.x * 128, m0 = blockIdx.y * 128;

    floatx4 zero = {0.f, 0.f, 0.f, 0.f};
    floatx4 acc[4][4];
#pragma unroll
    for (int i = 0; i < 4; i++)
#pragma unroll
        for (int j = 0; j < 4; j++) acc[i][j] = zero;

    mfma_mainloop(attnb + (size_t)m0 * DIMM, Wto + (size_t)n0 * DIMM, As, Bs,
                  DIMM, DIMM, DIMM, acc, tid);

    const int lane = tid & 63, wid = tid >> 6;
    const int q = lane >> 4, c = lane & 15;
    const int wm = (wid >> 1) * 64, wn = (wid & 1) * 64;
#pragma unroll
    for (int i = 0; i < 4; i++)
#pragma unroll
        for (int j = 0; j < 4; j++) {
            const int col = n0 + wn + j * 16 + c;
            const float bv = bias[col];
#pragma unroll
            for (int r = 0; r < 4; r++) {
                const int row = m0 + wm + i * 16 + q * 4 + r;
                out[(size_t)row * DIMM + col] = acc[i][j][r] + bv;
            }
        }
}

// =====================================================================
// kmax: key features MFMA, per-(b,h) max only (no stores) -> atomicMax
// =====================================================================
__global__ __launch_bounds__(256)
void kmax(const ushort_t* __restrict__ kb_, const ushort_t* __restrict__ projb,
          unsigned* __restrict__ mk_u)
{
    __shared__ alignas(16) ushort_t As[8192];    // 128 rows x 64k
    __shared__ alignas(16) ushort_t Bs[16384];   // 256 rows x 64k
    __shared__ float red[256];
    const int tid = threadIdx.x, lane = tid & 63, wid = tid >> 6;
    const int q = lane >> 4, cl = lane & 15;
    const int m0 = blockIdx.x * 128, h = blockIdx.y;
    const int bb = m0 >> 11;
    const ushort_t* Aq = kb_ + (size_t)m0 * DIMM + h * 64;

#pragma unroll
    for (int t = 0; t < 4; t++) {
        const int g = t * 256 + tid, r = g >> 3, kb = (g & 7) ^ (r & 7);
        gload16(Aq + (size_t)r * DIMM + kb * 8, As + (size_t)g * 8);
    }
#pragma unroll
    for (int t = 0; t < 8; t++) {
        const int g = t * 256 + tid, r = g >> 3, kb = (g & 7) ^ (r & 7);
        gload16(projb + (size_t)r * 64 + kb * 8, Bs + (size_t)g * 8);
    }
    __syncthreads();

    floatx4 zero = {0.f, 0.f, 0.f, 0.f};
    floatx4 acc[4][8];
#pragma unroll
    for (int i = 0; i < 4; i++)
#pragma unroll
        for (int j = 0; j < 8; j++) acc[i][j] = zero;
    const int wm = (wid >> 1) * 64, wn = (wid & 1) * 128;
#pragma unroll
    for (int ks = 0; ks < 2; ks++) {
        bf16x8 af[4], bfr[8];
#pragma unroll
        for (int i = 0; i < 4; i++) af[i] = frag8(As, wm + i * 16 + cl, ks * 4 + q);
#pragma unroll
        for (int j = 0; j < 8; j++) bfr[j] = frag8(Bs, wn + j * 16 + cl, ks * 4 + q);
#pragma unroll
        for (int i = 0; i < 4; i++)
#pragma unroll
            for (int j = 0; j < 8; j++)
                acc[i][j] = __builtin_amdgcn_mfma_f32_16x16x32_bf16(
                    af[i], bfr[j], acc[i][j], 0, 0, 0);
    }
    float mloc = -3.0e38f;
#pragma unroll
    for (int i = 0; i < 4; i++)
#pragma unroll
        for (int j = 0; j < 8; j++)
#pragma unroll
            for (int r = 0; r < 4; r++) mloc = fmaxf(mloc, acc[i][j][r]);
    red[tid] = mloc;
    __syncthreads();
    for (int s = 128; s > 0; s >>= 1) {
        if (tid < s) red[tid] = fmaxf(red[tid], red[tid + s]);
        __syncthreads();
    }
    if (tid == 0) atomicMax(&mk_u[bb * NH + h], enc_f(red[0]));
}

// =====================================================================
// featx: recompute features, exp-normalize in-register, coalesced stores.
//  z=0 (query): per-row max + diag -> qfb [n][f]
//  z=1 (key):   global max (mk_u) + diag -> kfb [n][f], kfTb [f][n], Ksum
// m-tile (128 rows) == one chunk, so Ksum falls out per-block.
// =====================================================================
__global__ __launch_bounds__(256)
void featx(const ushort_t* __restrict__ qb_, const ushort_t* __restrict__ kb_,
           const ushort_t* __restrict__ projb, const unsigned* __restrict__ mk_u,
           ushort_t* __restrict__ qfb, ushort_t* __restrict__ kfb,
           ushort_t* __restrict__ kfTb, float* __restrict__ Ksum)
{
    __shared__ alignas(16) ushort_t SM[24576];   // As(8192)+Bs(16384); reused as tile[128][132]
    __shared__ float dtmp[256];
    __shared__ float diag_l[128];
    __shared__ float mx2[2][128];
    __shared__ float colp[2][256];
    ushort_t* As = SM;
    ushort_t* Bs = SM + 8192;
    const int tid = threadIdx.x, lane = tid & 63, wid = tid >> 6;
    const int q = lane >> 4, cl = lane & 15;
    const int m0 = blockIdx.x * 128, h = blockIdx.y, src = blockIdx.z;
    const int bb = m0 >> 11, nloc = m0 & 2047;
    const int bh = bb * NH + h;
    const int cidx = nloc >> 7;
    const ushort_t* Aq = (src ? kb_ : qb_) + (size_t)m0 * DIMM + h * 64;

    // diag[row] = sum(qk^2)/16 (from the same bf16 inputs the GEMM uses)
    {
        const int row = tid >> 1, half = tid & 1;
        float s = 0.f;
        const ushort_t* p = Aq + (size_t)row * DIMM + half * 32;
#pragma unroll
        for (int d = 0; d < 32; d += 4) {
            ushort4 w = *(const ushort4*)(p + d);
            float a = bf2f(w.x), b2 = bf2f(w.y), c2 = bf2f(w.z), d2 = bf2f(w.w);
            s += a * a + b2 * b2 + c2 * c2 + d2 * d2;
        }
        dtmp[tid] = s;
    }
    __syncthreads();
    if (tid < 128) diag_l[tid] = (dtmp[2 * tid] + dtmp[2 * tid + 1]) * 0.0625f;

    // stage A (128x64) and proj (256x64)
#pragma unroll
    for (int t = 0; t < 4; t++) {
        const int g = t * 256 + tid, r = g >> 3, kb = (g & 7) ^ (r & 7);
        gload16(Aq + (size_t)r * DIMM + kb * 8, As + (size_t)g * 8);
    }
#pragma unroll
    for (int t = 0; t < 8; t++) {
        const int g = t * 256 + tid, r = g >> 3, kb = (g & 7) ^ (r & 7);
        gload16(projb + (size_t)r * 64 + kb * 8, Bs + (size_t)g * 8);
    }
    __syncthreads();

    floatx4 zero = {0.f, 0.f, 0.f, 0.f};
    floatx4 acc[4][8];
#pragma unroll
    for (int i = 0; i < 4; i++)
#pragma unroll
        for (int j = 0; j < 8; j++) acc[i][j] = zero;
    const int wm = (wid >> 1) * 64, wn = (wid & 1) * 128;
#pragma unroll
    for (int ks = 0; ks < 2; ks++) {
        bf16x8 af[4], bfr[8];
#pragma unroll
        for (int i = 0; i < 4; i++) af[i] = frag8(As, wm + i * 16 + cl, ks * 4 + q);
#pragma unroll
        for (int j = 0; j < 8; j++) bfr[j] = frag8(Bs, wn + j * 16 + cl, ks * 4 + q);
#pragma unroll
        for (int i = 0; i < 4; i++)
#pragma unroll
            for (int j = 0; j < 8; j++)
                acc[i][j] = __builtin_amdgcn_mfma_f32_16x16x32_bf16(
                    af[i], bfr[j], acc[i][j], 0, 0, 0);
    }

    const float mk = src ? dec_f(mk_u[bh]) : 0.f;
    if (src == 0) {
        // per-row max (both f-halves, via LDS across wave pairs)
#pragma unroll
        for (int i = 0; i < 4; i++)
#pragma unroll
            for (int r = 0; r < 4; r++) {
                const int row = wm + i * 16 + q * 4 + r;
                float mx = -3.0e38f;
#pragma unroll
                for (int j = 0; j < 8; j++) mx = fmaxf(mx, acc[i][j][r]);
                mx = fmaxf(mx, __shfl_xor(mx, 1)); mx = fmaxf(mx, __shfl_xor(mx, 2));
                mx = fmaxf(mx, __shfl_xor(mx, 4)); mx = fmaxf(mx, __shfl_xor(mx, 8));
                if (cl == 0) mx2[wid & 1][row] = mx;
            }
    }
    __syncthreads();   // mx2/diag visible; all frag ds_reads complete (SM now reusable)

    // exp-normalize in place
#pragma unroll
    for (int i = 0; i < 4; i++)
#pragma unroll
        for (int r = 0; r < 4; r++) {
            const int row = wm + i * 16 + q * 4 + r;
            const float cc = diag_l[row] + (src ? mk : fmaxf(mx2[0][row], mx2[1][row]));
#pragma unroll
            for (int j = 0; j < 8; j++)
                acc[i][j][r] = 0.0625f * (__expf(acc[i][j][r] - cc) + 1.0e-4f);
        }

    // key: column sums from registers (quad shuffles), then Ksum after sync
    if (src) {
#pragma unroll
        for (int j = 0; j < 8; j++) {
            float s = 0.f;
#pragma unroll
            for (int i = 0; i < 4; i++)
                s += acc[i][j][0] + acc[i][j][1] + acc[i][j][2] + acc[i][j][3];
            s += __shfl_xor(s, 16);
            s += __shfl_xor(s, 32);
            if (q == 0) colp[wid >> 1][wn + j * 16 + cl] = s;
        }
    }

    ushort_t* ff = src ? kfb : qfb;
    const size_t frow = (size_t)bh * NSEQ + nloc;

#pragma unroll
    for (int hf = 0; hf < 2; hf++) {
        __syncthreads();   // colp visible (hf=0); prior stores done (hf=1)
        if ((wid & 1) == hf) {
#pragma unroll
            for (int i = 0; i < 4; i++)
#pragma unroll
                for (int j = 0; j < 8; j++) {
                    const int col = j * 16 + cl;
#pragma unroll
                    for (int r = 0; r < 4; r++) {
                        const int row = wm + i * 16 + q * 4 + r;
                        SM[row * 132 + col] = f2bf(acc[i][j][r]);
                    }
                }
        }
        if (hf == 0 && src) {
            Ksum[((size_t)bh * NCHK + cidx) * FF + tid] = colp[0][tid] + colp[1][tid];
        }
        __syncthreads();
        // coalesced [n][f] stores (ushort4, 256B per 32 lanes)
#pragma unroll
        for (int p = 0; p < 16; p++) {
            const int idx = p * 256 + tid;
            const int row = idx >> 5, c4 = idx & 31;
            ushort4 o = *(const ushort4*)&SM[row * 132 + c4 * 4];
            *(ushort4*)(ff + (frow + row) * FF + hf * 128 + c4 * 4) = o;
        }
        if (src) {
            // transposed [f][n] stores
#pragma unroll
            for (int p = 0; p < 16; p++) {
                const int idx = p * 256 + tid;
                const int f = idx >> 5, n4 = idx & 31;
                union { ushort4 v4; unsigned short s[4]; } pk;
#pragma unroll
                for (int k = 0; k < 4; k++) pk.s[k] = SM[(n4 * 4 + k) * 132 + f];
                *(ushort4*)(kfTb + ((size_t)bh * FF + hf * 128 + f) * NSEQ + nloc + n4 * 4) = pk.v4;
            }
        }
    }
}

// ---------- CTXT[bh][c][e][f] = sum_n vT[e][n] kfT[f][n]  (= S^T per chunk) ----------
__global__ __launch_bounds__(256)
void ctx_mfma(const ushort_t* __restrict__ vTb, const ushort_t* __restrict__ kfTb,
              float* __restrict__ CTXT)
{
    __shared__ alignas(16) ushort_t As[4096];    // 64 rows x 64k
    __shared__ alignas(16) ushort_t Bs[16384];   // 256 rows x 64k
    const int tid = threadIdx.x, lane = tid & 63, wid = tid >> 6;
    const int q = lane >> 4, cl = lane & 15;
    const int bh = blockIdx.x >> 4, c = blockIdx.x & 15;
    const ushort_t* A = vTb + ((size_t)bh * 64) * NSEQ + c * CHK;
    const ushort_t* B = kfTb + ((size_t)bh * FF) * NSEQ + c * CHK;
    const int fw = wid * 64;

    floatx4 zero = {0.f, 0.f, 0.f, 0.f};
    floatx4 acc[4][4];
#pragma unroll
    for (int i = 0; i < 4; i++)
#pragma unroll
        for (int j = 0; j < 4; j++) acc[i][j] = zero;

    for (int k0 = 0; k0 < CHK; k0 += 64) {
#pragma unroll
        for (int t = 0; t < 2; t++) {
            const int g = t * 256 + tid, r = g >> 3, kb = (g & 7) ^ (r & 7);
            gload16(A + (size_t)r * NSEQ + k0 + kb * 8, As + (size_t)g * 8);
        }
#pragma unroll
        for (int t = 0; t < 8; t++) {
            const int g = t * 256 + tid, r = g >> 3, kb = (g & 7) ^ (r & 7);
            gload16(B + (size_t)r * NSEQ + k0 + kb * 8, Bs + (size_t)g * 8);
        }
        __syncthreads();
#pragma unroll
        for (int ks = 0; ks < 2; ks++) {
            bf16x8 af[4], bfr[4];
#pragma unroll
            for (int i = 0; i < 4; i++) {
                af[i]  = frag8(As, i * 16 + cl, ks * 4 + q);
                bfr[i] = frag8(Bs, fw + i * 16 + cl, ks * 4 + q);
            }
#pragma unroll
            for (int i = 0; i < 4; i++)
#pragma unroll
                for (int j = 0; j < 4; j++)
                    acc[i][j] = __builtin_amdgcn_mfma_f32_16x16x32_bf16(
                        af[i], bfr[j], acc[i][j], 0, 0, 0);
        }
        __syncthreads();
    }
#pragma unroll
    for (int i = 0; i < 4; i++)
#pragma unroll
        for (int j = 0; j < 4; j++) {
            const int f = fw + j * 16 + cl;
#pragma unroll
            for (int r = 0; r < 4; r++) {
                const int e = i * 16 + q * 4 + r;
                CTXT[(((size_t)bh * NCHK + c) * 64 + e) * FF + f] = acc[i][j][r];
            }
        }
}

// ---------- merged exclusive prefixes: blocks [0,1024) S-path, [1024,1040) Z-path ----------
__global__ void prefix_zs(float* __restrict__ Ksum, float* __restrict__ Zout,
                          const float* __restrict__ CTXT, ushort_t* __restrict__ ctxp,
                          float* __restrict__ Sout)
{
    const int b = blockIdx.x;
    if (b < 1024) {
        const int idx = b * 256 + threadIdx.x;
        const int bh = idx >> 14, ef = idx & 16383;
        const int e = ef >> 8, f = ef & 255;
        float run = 0.f;
#pragma unroll
        for (int c = 0; c < NCHK; c++) {
            const size_t o = (((size_t)bh * NCHK + c) * 64 + e) * FF + f;
            const float t = CTXT[o];
            ctxp[o] = f2bf(run);
            run += t;
        }
        Sout[((size_t)bh * FF + f) * 64 + e] = run;   // S[b,h,f,e]
    } else {
        const int idx = (b - 1024) * 256 + threadIdx.x;
        const int bh = idx >> 8, f = idx & 255;
        float run = 0.f;
#pragma unroll
        for (int c = 0; c < NCHK; c++) {
            const size_t o = ((size_t)(bh * NCHK + c)) * FF + f;
            const float t = Ksum[o];
            Ksum[o] = run;
            run += t;
        }
        Zout[(size_t)bh * FF + f] = run;
    }
}

// ---------- chunk output, full MFMA ----------
__global__ __launch_bounds__(256)
void chunk_out_mfma(const ushort_t* __restrict__ qfb, const ushort_t* __restrict__ kfb,
                    const ushort_t* __restrict__ vTb, const float* __restrict__ Zex,
                    const ushort_t* __restrict__ ctxp, ushort_t* __restrict__ attnb)
{
    __shared__ alignas(16) ushort_t Sld[16384];  // 32 KB: S (128x128) / out-tile reuse
    __shared__ alignas(16) ushort_t As[8192];    // 16 KB
    __shared__ alignas(16) ushort_t Bs[8192];    // 16 KB
    __shared__ float zeps[256];
    __shared__ float rows_part[2][128];
    __shared__ float denp[256];
    __shared__ float den_l[128];

    const int tid = threadIdx.x, lane = tid & 63, wid = tid >> 6;
    const int q = lane >> 4, cl = lane & 15;
    const int bh = blockIdx.x >> 4, c = blockIdx.x & 15;
    const int bb = bh >> 3, h = bh & 7;
    const int n0 = c * CHK;
    const ushort_t* Q  = qfb + ((size_t)bh * NSEQ + n0) * FF;
    const ushort_t* Kf = kfb + ((size_t)bh * NSEQ + n0) * FF;

    zeps[tid] = Zex[((size_t)bh * NCHK + c) * FF + tid] + 1.0e-6f;

    // ---- stage 1: S = Q @ Kf^T (K=256), wave-grid 2x2 ----
    floatx4 zero = {0.f, 0.f, 0.f, 0.f};
    floatx4 acc1[4][4];
#pragma unroll
    for (int i = 0; i < 4; i++)
#pragma unroll
        for (int j = 0; j < 4; j++) acc1[i][j] = zero;
    const int wm = (wid >> 1) * 64, wn = (wid & 1) * 64;
    for (int k0 = 0; k0 < FF; k0 += 64) {
#pragma unroll
        for (int t = 0; t < 4; t++) {
            const int g = t * 256 + tid, r = g >> 3, kb = (g & 7) ^ (r & 7);
            gload16(Q + (size_t)r * FF + k0 + kb * 8, As + (size_t)g * 8);
        }
#pragma unroll
        for (int t = 0; t < 4; t++) {
            const int g = t * 256 + tid, r = g >> 3, kb = (g & 7) ^ (r & 7);
            gload16(Kf + (size_t)r * FF + k0 + kb * 8, Bs + (size_t)g * 8);
        }
        __syncthreads();
#pragma unroll
        for (int ks = 0; ks < 2; ks++) {
            bf16x8 af[4], bfr[4];
#pragma unroll
            for (int i = 0; i < 4; i++) {
                af[i]  = frag8(As, wm + i * 16 + cl, ks * 4 + q);
                bfr[i] = frag8(Bs, wn + i * 16 + cl, ks * 4 + q);
            }
#pragma unroll
            for (int i = 0; i < 4; i++)
#pragma unroll
                for (int j = 0; j < 4; j++)
                    acc1[i][j] = __builtin_amdgcn_mfma_f32_16x16x32_bf16(
                        af[i], bfr[j], acc1[i][j], 0, 0, 0);
        }
        __syncthreads();
    }
    // ---- causal mask + rowsum(fp32) + S -> LDS (bf16, swizzled granules) ----
#pragma unroll
    for (int i = 0; i < 4; i++)
#pragma unroll
        for (int r = 0; r < 4; r++) {
            const int row = wm + i * 16 + q * 4 + r;
            float part = 0.f;
#pragma unroll
            for (int j = 0; j < 4; j++) {
                const int col = wn + j * 16 + cl;
                const float v = (col <= row) ? acc1[i][j][r] : 0.f;
                part += v;
                Sld[(row * 16 + ((col >> 3) ^ (row & 15))) * 8 + (col & 7)] = f2bf(v);
            }
            part += __shfl_xor(part, 1); part += __shfl_xor(part, 2);
            part += __shfl_xor(part, 4); part += __shfl_xor(part, 8);
            if (cl == 0) rows_part[wid & 1][row] = part;
        }
    __syncthreads();

    // ---- stage 3: acc2[e][row] += vT (x) S  (K = 128 seq) ----
    floatx4 acc2[4][2];
#pragma unroll
    for (int i = 0; i < 4; i++)
#pragma unroll
        for (int j = 0; j < 2; j++) acc2[i][j] = zero;
    const ushort_t* Vt = vTb + ((size_t)bh * 64) * NSEQ + n0;
    for (int k0 = 0; k0 < CHK; k0 += 64) {
#pragma unroll
        for (int t = 0; t < 2; t++) {
            const int g = t * 256 + tid, r = g >> 3, kb = (g & 7) ^ (r & 7);
            gload16(Vt + (size_t)r * NSEQ + k0 + kb * 8, As + (size_t)g * 8);
        }
        __syncthreads();
#pragma unroll
        for (int ks = 0; ks < 2; ks++) {
            bf16x8 af[4], bfr[2];
            const int kbS = (k0 >> 3) + ks * 4 + q;
#pragma unroll
            for (int i = 0; i < 4; i++) af[i] = frag8(As, i * 16 + cl, ks * 4 + q);
#pragma unroll
            for (int j = 0; j < 2; j++) bfr[j] = fragS(Sld, wid * 32 + j * 16 + cl, kbS);
#pragma unroll
            for (int i = 0; i < 4; i++)
#pragma unroll
                for (int j = 0; j < 2; j++)
                    acc2[i][j] = __builtin_amdgcn_mfma_f32_16x16x32_bf16(
                        af[i], bfr[j], acc2[i][j], 0, 0, 0);
        }
        __syncthreads();
    }

    // ---- stage 4: acc2 += ctxp (x) Q  (K = 256 features); den from staged Q ----
    const ushort_t* Cp = ctxp + ((size_t)bh * NCHK + c) * 64 * FF;
    float dacc = 0.f;
    const int drow = tid & 127, dhalf = tid >> 7;
    for (int k0 = 0; k0 < FF; k0 += 64) {
#pragma unroll
        for (int t = 0; t < 2; t++) {
            const int g = t * 256 + tid, r = g >> 3, kb = (g & 7) ^ (r & 7);
            gload16(Cp + (size_t)r * FF + k0 + kb * 8, As + (size_t)g * 8);
        }
#pragma unroll
        for (int t = 0; t < 4; t++) {
            const int g = t * 256 + tid, r = g >> 3, kb = (g & 7) ^ (r & 7);
            gload16(Q + (size_t)r * FF + k0 + kb * 8, Bs + (size_t)g * 8);
        }
        __syncthreads();
#pragma unroll
        for (int ks = 0; ks < 2; ks++) {
            bf16x8 af[4], bfr[2];
#pragma unroll
            for (int i = 0; i < 4; i++) af[i] = frag8(As, i * 16 + cl, ks * 4 + q);
#pragma unroll
            for (int j = 0; j < 2; j++) bfr[j] = frag8(Bs, wid * 32 + j * 16 + cl, ks * 4 + q);
#pragma unroll
            for (int i = 0; i < 4; i++)
#pragma unroll
                for (int j = 0; j < 2; j++)
                    acc2[i][j] = __builtin_amdgcn_mfma_f32_16x16x32_bf16(
                        af[i], bfr[j], acc2[i][j], 0, 0, 0);
        }
        // den partial: this thread's row, its 32-feature half of this k-step
#pragma unroll
        for (int gi = 0; gi < 4; gi++) {
            const int kb = dhalf * 4 + gi;
            const ushort_t* gp = Bs + ((size_t)drow * 8 + (kb ^ (drow & 7))) * 8;
            const int kbase = k0 + kb * 8;
#pragma unroll
            for (int e2 = 0; e2 < 8; e2++)
                dacc = fmaf(bf2f(gp[e2]), zeps[kbase + e2], dacc);
        }
        __syncthreads();
    }
    denp[tid] = dacc;
    __syncthreads();
    if (tid < 128)
        den_l[tid] = rows_part[0][tid] + rows_part[1][tid] + denp[tid] + denp[tid + 128];
    __syncthreads();

    // ---- epilogue: divide, transpose via LDS, coalesced bf16 store ----
#pragma unroll
    for (int j = 0; j < 2; j++) {
        const int row = wid * 32 + j * 16 + cl;
        const float dinv = 1.0f / den_l[row];
#pragma unroll
        for (int i = 0; i < 4; i++)
#pragma unroll
            for (int r = 0; r < 4; r++) {
                const int e = i * 16 + q * 4 + r;
                Sld[row * 68 + e] = f2bf(acc2[i][j][r] * dinv);
            }
    }
    __syncthreads();
#pragma unroll
    for (int p = 0; p < 8; p++) {
        const int idx = p * 256 + tid;
        const int row = idx >> 4, e4 = idx & 15;
        ushort4 o = *(const ushort4*)&Sld[row * 68 + e4 * 4];
        *(ushort4*)(attnb + ((size_t)(bb * NSEQ + n0 + row)) * DIMM + h * 64 + e4 * 4) = o;
    }
}

extern "C" void kernel_launch(void* const* d_in, const int* in_sizes, int n_in,
                              void* d_out, int out_size, void* d_ws, size_t ws_size,
                              hipStream_t stream)
{
    (void)in_sizes; (void)n_in; (void)out_size; (void)ws_size;
    const float* x    = (const float*)d_in[0];
    const float* proj = (const float*)d_in[1];
    const float* Wq   = (const float*)d_in[2];
    const float* Wk   = (const float*)d_in[3];
    const float* Wv   = (const float*)d_in[4];
    const float* Wo   = (const float*)d_in[5];
    const float* bo   = (const float*)d_in[6];
    float* out = (float*)d_out;

    // ---- workspace carve (~86 MB) ----
    char* W = (char*)d_ws;
    float*    CTXT = (float*)W;              W += (size_t)16777216;   // [bh][c][e][f] fp32
    ushort_t* kfTb = (ushort_t*)W;           W += (size_t)16777216;   // [bh][f][n] bf16
    ushort_t* qfb  = (ushort_t*)W;           W += (size_t)16777216;   // [bh][n][f] bf16
    ushort_t* kfb  = (ushort_t*)W;           W += (size_t)16777216;
    ushort_t* qb   = (ushort_t*)W;           W += (size_t)4194304;    // [n][dim] bf16
    ushort_t* kb   = (ushort_t*)W;           W += (size_t)4194304;    // contiguous after qb
    ushort_t* xb   = (ushort_t*)W;           W += (size_t)4194304;    // reused as attnb
    ushort_t* vTb  = (ushort_t*)W;           W += (size_t)4194304;    // [bh][e][n]
    ushort_t* Wtq  = (ushort_t*)W;           W += (size_t)524288;
    ushort_t* Wtk  = (ushort_t*)W;           W += (size_t)524288;
    ushort_t* Wtv  = (ushort_t*)W;           W += (size_t)524288;
    ushort_t* Wto  = (ushort_t*)W;           W += (size_t)524288;
    ushort_t* projb = (ushort_t*)W;          W += (size_t)32768;
    float*    Ksum = (float*)W;              W += (size_t)262144;     // [bh][c][f]
    unsigned* mk_u = (unsigned*)W;           W += (size_t)256;

    // aliases (lifetime-disjoint)
    ushort_t* ctxp = qb;           // prefix writes bf16 prefix into qb+kb (8.4 MB), dead by then
    ushort_t* attnb = xb;          // xb dead after gemm_qkv

    float* Zout = out + (size_t)4096 * 512;
    float* Sout = Zout + (size_t)NBH * FF;

    hipLaunchKernelGGL(prep, dim3(3089), dim3(256), 0, stream,
                       x, proj, Wq, Wk, Wv, Wo, xb, projb, Wtq, Wtk, Wtv, Wto, mk_u);
    hipLaunchKernelGGL(gemm_qkv, dim3(4, 32, 3), dim3(256), 0, stream,
                       xb, Wtq, Wtk, Wtv, qb, kb, vTb);
    hipLaunchKernelGGL(kmax, dim3(32, 8), dim3(256), 0, stream, kb, projb, mk_u);
    hipLaunchKernelGGL(featx, dim3(32, 8, 2), dim3(256), 0, stream,
                       qb, kb, projb, mk_u, qfb, kfb, kfTb, Ksum);
    hipLaunchKernelGGL(ctx_mfma, dim3(256), dim3(256), 0, stream, vTb, kfTb, CTXT);
    hipLaunchKernelGGL(prefix_zs, dim3(1040), dim3(256), 0, stream,
                       Ksum, Zout, CTXT, ctxp, Sout);
    hipLaunchKernelGGL(chunk_out_mfma, dim3(256), dim3(256), 0, stream,
                       qfb, kfb, vTb, Ksum, ctxp, attnb);
    hipLaunchKernelGGL(gemm_out, dim3(4, 32), dim3(256), 0, stream, attnb, Wto, out, bo);
}

// Round 7
// 157.289 us; speedup vs baseline: 2.7327x; 1.0535x over previous
//
#include <hip/hip_runtime.h>
#include <hip/hip_bf16.h>
#include <math.h>

// Problem constants (b=2, n=2048, dim=512, h=8, dh=64, f=256, chunk=128)
#define NB    2
#define NSEQ  2048
#define DIMM  512
#define NH    8
#define DHd   64
#define FF    256
#define CHK   128
#define NCHK  16
#define NBH   16   // NB*NH

typedef unsigned short ushort_t;
typedef __attribute__((ext_vector_type(8))) __bf16 bf16x8;
typedef __attribute__((ext_vector_type(4))) float floatx4;

__device__ __forceinline__ unsigned short f2bf(float x) {
    union { __hip_bfloat16 h; unsigned short u; } v;
    v.h = __float2bfloat16(x);
    return v.u;
}
__device__ __forceinline__ float bf2f(unsigned short u) {
    union { unsigned short u2[2]; float f; } v;
    v.u2[0] = 0; v.u2[1] = u;
    return v.f;
}
__device__ __forceinline__ unsigned enc_f(float x) {
    unsigned u = __float_as_uint(x);
    return (u & 0x80000000u) ? ~u : (u | 0x80000000u);
}
__device__ __forceinline__ float dec_f(unsigned e) {
    unsigned u = (e & 0x80000000u) ? (e & 0x7fffffffu) : ~e;
    return __uint_as_float(u);
}

__device__ __forceinline__ void gload16(const void* g, void* l) {
    __builtin_amdgcn_global_load_lds(
        (const __attribute__((address_space(1))) void*)g,
        (__attribute__((address_space(3))) void*)l, 16, 0, 0);
}

// frag read from a 64-k-step tile (8 granules/row, xor-swizzled)
__device__ __forceinline__ bf16x8 frag8(const ushort_t* lds, int row, int kb) {
    return *((const bf16x8*)lds + row * 8 + (kb ^ (row & 7)));
}
// frag read from a 128-k tile (16 granules/row)
__device__ __forceinline__ bf16x8 fragS(const ushort_t* lds, int row, int kb) {
    return *((const bf16x8*)lds + row * 16 + (kb ^ (row & 15)));
}

// =====================================================================
// prep: init mk_u + conv x->bf16 + conv proj->bf16(*dn) + transpose W's
// =====================================================================
__global__ __launch_bounds__(256)
void prep(const float* __restrict__ x, const float* __restrict__ proj,
          const float* __restrict__ W0, const float* __restrict__ W1,
          const float* __restrict__ W2, const float* __restrict__ W3,
          ushort_t* __restrict__ xb, ushort_t* __restrict__ projb,
          ushort_t* __restrict__ T0, ushort_t* __restrict__ T1,
          ushort_t* __restrict__ T2, ushort_t* __restrict__ T3,
          unsigned* __restrict__ mk_u)
{
    __shared__ float t[32][33];
    const int b = blockIdx.x, tid = threadIdx.x;
    if (b < 2048) {
        const int gid = b * 256 + tid;
        const float4 v = *(const float4*)(x + (size_t)gid * 4);
        union { ushort4 v4; unsigned short s[4]; } pk;
        pk.s[0] = f2bf(v.x); pk.s[1] = f2bf(v.y); pk.s[2] = f2bf(v.z); pk.s[3] = f2bf(v.w);
        ((ushort4*)xb)[gid] = pk.v4;
    } else if (b < 2064) {
        const int gid = (b - 2048) * 256 + tid;
        const float dn = 0.35355339059327379f;   // 64^-0.25 folded into proj
        const float4 v = *(const float4*)(proj + (size_t)gid * 4);
        union { ushort4 v4; unsigned short s[4]; } pk;
        pk.s[0] = f2bf(v.x * dn); pk.s[1] = f2bf(v.y * dn);
        pk.s[2] = f2bf(v.z * dn); pk.s[3] = f2bf(v.w * dn);
        ((ushort4*)projb)[gid] = pk.v4;
    } else if (b < 3088) {
        const int idx = b - 2064;                // 0..1023
        const int z = idx >> 8, rem = idx & 255;
        const int bx = rem & 15, by = rem >> 4;
        const float* W = (z == 0) ? W0 : (z == 1) ? W1 : (z == 2) ? W2 : W3;
        ushort_t* T = (z == 0) ? T0 : (z == 1) ? T1 : (z == 2) ? T2 : T3;
        const int x0 = bx * 32, y0 = by * 32;
        const int tx = tid & 31, ty = tid >> 5;  // 32 x 8
#pragma unroll
        for (int i = 0; i < 4; i++)
            t[ty + i * 8][tx] = W[(size_t)(y0 + ty + i * 8) * DIMM + x0 + tx];
        __syncthreads();
#pragma unroll
        for (int i = 0; i < 4; i++)
            T[(size_t)(x0 + ty + i * 8) * DIMM + y0 + tx] = f2bf(t[tx][ty + i * 8]);
    } else {
        if (tid < NBH) mk_u[tid] = 0u;
    }
}

// =====================================================================
// MFMA main loop: C[128x128] += A[128xK] * B[128xK]^T
// =====================================================================
__device__ __forceinline__ void mfma_mainloop(
    const ushort_t* __restrict__ AG, const ushort_t* __restrict__ BG,
    ushort_t* As, ushort_t* Bs, int ldA, int ldB, int K,
    floatx4 acc[4][4], int tid)
{
    const int lane = tid & 63, wid = tid >> 6;
    const int q = lane >> 4, c = lane & 15;
    const int wm = (wid >> 1) * 64, wn = (wid & 1) * 64;

    for (int k0 = 0; k0 < K; k0 += 64) {
#pragma unroll
        for (int t = 0; t < 4; t++) {
            const int g = t * 256 + tid, r = g >> 3, kb = (g & 7) ^ (r & 7);
            gload16(AG + (size_t)r * ldA + k0 + kb * 8, As + (size_t)g * 8);
        }
#pragma unroll
        for (int t = 0; t < 4; t++) {
            const int g = t * 256 + tid, r = g >> 3, kb = (g & 7) ^ (r & 7);
            gload16(BG + (size_t)r * ldB + k0 + kb * 8, Bs + (size_t)g * 8);
        }
        __syncthreads();
#pragma unroll
        for (int ks = 0; ks < 2; ks++) {
            bf16x8 af[4], bfr[4];
#pragma unroll
            for (int i = 0; i < 4; i++) {
                af[i]  = frag8(As, wm + i * 16 + c, ks * 4 + q);
                bfr[i] = frag8(Bs, wn + i * 16 + c, ks * 4 + q);
            }
#pragma unroll
            for (int i = 0; i < 4; i++)
#pragma unroll
                for (int j = 0; j < 4; j++)
                    acc[i][j] = __builtin_amdgcn_mfma_f32_16x16x32_bf16(
                        af[i], bfr[j], acc[i][j], 0, 0, 0);
        }
        __syncthreads();
    }
}

// ---------- QKV projection: z=0 -> qb, z=1 -> kb, z=2 -> vTb; ALL epilogues via LDS ----------
__global__ __launch_bounds__(256)
void gemm_qkv(const ushort_t* __restrict__ xb,
              const ushort_t* __restrict__ Wtq, const ushort_t* __restrict__ Wtk,
              const ushort_t* __restrict__ Wtv,
              ushort_t* __restrict__ qb, ushort_t* __restrict__ kb,
              ushort_t* __restrict__ vTb)
{
    __shared__ alignas(16) ushort_t SM[16896];   // As(8192)+Bs(8192) staging; reuse as tile[128][132]
    ushort_t* As = SM;
    ushort_t* Bs = SM + 8192;
    const int tid = threadIdx.x;
    const int n0 = blockIdx.x * 128, m0 = blockIdx.y * 128, z = blockIdx.z;
    const ushort_t* Bt = (z == 0) ? Wtq : ((z == 1) ? Wtk : Wtv);

    floatx4 zero = {0.f, 0.f, 0.f, 0.f};
    floatx4 acc[4][4];
#pragma unroll
    for (int i = 0; i < 4; i++)
#pragma unroll
        for (int j = 0; j < 4; j++) acc[i][j] = zero;

    mfma_mainloop(xb + (size_t)m0 * DIMM, Bt + (size_t)n0 * DIMM, As, Bs,
                  DIMM, DIMM, DIMM, acc, tid);

    const int lane = tid & 63, wid = tid >> 6;
    const int q = lane >> 4, c = lane & 15;
    const int wm = (wid >> 1) * 64, wn = (wid & 1) * 64;

    // C tile -> LDS
#pragma unroll
    for (int i = 0; i < 4; i++)
#pragma unroll
        for (int j = 0; j < 4; j++) {
            const int col = wn + j * 16 + c;
#pragma unroll
            for (int r = 0; r < 4; r++) {
                const int row = wm + i * 16 + q * 4 + r;
                SM[row * 132 + col] = f2bf(acc[i][j][r]);
            }
        }
    __syncthreads();

    if (z < 2) {
        ushort_t* ob = (z == 0) ? qb : kb;
#pragma unroll
        for (int p = 0; p < 16; p++) {
            const int idx = p * 256 + tid;
            const int row = idx >> 5, c4 = idx & 31;
            ushort4 o = *(const ushort4*)&SM[row * 132 + c4 * 4];
            *(ushort4*)(ob + (size_t)(m0 + row) * DIMM + n0 + c4 * 4) = o;
        }
    } else {
        const int bb = m0 >> 11, nbase = m0 & 2047;
#pragma unroll
        for (int p = 0; p < 16; p++) {
            const int idx = p * 256 + tid;
            const int cl2 = idx >> 5, n4 = idx & 31;
            const int C = n0 + cl2;
            const int h = C >> 6, e = C & 63;
            union { ushort4 v4; unsigned short s[4]; } pk;
#pragma unroll
            for (int k = 0; k < 4; k++) pk.s[k] = SM[(n4 * 4 + k) * 132 + cl2];
            *(ushort4*)(vTb + (((size_t)(bb * NH + h) * 64 + e)) * NSEQ + nbase + n4 * 4) = pk.v4;
        }
    }
}

// ---------- output projection ----------
__global__ __launch_bounds__(256)
void gemm_out(const ushort_t* __restrict__ attnb, const ushort_t* __restrict__ Wto,
              float* __restrict__ out, const float* __restrict__ bias)
{
    __shared__ alignas(16) ushort_t As[8192];
    __shared__ alignas(16) ushort_t Bs[8192];
    const int tid = threadIdx.x;
    const int n0 = blockIdx.x * 128, m0 = blockIdx.y * 128;

    floatx4 zero = {0.f, 0.f, 0.f, 0.f};
    floatx4 acc[4][4];
#pragma unroll
    for (int i = 0; i < 4; i++)
#pragma unroll
        for (int j = 0; j < 4; j++) acc[i][j] = zero;

    mfma_mainloop(attnb + (size_t)m0 * DIMM, Wto + (size_t)n0 * DIMM, As, Bs,
                  DIMM, DIMM, DIMM, acc, tid);

    const int lane = tid & 63, wid = tid >> 6;
    const int q = lane >> 4, c = lane & 15;
    const int wm = (wid >> 1) * 64, wn = (wid & 1) * 64;
#pragma unroll
    for (int i = 0; i < 4; i++)
#pragma unroll
        for (int j = 0; j < 4; j++) {
            const int col = n0 + wn + j * 16 + c;
            const float bv = bias[col];
#pragma unroll
            for (int r = 0; r < 4; r++) {
                const int row = m0 + wm + i * 16 + q * 4 + r;
                out[(size_t)row * DIMM + col] = acc[i][j][r] + bv;
            }
        }
}

// =====================================================================
// kmax: key features MFMA, per-(b,h) max only (no stores) -> atomicMax
// =====================================================================
__global__ __launch_bounds__(256)
void kmax(const ushort_t* __restrict__ kb_, const ushort_t* __restrict__ projb,
          unsigned* __restrict__ mk_u)
{
    __shared__ alignas(16) ushort_t As[8192];    // 128 rows x 64k
    __shared__ alignas(16) ushort_t Bs[16384];   // 256 rows x 64k
    __shared__ float red[256];
    const int tid = threadIdx.x, lane = tid & 63, wid = tid >> 6;
    const int q = lane >> 4, cl = lane & 15;
    const int m0 = blockIdx.x * 128, h = blockIdx.y;
    const int bb = m0 >> 11;
    const ushort_t* Aq = kb_ + (size_t)m0 * DIMM + h * 64;

#pragma unroll
    for (int t = 0; t < 4; t++) {
        const int g = t * 256 + tid, r = g >> 3, kb = (g & 7) ^ (r & 7);
        gload16(Aq + (size_t)r * DIMM + kb * 8, As + (size_t)g * 8);
    }
#pragma unroll
    for (int t = 0; t < 8; t++) {
        const int g = t * 256 + tid, r = g >> 3, kb = (g & 7) ^ (r & 7);
        gload16(projb + (size_t)r * 64 + kb * 8, Bs + (size_t)g * 8);
    }
    __syncthreads();

    floatx4 zero = {0.f, 0.f, 0.f, 0.f};
    floatx4 acc[4][8];
#pragma unroll
    for (int i = 0; i < 4; i++)
#pragma unroll
        for (int j = 0; j < 8; j++) acc[i][j] = zero;
    const int wm = (wid >> 1) * 64, wn = (wid & 1) * 128;
#pragma unroll
    for (int ks = 0; ks < 2; ks++) {
        bf16x8 af[4], bfr[8];
#pragma unroll
        for (int i = 0; i < 4; i++) af[i] = frag8(As, wm + i * 16 + cl, ks * 4 + q);
#pragma unroll
        for (int j = 0; j < 8; j++) bfr[j] = frag8(Bs, wn + j * 16 + cl, ks * 4 + q);
#pragma unroll
        for (int i = 0; i < 4; i++)
#pragma unroll
            for (int j = 0; j < 8; j++)
                acc[i][j] = __builtin_amdgcn_mfma_f32_16x16x32_bf16(
                    af[i], bfr[j], acc[i][j], 0, 0, 0);
    }
    float mloc = -3.0e38f;
#pragma unroll
    for (int i = 0; i < 4; i++)
#pragma unroll
        for (int j = 0; j < 8; j++)
#pragma unroll
            for (int r = 0; r < 4; r++) mloc = fmaxf(mloc, acc[i][j][r]);
    red[tid] = mloc;
    __syncthreads();
    for (int s = 128; s > 0; s >>= 1) {
        if (tid < s) red[tid] = fmaxf(red[tid], red[tid + s]);
        __syncthreads();
    }
    if (tid == 0) atomicMax(&mk_u[bb * NH + h], enc_f(red[0]));
}

// =====================================================================
// featx: features + exp; query -> qfb; key -> kfb + Ksum + fused CTXT
// (key m-tile == one chunk). kfTb surface eliminated.
// =====================================================================
__global__ __launch_bounds__(256)
void featx(const ushort_t* __restrict__ qb_, const ushort_t* __restrict__ kb_,
           const ushort_t* __restrict__ projb, const unsigned* __restrict__ mk_u,
           const ushort_t* __restrict__ vTb,
           ushort_t* __restrict__ qfb, ushort_t* __restrict__ kfb,
           float* __restrict__ CTXT, float* __restrict__ Ksum)
{
    __shared__ alignas(16) ushort_t SM[24576];   // staging As(8192)+Bs(16384); reused
    __shared__ float dtmp[256];
    __shared__ float diag_l[128];
    __shared__ float mx2[2][128];
    __shared__ float colp[2][256];
    ushort_t* As = SM;
    ushort_t* Bs = SM + 8192;
    const int tid = threadIdx.x, lane = tid & 63, wid = tid >> 6;
    const int q = lane >> 4, cl = lane & 15;
    const int m0 = blockIdx.x * 128, h = blockIdx.y, src = blockIdx.z;
    const int bb = m0 >> 11, nloc = m0 & 2047;
    const int bh = bb * NH + h;
    const int cidx = nloc >> 7;
    const ushort_t* Aq = (src ? kb_ : qb_) + (size_t)m0 * DIMM + h * 64;

    // diag[row] = sum(qk^2)/16 (from the same bf16 inputs the GEMM uses)
    {
        const int row = tid >> 1, half = tid & 1;
        float s = 0.f;
        const ushort_t* p = Aq + (size_t)row * DIMM + half * 32;
#pragma unroll
        for (int d = 0; d < 32; d += 4) {
            ushort4 w = *(const ushort4*)(p + d);
            float a = bf2f(w.x), b2 = bf2f(w.y), c2 = bf2f(w.z), d2 = bf2f(w.w);
            s += a * a + b2 * b2 + c2 * c2 + d2 * d2;
        }
        dtmp[tid] = s;
    }
    __syncthreads();
    if (tid < 128) diag_l[tid] = (dtmp[2 * tid] + dtmp[2 * tid + 1]) * 0.0625f;

    // stage A (128x64) and proj (256x64)
#pragma unroll
    for (int t = 0; t < 4; t++) {
        const int g = t * 256 + tid, r = g >> 3, kb = (g & 7) ^ (r & 7);
        gload16(Aq + (size_t)r * DIMM + kb * 8, As + (size_t)g * 8);
    }
#pragma unroll
    for (int t = 0; t < 8; t++) {
        const int g = t * 256 + tid, r = g >> 3, kb = (g & 7) ^ (r & 7);
        gload16(projb + (size_t)r * 64 + kb * 8, Bs + (size_t)g * 8);
    }
    __syncthreads();

    floatx4 zero = {0.f, 0.f, 0.f, 0.f};
    floatx4 acc[4][8];
#pragma unroll
    for (int i = 0; i < 4; i++)
#pragma unroll
        for (int j = 0; j < 8; j++) acc[i][j] = zero;
    const int wm = (wid >> 1) * 64, wn = (wid & 1) * 128;
#pragma unroll
    for (int ks = 0; ks < 2; ks++) {
        bf16x8 af[4], bfr[8];
#pragma unroll
        for (int i = 0; i < 4; i++) af[i] = frag8(As, wm + i * 16 + cl, ks * 4 + q);
#pragma unroll
        for (int j = 0; j < 8; j++) bfr[j] = frag8(Bs, wn + j * 16 + cl, ks * 4 + q);
#pragma unroll
        for (int i = 0; i < 4; i++)
#pragma unroll
            for (int j = 0; j < 8; j++)
                acc[i][j] = __builtin_amdgcn_mfma_f32_16x16x32_bf16(
                    af[i], bfr[j], acc[i][j], 0, 0, 0);
    }

    const float mk = src ? dec_f(mk_u[bh]) : 0.f;
    if (src == 0) {
        // per-row max (both f-halves, via LDS across wave pairs)
#pragma unroll
        for (int i = 0; i < 4; i++)
#pragma unroll
            for (int r = 0; r < 4; r++) {
                const int row = wm + i * 16 + q * 4 + r;
                float mx = -3.0e38f;
#pragma unroll
                for (int j = 0; j < 8; j++) mx = fmaxf(mx, acc[i][j][r]);
                mx = fmaxf(mx, __shfl_xor(mx, 1)); mx = fmaxf(mx, __shfl_xor(mx, 2));
                mx = fmaxf(mx, __shfl_xor(mx, 4)); mx = fmaxf(mx, __shfl_xor(mx, 8));
                if (cl == 0) mx2[wid & 1][row] = mx;
            }
    }
    __syncthreads();   // mx2/diag visible; frag ds_reads complete (SM reusable)

    // exp-normalize in place
#pragma unroll
    for (int i = 0; i < 4; i++)
#pragma unroll
        for (int r = 0; r < 4; r++) {
            const int row = wm + i * 16 + q * 4 + r;
            const float cc = diag_l[row] + (src ? mk : fmaxf(mx2[0][row], mx2[1][row]));
#pragma unroll
            for (int j = 0; j < 8; j++)
                acc[i][j][r] = 0.0625f * (__expf(acc[i][j][r] - cc) + 1.0e-4f);
        }

    // key: column sums from registers (quad shuffles)
    if (src) {
#pragma unroll
        for (int j = 0; j < 8; j++) {
            float s = 0.f;
#pragma unroll
            for (int i = 0; i < 4; i++)
                s += acc[i][j][0] + acc[i][j][1] + acc[i][j][2] + acc[i][j][3];
            s += __shfl_xor(s, 16);
            s += __shfl_xor(s, 32);
            if (q == 0) colp[wid >> 1][wn + j * 16 + cl] = s;
        }
    }

    ushort_t* ff = src ? kfb : qfb;
    const size_t frow = (size_t)bh * NSEQ + nloc;

#pragma unroll
    for (int hf = 0; hf < 2; hf++) {
        __syncthreads();   // colp visible (hf=0); prior reads done (hf=1)
        if ((wid & 1) == hf) {
#pragma unroll
            for (int i = 0; i < 4; i++)
#pragma unroll
                for (int j = 0; j < 8; j++) {
                    const int col = j * 16 + cl;
#pragma unroll
                    for (int r = 0; r < 4; r++) {
                        const int row = wm + i * 16 + q * 4 + r;
                        SM[row * 132 + col] = f2bf(acc[i][j][r]);
                    }
                }
        }
        if (hf == 0 && src) {
            Ksum[((size_t)bh * NCHK + cidx) * FF + tid] = colp[0][tid] + colp[1][tid];
        }
        __syncthreads();
        // coalesced [n][f] stores
#pragma unroll
        for (int p = 0; p < 16; p++) {
            const int idx = p * 256 + tid;
            const int row = idx >> 5, c4 = idx & 31;
            ushort4 o = *(const ushort4*)&SM[row * 132 + c4 * 4];
            *(ushort4*)(ff + (frow + row) * FF + hf * 128 + c4 * 4) = o;
        }
    }

    if (src == 0) return;

    // =====================================================================
    // fused ctx: CTXT[bh][cidx][e][f] = sum_n vT[e][n] * kf[n][f]
    // Vs (64e x 128n, fragS layout) at SM[0..8191]; T quarter (64f x 136n)
    // at SM[8192..16895]. Same contraction order as old ctx_mfma.
    // =====================================================================
    __syncthreads();   // all kfb-store reads of SM done before overwrite
    ushort_t* Vs = SM;
    ushort_t* T  = SM + 8192;
    const ushort_t* Vg = vTb + ((size_t)bh * 64) * NSEQ + nloc;
    // stage vT chunk: 64 rows x 16 granules
#pragma unroll
    for (int t = 0; t < 4; t++) {
        const int g = t * 256 + tid, r = g >> 4, kb = (g & 15) ^ (r & 15);
        gload16(Vg + (size_t)r * NSEQ + kb * 8, Vs + (size_t)g * 8);
    }

    const size_t cbase = ((size_t)bh * NCHK + cidx) * 64;
#pragma unroll
    for (int fq = 0; fq < 4; fq++) {
        // build T quarter from registers (2 of 4 waves own this f-range)
        if ((wid & 1) == (fq >> 1)) {
#pragma unroll
            for (int jj = 0; jj < 4; jj++) {
                const int j = (fq & 1) * 4 + jj;
#pragma unroll
                for (int i = 0; i < 4; i++)
#pragma unroll
                    for (int r = 0; r < 4; r++) {
                        const int n = wm + i * 16 + q * 4 + r;
                        T[(jj * 16 + cl) * 136 + n] = f2bf(acc[i][j][r]);
                    }
            }
        }
        __syncthreads();   // T ready; (fq=0) also drains Vs DMA
        floatx4 accc[4];
#pragma unroll
        for (int jj = 0; jj < 4; jj++) accc[jj] = zero;
#pragma unroll
        for (int kt = 0; kt < 4; kt++) {
            const bf16x8 av = fragS(Vs, wid * 16 + cl, kt * 4 + q);
#pragma unroll
            for (int jj = 0; jj < 4; jj++) {
                const bf16x8 bv = *(const bf16x8*)(T + (jj * 16 + cl) * 136 + (kt * 4 + q) * 8);
                accc[jj] = __builtin_amdgcn_mfma_f32_16x16x32_bf16(av, bv, accc[jj], 0, 0, 0);
            }
        }
#pragma unroll
        for (int jj = 0; jj < 4; jj++) {
            const int f = fq * 64 + jj * 16 + cl;
#pragma unroll
            for (int r = 0; r < 4; r++) {
                const int e = wid * 16 + q * 4 + r;
                CTXT[(cbase + e) * FF + f] = accc[jj][r];
            }
        }
        __syncthreads();   // before next quarter's T overwrite
    }
}

// ---------- merged exclusive prefixes: blocks [0,1024) S-path, [1024,1040) Z-path ----------
__global__ void prefix_zs(float* __restrict__ Ksum, float* __restrict__ Zout,
                          const float* __restrict__ CTXT, ushort_t* __restrict__ ctxp,
                          float* __restrict__ Sout)
{
    const int b = blockIdx.x;
    if (b < 1024) {
        const int idx = b * 256 + threadIdx.x;
        const int bh = idx >> 14, ef = idx & 16383;
        const int e = ef >> 8, f = ef & 255;
        float run = 0.f;
#pragma unroll
        for (int c = 0; c < NCHK; c++) {
            const size_t o = (((size_t)bh * NCHK + c) * 64 + e) * FF + f;
            const float t = CTXT[o];
            ctxp[o] = f2bf(run);
            run += t;
        }
        Sout[((size_t)bh * FF + f) * 64 + e] = run;   // S[b,h,f,e]
    } else {
        const int idx = (b - 1024) * 256 + threadIdx.x;
        const int bh = idx >> 8, f = idx & 255;
        float run = 0.f;
#pragma unroll
        for (int c = 0; c < NCHK; c++) {
            const size_t o = ((size_t)(bh * NCHK + c)) * FF + f;
            const float t = Ksum[o];
            Ksum[o] = run;
            run += t;
        }
        Zout[(size_t)bh * FF + f] = run;
    }
}

// ---------- chunk output, full MFMA ----------
__global__ __launch_bounds__(256)
void chunk_out_mfma(const ushort_t* __restrict__ qfb, const ushort_t* __restrict__ kfb,
                    const ushort_t* __restrict__ vTb, const float* __restrict__ Zex,
                    const ushort_t* __restrict__ ctxp, ushort_t* __restrict__ attnb)
{
    __shared__ alignas(16) ushort_t Sld[16384];  // 32 KB: S (128x128) / out-tile reuse
    __shared__ alignas(16) ushort_t As[8192];    // 16 KB
    __shared__ alignas(16) ushort_t Bs[8192];    // 16 KB
    __shared__ float zeps[256];
    __shared__ float rows_part[2][128];
    __shared__ float denp[256];
    __shared__ float den_l[128];

    const int tid = threadIdx.x, lane = tid & 63, wid = tid >> 6;
    const int q = lane >> 4, cl = lane & 15;
    const int bh = blockIdx.x >> 4, c = blockIdx.x & 15;
    const int bb = bh >> 3, h = bh & 7;
    const int n0 = c * CHK;
    const ushort_t* Q  = qfb + ((size_t)bh * NSEQ + n0) * FF;
    const ushort_t* Kf = kfb + ((size_t)bh * NSEQ + n0) * FF;

    zeps[tid] = Zex[((size_t)bh * NCHK + c) * FF + tid] + 1.0e-6f;

    // ---- stage 1: S = Q @ Kf^T (K=256), wave-grid 2x2 ----
    floatx4 zero = {0.f, 0.f, 0.f, 0.f};
    floatx4 acc1[4][4];
#pragma unroll
    for (int i = 0; i < 4; i++)
#pragma unroll
        for (int j = 0; j < 4; j++) acc1[i][j] = zero;
    const int wm = (wid >> 1) * 64, wn = (wid & 1) * 64;
    for (int k0 = 0; k0 < FF; k0 += 64) {
#pragma unroll
        for (int t = 0; t < 4; t++) {
            const int g = t * 256 + tid, r = g >> 3, kb = (g & 7) ^ (r & 7);
            gload16(Q + (size_t)r * FF + k0 + kb * 8, As + (size_t)g * 8);
        }
#pragma unroll
        for (int t = 0; t < 4; t++) {
            const int g = t * 256 + tid, r = g >> 3, kb = (g & 7) ^ (r & 7);
            gload16(Kf + (size_t)r * FF + k0 + kb * 8, Bs + (size_t)g * 8);
        }
        __syncthreads();
#pragma unroll
        for (int ks = 0; ks < 2; ks++) {
            bf16x8 af[4], bfr[4];
#pragma unroll
            for (int i = 0; i < 4; i++) {
                af[i]  = frag8(As, wm + i * 16 + cl, ks * 4 + q);
                bfr[i] = frag8(Bs, wn + i * 16 + cl, ks * 4 + q);
            }
#pragma unroll
            for (int i = 0; i < 4; i++)
#pragma unroll
                for (int j = 0; j < 4; j++)
                    acc1[i][j] = __builtin_amdgcn_mfma_f32_16x16x32_bf16(
                        af[i], bfr[j], acc1[i][j], 0, 0, 0);
        }
        __syncthreads();
    }
    // ---- causal mask + rowsum(fp32) + S -> LDS (bf16, swizzled granules) ----
#pragma unroll
    for (int i = 0; i < 4; i++)
#pragma unroll
        for (int r = 0; r < 4; r++) {
            const int row = wm + i * 16 + q * 4 + r;
            float part = 0.f;
#pragma unroll
            for (int j = 0; j < 4; j++) {
                const int col = wn + j * 16 + cl;
                const float v = (col <= row) ? acc1[i][j][r] : 0.f;
                part += v;
                Sld[(row * 16 + ((col >> 3) ^ (row & 15))) * 8 + (col & 7)] = f2bf(v);
            }
            part += __shfl_xor(part, 1); part += __shfl_xor(part, 2);
            part += __shfl_xor(part, 4); part += __shfl_xor(part, 8);
            if (cl == 0) rows_part[wid & 1][row] = part;
        }
    __syncthreads();

    // ---- stage 3: acc2[e][row] += vT (x) S  (K = 128 seq) ----
    floatx4 acc2[4][2];
#pragma unroll
    for (int i = 0; i < 4; i++)
#pragma unroll
        for (int j = 0; j < 2; j++) acc2[i][j] = zero;
    const ushort_t* Vt = vTb + ((size_t)bh * 64) * NSEQ + n0;
    for (int k0 = 0; k0 < CHK; k0 += 64) {
#pragma unroll
        for (int t = 0; t < 2; t++) {
            const int g = t * 256 + tid, r = g >> 3, kb = (g & 7) ^ (r & 7);
            gload16(Vt + (size_t)r * NSEQ + k0 + kb * 8, As + (size_t)g * 8);
        }
        __syncthreads();
#pragma unroll
        for (int ks = 0; ks < 2; ks++) {
            bf16x8 af[4], bfr[2];
            const int kbS = (k0 >> 3) + ks * 4 + q;
#pragma unroll
            for (int i = 0; i < 4; i++) af[i] = frag8(As, i * 16 + cl, ks * 4 + q);
#pragma unroll
            for (int j = 0; j < 2; j++) bfr[j] = fragS(Sld, wid * 32 + j * 16 + cl, kbS);
#pragma unroll
            for (int i = 0; i < 4; i++)
#pragma unroll
                for (int j = 0; j < 2; j++)
                    acc2[i][j] = __builtin_amdgcn_mfma_f32_16x16x32_bf16(
                        af[i], bfr[j], acc2[i][j], 0, 0, 0);
        }
        __syncthreads();
    }

    // ---- stage 4: acc2 += ctxp (x) Q  (K = 256 features); den from staged Q ----
    const ushort_t* Cp = ctxp + ((size_t)bh * NCHK + c) * 64 * FF;
    float dacc = 0.f;
    const int drow = tid & 127, dhalf = tid >> 7;
    for (int k0 = 0; k0 < FF; k0 += 64) {
#pragma unroll
        for (int t = 0; t < 2; t++) {
            const int g = t * 256 + tid, r = g >> 3, kb = (g & 7) ^ (r & 7);
            gload16(Cp + (size_t)r * FF + k0 + kb * 8, As + (size_t)g * 8);
        }
#pragma unroll
        for (int t = 0; t < 4; t++) {
            const int g = t * 256 + tid, r = g >> 3, kb = (g & 7) ^ (r & 7);
            gload16(Q + (size_t)r * FF + k0 + kb * 8, Bs + (size_t)g * 8);
        }
        __syncthreads();
#pragma unroll
        for (int ks = 0; ks < 2; ks++) {
            bf16x8 af[4], bfr[2];
#pragma unroll
            for (int i = 0; i < 4; i++) af[i] = frag8(As, i * 16 + cl, ks * 4 + q);
#pragma unroll
            for (int j = 0; j < 2; j++) bfr[j] = frag8(Bs, wid * 32 + j * 16 + cl, ks * 4 + q);
#pragma unroll
            for (int i = 0; i < 4; i++)
#pragma unroll
                for (int j = 0; j < 2; j++)
                    acc2[i][j] = __builtin_amdgcn_mfma_f32_16x16x32_bf16(
                        af[i], bfr[j], acc2[i][j], 0, 0, 0);
        }
        // den partial: this thread's row, its 32-feature half of this k-step
#pragma unroll
        for (int gi = 0; gi < 4; gi++) {
            const int kb = dhalf * 4 + gi;
            const ushort_t* gp = Bs + ((size_t)drow * 8 + (kb ^ (drow & 7))) * 8;
            const int kbase = k0 + kb * 8;
#pragma unroll
            for (int e2 = 0; e2 < 8; e2++)
                dacc = fmaf(bf2f(gp[e2]), zeps[kbase + e2], dacc);
        }
        __syncthreads();
    }
    denp[tid] = dacc;
    __syncthreads();
    if (tid < 128)
        den_l[tid] = rows_part[0][tid] + rows_part[1][tid] + denp[tid] + denp[tid + 128];
    __syncthreads();

    // ---- epilogue: divide, transpose via LDS, coalesced bf16 store ----
#pragma unroll
    for (int j = 0; j < 2; j++) {
        const int row = wid * 32 + j * 16 + cl;
        const float dinv = 1.0f / den_l[row];
#pragma unroll
        for (int i = 0; i < 4; i++)
#pragma unroll
            for (int r = 0; r < 4; r++) {
                const int e = i * 16 + q * 4 + r;
                Sld[row * 68 + e] = f2bf(acc2[i][j][r] * dinv);
            }
    }
    __syncthreads();
#pragma unroll
    for (int p = 0; p < 8; p++) {
        const int idx = p * 256 + tid;
        const int row = idx >> 4, e4 = idx & 15;
        ushort4 o = *(const ushort4*)&Sld[row * 68 + e4 * 4];
        *(ushort4*)(attnb + ((size_t)(bb * NSEQ + n0 + row)) * DIMM + h * 64 + e4 * 4) = o;
    }
}

extern "C" void kernel_launch(void* const* d_in, const int* in_sizes, int n_in,
                              void* d_out, int out_size, void* d_ws, size_t ws_size,
                              hipStream_t stream)
{
    (void)in_sizes; (void)n_in; (void)out_size; (void)ws_size;
    const float* x    = (const float*)d_in[0];
    const float* proj = (const float*)d_in[1];
    const float* Wq   = (const float*)d_in[2];
    const float* Wk   = (const float*)d_in[3];
    const float* Wv   = (const float*)d_in[4];
    const float* Wo   = (const float*)d_in[5];
    const float* bo   = (const float*)d_in[6];
    float* out = (float*)d_out;

    // ---- workspace carve (~70 MB) ----
    char* W = (char*)d_ws;
    float*    CTXT = (float*)W;              W += (size_t)16777216;   // [bh][c][e][f] fp32
    ushort_t* qfb  = (ushort_t*)W;           W += (size_t)16777216;   // [bh][n][f] bf16
    ushort_t* kfb  = (ushort_t*)W;           W += (size_t)16777216;
    ushort_t* qb   = (ushort_t*)W;           W += (size_t)4194304;    // [n][dim] bf16
    ushort_t* kb   = (ushort_t*)W;           W += (size_t)4194304;    // contiguous after qb
    ushort_t* xb   = (ushort_t*)W;           W += (size_t)4194304;    // reused as attnb
    ushort_t* vTb  = (ushort_t*)W;           W += (size_t)4194304;    // [bh][e][n]
    ushort_t* Wtq  = (ushort_t*)W;           W += (size_t)524288;
    ushort_t* Wtk  = (ushort_t*)W;           W += (size_t)524288;
    ushort_t* Wtv  = (ushort_t*)W;           W += (size_t)524288;
    ushort_t* Wto  = (ushort_t*)W;           W += (size_t)524288;
    ushort_t* projb = (ushort_t*)W;          W += (size_t)32768;
    float*    Ksum = (float*)W;              W += (size_t)262144;     // [bh][c][f]
    unsigned* mk_u = (unsigned*)W;           W += (size_t)256;

    // aliases (lifetime-disjoint)
    ushort_t* ctxp = qb;           // prefix writes bf16 prefix into qb+kb (8.4 MB), dead by then
    ushort_t* attnb = xb;          // xb dead after gemm_qkv

    float* Zout = out + (size_t)4096 * 512;
    float* Sout = Zout + (size_t)NBH * FF;

    hipLaunchKernelGGL(prep, dim3(3089), dim3(256), 0, stream,
                       x, proj, Wq, Wk, Wv, Wo, xb, projb, Wtq, Wtk, Wtv, Wto, mk_u);
    hipLaunchKernelGGL(gemm_qkv, dim3(4, 32, 3), dim3(256), 0, stream,
                       xb, Wtq, Wtk, Wtv, qb, kb, vTb);
    hipLaunchKernelGGL(kmax, dim3(32, 8), dim3(256), 0, stream, kb, projb, mk_u);
    hipLaunchKernelGGL(featx, dim3(32, 8, 2), dim3(256), 0, stream,
                       qb, kb, projb, mk_u, vTb, qfb, kfb, CTXT, Ksum);
    hipLaunchKernelGGL(prefix_zs, dim3(1040), dim3(256), 0, stream,
                       Ksum, Zout, CTXT, ctxp, Sout);
    hipLaunchKernelGGL(chunk_out_mfma, dim3(256), dim3(256), 0, stream,
                       qfb, kfb, vTb, Ksum, ctxp, attnb);
    hipLaunchKernelGGL(gemm_out, dim3(4, 32), dim3(256), 0, stream, attnb, Wto, out, bo);
}

// Round 8
// 155.562 us; speedup vs baseline: 2.7630x; 1.0111x over previous
//
#include <hip/hip_runtime.h>
#include <hip/hip_bf16.h>
#include <math.h>

// Problem constants (b=2, n=2048, dim=512, h=8, dh=64, f=256, chunk=128)
#define NB    2
#define NSEQ  2048
#define DIMM  512
#define NH    8
#define DHd   64
#define FF    256
#define CHK   128
#define NCHK  16
#define NBH   16   // NB*NH

typedef unsigned short ushort_t;
typedef __attribute__((ext_vector_type(8))) __bf16 bf16x8;
typedef __attribute__((ext_vector_type(4))) float floatx4;

__device__ __forceinline__ unsigned short f2bf(float x) {
    union { __hip_bfloat16 h; unsigned short u; } v;
    v.h = __float2bfloat16(x);
    return v.u;
}
__device__ __forceinline__ float bf2f(unsigned short u) {
    union { unsigned short u2[2]; float f; } v;
    v.u2[0] = 0; v.u2[1] = u;
    return v.f;
}
__device__ __forceinline__ unsigned enc_f(float x) {
    unsigned u = __float_as_uint(x);
    return (u & 0x80000000u) ? ~u : (u | 0x80000000u);
}
__device__ __forceinline__ float dec_f(unsigned e) {
    unsigned u = (e & 0x80000000u) ? (e & 0x7fffffffu) : ~e;
    return __uint_as_float(u);
}

__device__ __forceinline__ void gload16(const void* g, void* l) {
    __builtin_amdgcn_global_load_lds(
        (const __attribute__((address_space(1))) void*)g,
        (__attribute__((address_space(3))) void*)l, 16, 0, 0);
}

// frag read from a 64-k-step tile (8 granules/row, xor-swizzled)
__device__ __forceinline__ bf16x8 frag8(const ushort_t* lds, int row, int kb) {
    return *((const bf16x8*)lds + row * 8 + (kb ^ (row & 7)));
}
// frag read from a 128-k tile (16 granules/row)
__device__ __forceinline__ bf16x8 fragS(const ushort_t* lds, int row, int kb) {
    return *((const bf16x8*)lds + row * 16 + (kb ^ (row & 15)));
}

// =====================================================================
// prep: init mk_u + conv x->bf16 + conv proj->bf16(*dn) + transpose W's
// =====================================================================
__global__ __launch_bounds__(256)
void prep(const float* __restrict__ x, const float* __restrict__ proj,
          const float* __restrict__ W0, const float* __restrict__ W1,
          const float* __restrict__ W2, const float* __restrict__ W3,
          ushort_t* __restrict__ xb, ushort_t* __restrict__ projb,
          ushort_t* __restrict__ T0, ushort_t* __restrict__ T1,
          ushort_t* __restrict__ T2, ushort_t* __restrict__ T3,
          unsigned* __restrict__ mk_u)
{
    __shared__ float t[32][33];
    const int b = blockIdx.x, tid = threadIdx.x;
    if (b < 2048) {
        const int gid = b * 256 + tid;
        const float4 v = *(const float4*)(x + (size_t)gid * 4);
        union { ushort4 v4; unsigned short s[4]; } pk;
        pk.s[0] = f2bf(v.x); pk.s[1] = f2bf(v.y); pk.s[2] = f2bf(v.z); pk.s[3] = f2bf(v.w);
        ((ushort4*)xb)[gid] = pk.v4;
    } else if (b < 2064) {
        const int gid = (b - 2048) * 256 + tid;
        const float dn = 0.35355339059327379f;   // 64^-0.25 folded into proj
        const float4 v = *(const float4*)(proj + (size_t)gid * 4);
        union { ushort4 v4; unsigned short s[4]; } pk;
        pk.s[0] = f2bf(v.x * dn); pk.s[1] = f2bf(v.y * dn);
        pk.s[2] = f2bf(v.z * dn); pk.s[3] = f2bf(v.w * dn);
        ((ushort4*)projb)[gid] = pk.v4;
    } else if (b < 3088) {
        const int idx = b - 2064;                // 0..1023
        const int z = idx >> 8, rem = idx & 255;
        const int bx = rem & 15, by = rem >> 4;
        const float* W = (z == 0) ? W0 : (z == 1) ? W1 : (z == 2) ? W2 : W3;
        ushort_t* T = (z == 0) ? T0 : (z == 1) ? T1 : (z == 2) ? T2 : T3;
        const int x0 = bx * 32, y0 = by * 32;
        const int tx = tid & 31, ty = tid >> 5;  // 32 x 8
#pragma unroll
        for (int i = 0; i < 4; i++)
            t[ty + i * 8][tx] = W[(size_t)(y0 + ty + i * 8) * DIMM + x0 + tx];
        __syncthreads();
#pragma unroll
        for (int i = 0; i < 4; i++)
            T[(size_t)(x0 + ty + i * 8) * DIMM + y0 + tx] = f2bf(t[tx][ty + i * 8]);
    } else {
        if (tid < NBH) mk_u[tid] = 0u;
    }
}

// =====================================================================
// MFMA main loop: C[128x128] += A[128xK] * B[128xK]^T
// =====================================================================
__device__ __forceinline__ void mfma_mainloop(
    const ushort_t* __restrict__ AG, const ushort_t* __restrict__ BG,
    ushort_t* As, ushort_t* Bs, int ldA, int ldB, int K,
    floatx4 acc[4][4], int tid)
{
    const int lane = tid & 63, wid = tid >> 6;
    const int q = lane >> 4, c = lane & 15;
    const int wm = (wid >> 1) * 64, wn = (wid & 1) * 64;

    for (int k0 = 0; k0 < K; k0 += 64) {
#pragma unroll
        for (int t = 0; t < 4; t++) {
            const int g = t * 256 + tid, r = g >> 3, kb = (g & 7) ^ (r & 7);
            gload16(AG + (size_t)r * ldA + k0 + kb * 8, As + (size_t)g * 8);
        }
#pragma unroll
        for (int t = 0; t < 4; t++) {
            const int g = t * 256 + tid, r = g >> 3, kb = (g & 7) ^ (r & 7);
            gload16(BG + (size_t)r * ldB + k0 + kb * 8, Bs + (size_t)g * 8);
        }
        __syncthreads();
#pragma unroll
        for (int ks = 0; ks < 2; ks++) {
            bf16x8 af[4], bfr[4];
#pragma unroll
            for (int i = 0; i < 4; i++) {
                af[i]  = frag8(As, wm + i * 16 + c, ks * 4 + q);
                bfr[i] = frag8(Bs, wn + i * 16 + c, ks * 4 + q);
            }
#pragma unroll
            for (int i = 0; i < 4; i++)
#pragma unroll
                for (int j = 0; j < 4; j++)
                    acc[i][j] = __builtin_amdgcn_mfma_f32_16x16x32_bf16(
                        af[i], bfr[j], acc[i][j], 0, 0, 0);
        }
        __syncthreads();
    }
}

// =====================================================================
// QKV projection: z=0 -> qb, z=1 -> kb (+ fused key-feature max), z=2 -> vTb.
// C tile parked in LDS (stride 136 for 16B-aligned frag reads); z=1 runs the
// K=64 feature MFMA against its two complete in-LDS head slices and
// atomicMax's mk_u — the old kmax kernel is gone.
// =====================================================================
__global__ __launch_bounds__(256)
void gemm_qkv(const ushort_t* __restrict__ xb,
              const ushort_t* __restrict__ Wtq, const ushort_t* __restrict__ Wtk,
              const ushort_t* __restrict__ Wtv, const ushort_t* __restrict__ projb,
              ushort_t* __restrict__ qb, ushort_t* __restrict__ kb,
              ushort_t* __restrict__ vTb, unsigned* __restrict__ mk_u)
{
    __shared__ alignas(16) ushort_t SM[25600];   // staging As/Bs; tile[128][136]; PS proj half
    __shared__ float red[256];
    ushort_t* As = SM;
    ushort_t* Bs = SM + 8192;
    ushort_t* PS = SM + 17408;                   // 8192 ushorts: 128f x 64k proj half
    const int tid = threadIdx.x;
    const int n0 = blockIdx.x * 128, m0 = blockIdx.y * 128, z = blockIdx.z;
    const ushort_t* Bt = (z == 0) ? Wtq : ((z == 1) ? Wtk : Wtv);

    floatx4 zero = {0.f, 0.f, 0.f, 0.f};
    floatx4 acc[4][4];
#pragma unroll
    for (int i = 0; i < 4; i++)
#pragma unroll
        for (int j = 0; j < 4; j++) acc[i][j] = zero;

    mfma_mainloop(xb + (size_t)m0 * DIMM, Bt + (size_t)n0 * DIMM, As, Bs,
                  DIMM, DIMM, DIMM, acc, tid);

    const int lane = tid & 63, wid = tid >> 6;
    const int q = lane >> 4, cl = lane & 15;
    const int wm = (wid >> 1) * 64, wn = (wid & 1) * 64;

    // C tile -> LDS (stride 136: 16B-aligned rows, 2-way bank aliasing = free)
#pragma unroll
    for (int i = 0; i < 4; i++)
#pragma unroll
        for (int j = 0; j < 4; j++) {
            const int col = wn + j * 16 + cl;
#pragma unroll
            for (int r = 0; r < 4; r++) {
                const int row = wm + i * 16 + q * 4 + r;
                SM[row * 136 + col] = f2bf(acc[i][j][r]);
            }
        }
    __syncthreads();

    if (z < 2) {
        ushort_t* ob = (z == 0) ? qb : kb;
        if (z == 1) {
            // prefetch proj half 0 (f rows 0..127) while we do the kb stores
#pragma unroll
            for (int t = 0; t < 4; t++) {
                const int g = t * 256 + tid, f = g >> 3, kbg = (g & 7) ^ (f & 7);
                gload16(projb + (size_t)f * 64 + kbg * 8, PS + (size_t)g * 8);
            }
        }
#pragma unroll
        for (int p = 0; p < 16; p++) {
            const int idx = p * 256 + tid;
            const int row = idx >> 5, c4 = idx & 31;
            ushort4 o = *(const ushort4*)&SM[row * 136 + c4 * 4];
            *(ushort4*)(ob + (size_t)(m0 + row) * DIMM + n0 + c4 * 4) = o;
        }
        if (z == 1) {
            // fused key-feature max for the 2 heads in this tile
            const int bb = m0 >> 11;
            const int h0 = n0 >> 6;
            float mx[2] = {-3.0e38f, -3.0e38f};
#pragma unroll
            for (int half = 0; half < 2; half++) {
                __syncthreads();   // PS DMA drained; prior-half frag reads done
#pragma unroll
                for (int hh = 0; hh < 2; hh++) {
                    floatx4 a2[4][4];
#pragma unroll
                    for (int i = 0; i < 4; i++)
#pragma unroll
                        for (int j = 0; j < 4; j++) a2[i][j] = zero;
#pragma unroll
                    for (int ks = 0; ks < 2; ks++) {
                        bf16x8 af[4], bfr[4];
#pragma unroll
                        for (int i = 0; i < 4; i++)
                            af[i] = *(const bf16x8*)&SM[(wm + i * 16 + cl) * 136 + hh * 64 + (ks * 4 + q) * 8];
#pragma unroll
                        for (int j = 0; j < 4; j++)
                            bfr[j] = frag8(PS, wn + j * 16 + cl, ks * 4 + q);
#pragma unroll
                        for (int i = 0; i < 4; i++)
#pragma unroll
                            for (int j = 0; j < 4; j++)
                                a2[i][j] = __builtin_amdgcn_mfma_f32_16x16x32_bf16(
                                    af[i], bfr[j], a2[i][j], 0, 0, 0);
                    }
#pragma unroll
                    for (int i = 0; i < 4; i++)
#pragma unroll
                        for (int j = 0; j < 4; j++)
#pragma unroll
                            for (int r = 0; r < 4; r++) mx[hh] = fmaxf(mx[hh], a2[i][j][r]);
                }
                if (half == 0) {
                    __syncthreads();   // all waves done reading PS half 0
#pragma unroll
                    for (int t = 0; t < 4; t++) {
                        const int g = t * 256 + tid, f = g >> 3, kbg = (g & 7) ^ (f & 7);
                        gload16(projb + (size_t)(128 + f) * 64 + kbg * 8, PS + (size_t)g * 8);
                    }
                }
            }
#pragma unroll
            for (int hh = 0; hh < 2; hh++) {
                __syncthreads();
                red[tid] = mx[hh];
                __syncthreads();
                for (int s = 128; s > 0; s >>= 1) {
                    if (tid < s) red[tid] = fmaxf(red[tid], red[tid + s]);
                    __syncthreads();
                }
                if (tid == 0) atomicMax(&mk_u[bb * NH + h0 + hh], enc_f(red[0]));
            }
        }
    } else {
        const int bb = m0 >> 11, nbase = m0 & 2047;
#pragma unroll
        for (int p = 0; p < 16; p++) {
            const int idx = p * 256 + tid;
            const int cl2 = idx >> 5, n4 = idx & 31;
            const int C = n0 + cl2;
            const int h = C >> 6, e = C & 63;
            union { ushort4 v4; unsigned short s[4]; } pk;
#pragma unroll
            for (int k = 0; k < 4; k++) pk.s[k] = SM[(n4 * 4 + k) * 136 + cl2];
            *(ushort4*)(vTb + (((size_t)(bb * NH + h) * 64 + e)) * NSEQ + nbase + n4 * 4) = pk.v4;
        }
    }
}

// ---------- output projection ----------
__global__ __launch_bounds__(256)
void gemm_out(const ushort_t* __restrict__ attnb, const ushort_t* __restrict__ Wto,
              float* __restrict__ out, const float* __restrict__ bias)
{
    __shared__ alignas(16) ushort_t As[8192];
    __shared__ alignas(16) ushort_t Bs[8192];
    const int tid = threadIdx.x;
    const int n0 = blockIdx.x * 128, m0 = blockIdx.y * 128;

    floatx4 zero = {0.f, 0.f, 0.f, 0.f};
    floatx4 acc[4][4];
#pragma unroll
    for (int i = 0; i < 4; i++)
#pragma unroll
        for (int j = 0; j < 4; j++) acc[i][j] = zero;

    mfma_mainloop(attnb + (size_t)m0 * DIMM, Wto + (size_t)n0 * DIMM, As, Bs,
                  DIMM, DIMM, DIMM, acc, tid);

    const int lane = tid & 63, wid = tid >> 6;
    const int q = lane >> 4, c = lane & 15;
    const int wm = (wid >> 1) * 64, wn = (wid & 1) * 64;
#pragma unroll
    for (int i = 0; i < 4; i++)
#pragma unroll
        for (int j = 0; j < 4; j++) {
            const int col = n0 + wn + j * 16 + c;
            const float bv = bias[col];
#pragma unroll
            for (int r = 0; r < 4; r++) {
                const int row = m0 + wm + i * 16 + q * 4 + r;
                out[(size_t)row * DIMM + col] = acc[i][j][r] + bv;
            }
        }
}

// =====================================================================
// featx: features + exp; query -> qfb; key -> kfb + Ksum + fused CTXT
// (key m-tile == one chunk).
// =====================================================================
__global__ __launch_bounds__(256)
void featx(const ushort_t* __restrict__ qb_, const ushort_t* __restrict__ kb_,
           const ushort_t* __restrict__ projb, const unsigned* __restrict__ mk_u,
           const ushort_t* __restrict__ vTb,
           ushort_t* __restrict__ qfb, ushort_t* __restrict__ kfb,
           float* __restrict__ CTXT, float* __restrict__ Ksum)
{
    __shared__ alignas(16) ushort_t SM[24576];   // staging As(8192)+Bs(16384); reused
    __shared__ float dtmp[256];
    __shared__ float diag_l[128];
    __shared__ float mx2[2][128];
    __shared__ float colp[2][256];
    ushort_t* As = SM;
    ushort_t* Bs = SM + 8192;
    const int tid = threadIdx.x, lane = tid & 63, wid = tid >> 6;
    const int q = lane >> 4, cl = lane & 15;
    const int m0 = blockIdx.x * 128, h = blockIdx.y, src = blockIdx.z;
    const int bb = m0 >> 11, nloc = m0 & 2047;
    const int bh = bb * NH + h;
    const int cidx = nloc >> 7;
    const ushort_t* Aq = (src ? kb_ : qb_) + (size_t)m0 * DIMM + h * 64;

    // diag[row] = sum(qk^2)/16 (from the same bf16 inputs the GEMM uses)
    {
        const int row = tid >> 1, half = tid & 1;
        float s = 0.f;
        const ushort_t* p = Aq + (size_t)row * DIMM + half * 32;
#pragma unroll
        for (int d = 0; d < 32; d += 4) {
            ushort4 w = *(const ushort4*)(p + d);
            float a = bf2f(w.x), b2 = bf2f(w.y), c2 = bf2f(w.z), d2 = bf2f(w.w);
            s += a * a + b2 * b2 + c2 * c2 + d2 * d2;
        }
        dtmp[tid] = s;
    }
    __syncthreads();
    if (tid < 128) diag_l[tid] = (dtmp[2 * tid] + dtmp[2 * tid + 1]) * 0.0625f;

    // stage A (128x64) and proj (256x64)
#pragma unroll
    for (int t = 0; t < 4; t++) {
        const int g = t * 256 + tid, r = g >> 3, kb = (g & 7) ^ (r & 7);
        gload16(Aq + (size_t)r * DIMM + kb * 8, As + (size_t)g * 8);
    }
#pragma unroll
    for (int t = 0; t < 8; t++) {
        const int g = t * 256 + tid, r = g >> 3, kb = (g & 7) ^ (r & 7);
        gload16(projb + (size_t)r * 64 + kb * 8, Bs + (size_t)g * 8);
    }
    __syncthreads();

    floatx4 zero = {0.f, 0.f, 0.f, 0.f};
    floatx4 acc[4][8];
#pragma unroll
    for (int i = 0; i < 4; i++)
#pragma unroll
        for (int j = 0; j < 8; j++) acc[i][j] = zero;
    const int wm = (wid >> 1) * 64, wn = (wid & 1) * 128;
#pragma unroll
    for (int ks = 0; ks < 2; ks++) {
        bf16x8 af[4], bfr[8];
#pragma unroll
        for (int i = 0; i < 4; i++) af[i] = frag8(As, wm + i * 16 + cl, ks * 4 + q);
#pragma unroll
        for (int j = 0; j < 8; j++) bfr[j] = frag8(Bs, wn + j * 16 + cl, ks * 4 + q);
#pragma unroll
        for (int i = 0; i < 4; i++)
#pragma unroll
            for (int j = 0; j < 8; j++)
                acc[i][j] = __builtin_amdgcn_mfma_f32_16x16x32_bf16(
                    af[i], bfr[j], acc[i][j], 0, 0, 0);
    }

    const float mk = src ? dec_f(mk_u[bh]) : 0.f;
    if (src == 0) {
        // per-row max (both f-halves, via LDS across wave pairs)
#pragma unroll
        for (int i = 0; i < 4; i++)
#pragma unroll
            for (int r = 0; r < 4; r++) {
                const int row = wm + i * 16 + q * 4 + r;
                float mx = -3.0e38f;
#pragma unroll
                for (int j = 0; j < 8; j++) mx = fmaxf(mx, acc[i][j][r]);
                mx = fmaxf(mx, __shfl_xor(mx, 1)); mx = fmaxf(mx, __shfl_xor(mx, 2));
                mx = fmaxf(mx, __shfl_xor(mx, 4)); mx = fmaxf(mx, __shfl_xor(mx, 8));
                if (cl == 0) mx2[wid & 1][row] = mx;
            }
    }
    __syncthreads();   // mx2/diag visible; frag ds_reads complete (SM reusable)

    // exp-normalize in place
#pragma unroll
    for (int i = 0; i < 4; i++)
#pragma unroll
        for (int r = 0; r < 4; r++) {
            const int row = wm + i * 16 + q * 4 + r;
            const float cc = diag_l[row] + (src ? mk : fmaxf(mx2[0][row], mx2[1][row]));
#pragma unroll
            for (int j = 0; j < 8; j++)
                acc[i][j][r] = 0.0625f * (__expf(acc[i][j][r] - cc) + 1.0e-4f);
        }

    // key: column sums from registers (quad shuffles)
    if (src) {
#pragma unroll
        for (int j = 0; j < 8; j++) {
            float s = 0.f;
#pragma unroll
            for (int i = 0; i < 4; i++)
                s += acc[i][j][0] + acc[i][j][1] + acc[i][j][2] + acc[i][j][3];
            s += __shfl_xor(s, 16);
            s += __shfl_xor(s, 32);
            if (q == 0) colp[wid >> 1][wn + j * 16 + cl] = s;
        }
    }

    ushort_t* ff = src ? kfb : qfb;
    const size_t frow = (size_t)bh * NSEQ + nloc;

#pragma unroll
    for (int hf = 0; hf < 2; hf++) {
        __syncthreads();   // colp visible (hf=0); prior reads done (hf=1)
        if ((wid & 1) == hf) {
#pragma unroll
            for (int i = 0; i < 4; i++)
#pragma unroll
                for (int j = 0; j < 8; j++) {
                    const int col = j * 16 + cl;
#pragma unroll
                    for (int r = 0; r < 4; r++) {
                        const int row = wm + i * 16 + q * 4 + r;
                        SM[row * 132 + col] = f2bf(acc[i][j][r]);
                    }
                }
        }
        if (hf == 0 && src) {
            Ksum[((size_t)bh * NCHK + cidx) * FF + tid] = colp[0][tid] + colp[1][tid];
        }
        __syncthreads();
        // coalesced [n][f] stores
#pragma unroll
        for (int p = 0; p < 16; p++) {
            const int idx = p * 256 + tid;
            const int row = idx >> 5, c4 = idx & 31;
            ushort4 o = *(const ushort4*)&SM[row * 132 + c4 * 4];
            *(ushort4*)(ff + (frow + row) * FF + hf * 128 + c4 * 4) = o;
        }
    }

    if (src == 0) return;

    // fused ctx: CTXT[bh][cidx][e][f] = sum_n vT[e][n] * kf[n][f]
    __syncthreads();   // all kfb-store reads of SM done before overwrite
    ushort_t* Vs = SM;
    ushort_t* T  = SM + 8192;
    const ushort_t* Vg = vTb + ((size_t)bh * 64) * NSEQ + nloc;
#pragma unroll
    for (int t = 0; t < 4; t++) {
        const int g = t * 256 + tid, r = g >> 4, kb = (g & 15) ^ (r & 15);
        gload16(Vg + (size_t)r * NSEQ + kb * 8, Vs + (size_t)g * 8);
    }

    const size_t cbase = ((size_t)bh * NCHK + cidx) * 64;
#pragma unroll
    for (int fq = 0; fq < 4; fq++) {
        if ((wid & 1) == (fq >> 1)) {
#pragma unroll
            for (int jj = 0; jj < 4; jj++) {
                const int j = (fq & 1) * 4 + jj;
#pragma unroll
                for (int i = 0; i < 4; i++)
#pragma unroll
                    for (int r = 0; r < 4; r++) {
                        const int n = wm + i * 16 + q * 4 + r;
                        T[(jj * 16 + cl) * 136 + n] = f2bf(acc[i][j][r]);
                    }
            }
        }
        __syncthreads();   // T ready; (fq=0) also drains Vs DMA
        floatx4 accc[4];
#pragma unroll
        for (int jj = 0; jj < 4; jj++) accc[jj] = zero;
#pragma unroll
        for (int kt = 0; kt < 4; kt++) {
            const bf16x8 av = fragS(Vs, wid * 16 + cl, kt * 4 + q);
#pragma unroll
            for (int jj = 0; jj < 4; jj++) {
                const bf16x8 bv = *(const bf16x8*)(T + (jj * 16 + cl) * 136 + (kt * 4 + q) * 8);
                accc[jj] = __builtin_amdgcn_mfma_f32_16x16x32_bf16(av, bv, accc[jj], 0, 0, 0);
            }
        }
#pragma unroll
        for (int jj = 0; jj < 4; jj++) {
            const int f = fq * 64 + jj * 16 + cl;
#pragma unroll
            for (int r = 0; r < 4; r++) {
                const int e = wid * 16 + q * 4 + r;
                CTXT[(cbase + e) * FF + f] = accc[jj][r];
            }
        }
        __syncthreads();   // before next quarter's T overwrite
    }
}

// ---------- merged exclusive prefixes: blocks [0,1024) S-path, [1024,1040) Z-path ----------
__global__ void prefix_zs(float* __restrict__ Ksum, float* __restrict__ Zout,
                          const float* __restrict__ CTXT, ushort_t* __restrict__ ctxp,
                          float* __restrict__ Sout)
{
    const int b = blockIdx.x;
    if (b < 1024) {
        const int idx = b * 256 + threadIdx.x;
        const int bh = idx >> 14, ef = idx & 16383;
        const int e = ef >> 8, f = ef & 255;
        float run = 0.f;
#pragma unroll
        for (int c = 0; c < NCHK; c++) {
            const size_t o = (((size_t)bh * NCHK + c) * 64 + e) * FF + f;
            const float t = CTXT[o];
            ctxp[o] = f2bf(run);
            run += t;
        }
        Sout[((size_t)bh * FF + f) * 64 + e] = run;   // S[b,h,f,e]
    } else {
        const int idx = (b - 1024) * 256 + threadIdx.x;
        const int bh = idx >> 8, f = idx & 255;
        float run = 0.f;
#pragma unroll
        for (int c = 0; c < NCHK; c++) {
            const size_t o = ((size_t)(bh * NCHK + c)) * FF + f;
            const float t = Ksum[o];
            Ksum[o] = run;
            run += t;
        }
        Zout[(size_t)bh * FF + f] = run;
    }
}

// ---------- chunk output, full MFMA ----------
__global__ __launch_bounds__(256)
void chunk_out_mfma(const ushort_t* __restrict__ qfb, const ushort_t* __restrict__ kfb,
                    const ushort_t* __restrict__ vTb, const float* __restrict__ Zex,
                    const ushort_t* __restrict__ ctxp, ushort_t* __restrict__ attnb)
{
    __shared__ alignas(16) ushort_t Sld[16384];  // 32 KB: S (128x128) / out-tile reuse
    __shared__ alignas(16) ushort_t As[8192];    // 16 KB
    __shared__ alignas(16) ushort_t Bs[8192];    // 16 KB
    __shared__ float zeps[256];
    __shared__ float rows_part[2][128];
    __shared__ float denp[256];
    __shared__ float den_l[128];

    const int tid = threadIdx.x, lane = tid & 63, wid = tid >> 6;
    const int q = lane >> 4, cl = lane & 15;
    const int bh = blockIdx.x >> 4, c = blockIdx.x & 15;
    const int bb = bh >> 3, h = bh & 7;
    const int n0 = c * CHK;
    const ushort_t* Q  = qfb + ((size_t)bh * NSEQ + n0) * FF;
    const ushort_t* Kf = kfb + ((size_t)bh * NSEQ + n0) * FF;

    zeps[tid] = Zex[((size_t)bh * NCHK + c) * FF + tid] + 1.0e-6f;

    // ---- stage 1: S = Q @ Kf^T (K=256), wave-grid 2x2 ----
    floatx4 zero = {0.f, 0.f, 0.f, 0.f};
    floatx4 acc1[4][4];
#pragma unroll
    for (int i = 0; i < 4; i++)
#pragma unroll
        for (int j = 0; j < 4; j++) acc1[i][j] = zero;
    const int wm = (wid >> 1) * 64, wn = (wid & 1) * 64;
    for (int k0 = 0; k0 < FF; k0 += 64) {
#pragma unroll
        for (int t = 0; t < 4; t++) {
            const int g = t * 256 + tid, r = g >> 3, kb = (g & 7) ^ (r & 7);
            gload16(Q + (size_t)r * FF + k0 + kb * 8, As + (size_t)g * 8);
        }
#pragma unroll
        for (int t = 0; t < 4; t++) {
            const int g = t * 256 + tid, r = g >> 3, kb = (g & 7) ^ (r & 7);
            gload16(Kf + (size_t)r * FF + k0 + kb * 8, Bs + (size_t)g * 8);
        }
        __syncthreads();
#pragma unroll
        for (int ks = 0; ks < 2; ks++) {
            bf16x8 af[4], bfr[4];
#pragma unroll
            for (int i = 0; i < 4; i++) {
                af[i]  = frag8(As, wm + i * 16 + cl, ks * 4 + q);
                bfr[i] = frag8(Bs, wn + i * 16 + cl, ks * 4 + q);
            }
#pragma unroll
            for (int i = 0; i < 4; i++)
#pragma unroll
                for (int j = 0; j < 4; j++)
                    acc1[i][j] = __builtin_amdgcn_mfma_f32_16x16x32_bf16(
                        af[i], bfr[j], acc1[i][j], 0, 0, 0);
        }
        __syncthreads();
    }
    // ---- causal mask + rowsum(fp32) + S -> LDS (bf16, swizzled granules) ----
#pragma unroll
    for (int i = 0; i < 4; i++)
#pragma unroll
        for (int r = 0; r < 4; r++) {
            const int row = wm + i * 16 + q * 4 + r;
            float part = 0.f;
#pragma unroll
            for (int j = 0; j < 4; j++) {
                const int col = wn + j * 16 + cl;
                const float v = (col <= row) ? acc1[i][j][r] : 0.f;
                part += v;
                Sld[(row * 16 + ((col >> 3) ^ (row & 15))) * 8 + (col & 7)] = f2bf(v);
            }
            part += __shfl_xor(part, 1); part += __shfl_xor(part, 2);
            part += __shfl_xor(part, 4); part += __shfl_xor(part, 8);
            if (cl == 0) rows_part[wid & 1][row] = part;
        }
    __syncthreads();

    // ---- stage 3: acc2[e][row] += vT (x) S  (K = 128 seq) ----
    floatx4 acc2[4][2];
#pragma unroll
    for (int i = 0; i < 4; i++)
#pragma unroll
        for (int j = 0; j < 2; j++) acc2[i][j] = zero;
    const ushort_t* Vt = vTb + ((size_t)bh * 64) * NSEQ + n0;
    for (int k0 = 0; k0 < CHK; k0 += 64) {
#pragma unroll
        for (int t = 0; t < 2; t++) {
            const int g = t * 256 + tid, r = g >> 3, kb = (g & 7) ^ (r & 7);
            gload16(Vt + (size_t)r * NSEQ + k0 + kb * 8, As + (size_t)g * 8);
        }
        __syncthreads();
#pragma unroll
        for (int ks = 0; ks < 2; ks++) {
            bf16x8 af[4], bfr[2];
            const int kbS = (k0 >> 3) + ks * 4 + q;
#pragma unroll
            for (int i = 0; i < 4; i++) af[i] = frag8(As, i * 16 + cl, ks * 4 + q);
#pragma unroll
            for (int j = 0; j < 2; j++) bfr[j] = fragS(Sld, wid * 32 + j * 16 + cl, kbS);
#pragma unroll
            for (int i = 0; i < 4; i++)
#pragma unroll
                for (int j = 0; j < 2; j++)
                    acc2[i][j] = __builtin_amdgcn_mfma_f32_16x16x32_bf16(
                        af[i], bfr[j], acc2[i][j], 0, 0, 0);
        }
        __syncthreads();
    }

    // ---- stage 4: acc2 += ctxp (x) Q  (K = 256 features); den from staged Q ----
    const ushort_t* Cp = ctxp + ((size_t)bh * NCHK + c) * 64 * FF;
    float dacc = 0.f;
    const int drow = tid & 127, dhalf = tid >> 7;
    for (int k0 = 0; k0 < FF; k0 += 64) {
#pragma unroll
        for (int t = 0; t < 2; t++) {
            const int g = t * 256 + tid, r = g >> 3, kb = (g & 7) ^ (r & 7);
            gload16(Cp + (size_t)r * FF + k0 + kb * 8, As + (size_t)g * 8);
        }
#pragma unroll
        for (int t = 0; t < 4; t++) {
            const int g = t * 256 + tid, r = g >> 3, kb = (g & 7) ^ (r & 7);
            gload16(Q + (size_t)r * FF + k0 + kb * 8, Bs + (size_t)g * 8);
        }
        __syncthreads();
#pragma unroll
        for (int ks = 0; ks < 2; ks++) {
            bf16x8 af[4], bfr[2];
#pragma unroll
            for (int i = 0; i < 4; i++) af[i] = frag8(As, i * 16 + cl, ks * 4 + q);
#pragma unroll
            for (int j = 0; j < 2; j++) bfr[j] = frag8(Bs, wid * 32 + j * 16 + cl, ks * 4 + q);
#pragma unroll
            for (int i = 0; i < 4; i++)
#pragma unroll
                for (int j = 0; j < 2; j++)
                    acc2[i][j] = __builtin_amdgcn_mfma_f32_16x16x32_bf16(
                        af[i], bfr[j], acc2[i][j], 0, 0, 0);
        }
        // den partial: this thread's row, its 32-feature half of this k-step
#pragma unroll
        for (int gi = 0; gi < 4; gi++) {
            const int kb = dhalf * 4 + gi;
            const ushort_t* gp = Bs + ((size_t)drow * 8 + (kb ^ (drow & 7))) * 8;
            const int kbase = k0 + kb * 8;
#pragma unroll
            for (int e2 = 0; e2 < 8; e2++)
                dacc = fmaf(bf2f(gp[e2]), zeps[kbase + e2], dacc);
        }
        __syncthreads();
    }
    denp[tid] = dacc;
    __syncthreads();
    if (tid < 128)
        den_l[tid] = rows_part[0][tid] + rows_part[1][tid] + denp[tid] + denp[tid + 128];
    __syncthreads();

    // ---- epilogue: divide, transpose via LDS, coalesced bf16 store ----
#pragma unroll
    for (int j = 0; j < 2; j++) {
        const int row = wid * 32 + j * 16 + cl;
        const float dinv = 1.0f / den_l[row];
#pragma unroll
        for (int i = 0; i < 4; i++)
#pragma unroll
            for (int r = 0; r < 4; r++) {
                const int e = i * 16 + q * 4 + r;
                Sld[row * 68 + e] = f2bf(acc2[i][j][r] * dinv);
            }
    }
    __syncthreads();
#pragma unroll
    for (int p = 0; p < 8; p++) {
        const int idx = p * 256 + tid;
        const int row = idx >> 4, e4 = idx & 15;
        ushort4 o = *(const ushort4*)&Sld[row * 68 + e4 * 4];
        *(ushort4*)(attnb + ((size_t)(bb * NSEQ + n0 + row)) * DIMM + h * 64 + e4 * 4) = o;
    }
}

extern "C" void kernel_launch(void* const* d_in, const int* in_sizes, int n_in,
                              void* d_out, int out_size, void* d_ws, size_t ws_size,
                              hipStream_t stream)
{
    (void)in_sizes; (void)n_in; (void)out_size; (void)ws_size;
    const float* x    = (const float*)d_in[0];
    const float* proj = (const float*)d_in[1];
    const float* Wq   = (const float*)d_in[2];
    const float* Wk   = (const float*)d_in[3];
    const float* Wv   = (const float*)d_in[4];
    const float* Wo   = (const float*)d_in[5];
    const float* bo   = (const float*)d_in[6];
    float* out = (float*)d_out;

    // ---- workspace carve (~70 MB) ----
    char* W = (char*)d_ws;
    float*    CTXT = (float*)W;              W += (size_t)16777216;   // [bh][c][e][f] fp32
    ushort_t* qfb  = (ushort_t*)W;           W += (size_t)16777216;   // [bh][n][f] bf16
    ushort_t* kfb  = (ushort_t*)W;           W += (size_t)16777216;
    ushort_t* qb   = (ushort_t*)W;           W += (size_t)4194304;    // [n][dim] bf16
    ushort_t* kb   = (ushort_t*)W;           W += (size_t)4194304;    // contiguous after qb
    ushort_t* xb   = (ushort_t*)W;           W += (size_t)4194304;    // reused as attnb
    ushort_t* vTb  = (ushort_t*)W;           W += (size_t)4194304;    // [bh][e][n]
    ushort_t* Wtq  = (ushort_t*)W;           W += (size_t)524288;
    ushort_t* Wtk  = (ushort_t*)W;           W += (size_t)524288;
    ushort_t* Wtv  = (ushort_t*)W;           W += (size_t)524288;
    ushort_t* Wto  = (ushort_t*)W;           W += (size_t)524288;
    ushort_t* projb = (ushort_t*)W;          W += (size_t)32768;
    float*    Ksum = (float*)W;              W += (size_t)262144;     // [bh][c][f]
    unsigned* mk_u = (unsigned*)W;           W += (size_t)256;

    // aliases (lifetime-disjoint)
    ushort_t* ctxp = qb;           // prefix writes bf16 prefix into qb+kb (8.4 MB), dead by then
    ushort_t* attnb = xb;          // xb dead after gemm_qkv

    float* Zout = out + (size_t)4096 * 512;
    float* Sout = Zout + (size_t)NBH * FF;

    hipLaunchKernelGGL(prep, dim3(3089), dim3(256), 0, stream,
                       x, proj, Wq, Wk, Wv, Wo, xb, projb, Wtq, Wtk, Wtv, Wto, mk_u);
    hipLaunchKernelGGL(gemm_qkv, dim3(4, 32, 3), dim3(256), 0, stream,
                       xb, Wtq, Wtk, Wtv, projb, qb, kb, vTb, mk_u);
    hipLaunchKernelGGL(featx, dim3(32, 8, 2), dim3(256), 0, stream,
                       qb, kb, projb, mk_u, vTb, qfb, kfb, CTXT, Ksum);
    hipLaunchKernelGGL(prefix_zs, dim3(1040), dim3(256), 0, stream,
                       Ksum, Zout, CTXT, ctxp, Sout);
    hipLaunchKernelGGL(chunk_out_mfma, dim3(256), dim3(256), 0, stream,
                       qfb, kfb, vTb, Ksum, ctxp, attnb);
    hipLaunchKernelGGL(gemm_out, dim3(4, 32), dim3(256), 0, stream, attnb, Wto, out, bo);
}

// Round 9
// 149.384 us; speedup vs baseline: 2.8773x; 1.0414x over previous
//
#include <hip/hip_runtime.h>
#include <hip/hip_bf16.h>
#include <math.h>

// Problem constants (b=2, n=2048, dim=512, h=8, dh=64, f=256, chunk=128)
#define NB    2
#define NSEQ  2048
#define DIMM  512
#define NH    8
#define DHd   64
#define FF    256
#define CHK   128
#define NCHK  16
#define NBH   16   // NB*NH

typedef unsigned short ushort_t;
typedef __attribute__((ext_vector_type(8))) __bf16 bf16x8;
typedef __attribute__((ext_vector_type(4))) float floatx4;

__device__ __forceinline__ unsigned short f2bf(float x) {
    union { __hip_bfloat16 h; unsigned short u; } v;
    v.h = __float2bfloat16(x);
    return v.u;
}
__device__ __forceinline__ float bf2f(unsigned short u) {
    union { unsigned short u2[2]; float f; } v;
    v.u2[0] = 0; v.u2[1] = u;
    return v.f;
}
__device__ __forceinline__ unsigned enc_f(float x) {
    unsigned u = __float_as_uint(x);
    return (u & 0x80000000u) ? ~u : (u | 0x80000000u);
}
__device__ __forceinline__ float dec_f(unsigned e) {
    unsigned u = (e & 0x80000000u) ? (e & 0x7fffffffu) : ~e;
    return __uint_as_float(u);
}

__device__ __forceinline__ void gload16(const void* g, void* l) {
    __builtin_amdgcn_global_load_lds(
        (const __attribute__((address_space(1))) void*)g,
        (__attribute__((address_space(3))) void*)l, 16, 0, 0);
}

// frag read from a 64-k-step tile (8 granules/row, xor-swizzled)
__device__ __forceinline__ bf16x8 frag8(const ushort_t* lds, int row, int kb) {
    return *((const bf16x8*)lds + row * 8 + (kb ^ (row & 7)));
}
// frag read from a 128-k tile (16 granules/row)
__device__ __forceinline__ bf16x8 fragS(const ushort_t* lds, int row, int kb) {
    return *((const bf16x8*)lds + row * 16 + (kb ^ (row & 15)));
}

// =====================================================================
// prep: init mk_u + conv x->bf16 + conv proj->bf16(*dn) + transpose W's
// =====================================================================
__global__ __launch_bounds__(256)
void prep(const float* __restrict__ x, const float* __restrict__ proj,
          const float* __restrict__ W0, const float* __restrict__ W1,
          const float* __restrict__ W2, const float* __restrict__ W3,
          ushort_t* __restrict__ xb, ushort_t* __restrict__ projb,
          ushort_t* __restrict__ T0, ushort_t* __restrict__ T1,
          ushort_t* __restrict__ T2, ushort_t* __restrict__ T3,
          unsigned* __restrict__ mk_u)
{
    __shared__ float t[32][33];
    const int b = blockIdx.x, tid = threadIdx.x;
    if (b < 2048) {
        const int gid = b * 256 + tid;
        const float4 v = *(const float4*)(x + (size_t)gid * 4);
        union { ushort4 v4; unsigned short s[4]; } pk;
        pk.s[0] = f2bf(v.x); pk.s[1] = f2bf(v.y); pk.s[2] = f2bf(v.z); pk.s[3] = f2bf(v.w);
        ((ushort4*)xb)[gid] = pk.v4;
    } else if (b < 2064) {
        const int gid = (b - 2048) * 256 + tid;
        const float dn = 0.35355339059327379f;   // 64^-0.25 folded into proj
        const float4 v = *(const float4*)(proj + (size_t)gid * 4);
        union { ushort4 v4; unsigned short s[4]; } pk;
        pk.s[0] = f2bf(v.x * dn); pk.s[1] = f2bf(v.y * dn);
        pk.s[2] = f2bf(v.z * dn); pk.s[3] = f2bf(v.w * dn);
        ((ushort4*)projb)[gid] = pk.v4;
    } else if (b < 3088) {
        const int idx = b - 2064;                // 0..1023
        const int z = idx >> 8, rem = idx & 255;
        const int bx = rem & 15, by = rem >> 4;
        const float* W = (z == 0) ? W0 : (z == 1) ? W1 : (z == 2) ? W2 : W3;
        ushort_t* T = (z == 0) ? T0 : (z == 1) ? T1 : (z == 2) ? T2 : T3;
        const int x0 = bx * 32, y0 = by * 32;
        const int tx = tid & 31, ty = tid >> 5;  // 32 x 8
#pragma unroll
        for (int i = 0; i < 4; i++)
            t[ty + i * 8][tx] = W[(size_t)(y0 + ty + i * 8) * DIMM + x0 + tx];
        __syncthreads();
#pragma unroll
        for (int i = 0; i < 4; i++)
            T[(size_t)(x0 + ty + i * 8) * DIMM + y0 + tx] = f2bf(t[tx][ty + i * 8]);
    } else {
        if (tid < NBH) mk_u[tid] = 0u;
    }
}

// =====================================================================
// MFMA main loop: C[128x128] += A[128xK] * B[128xK]^T
// =====================================================================
__device__ __forceinline__ void mfma_mainloop(
    const ushort_t* __restrict__ AG, const ushort_t* __restrict__ BG,
    ushort_t* As, ushort_t* Bs, int ldA, int ldB, int K,
    floatx4 acc[4][4], int tid)
{
    const int lane = tid & 63, wid = tid >> 6;
    const int q = lane >> 4, c = lane & 15;
    const int wm = (wid >> 1) * 64, wn = (wid & 1) * 64;

    for (int k0 = 0; k0 < K; k0 += 64) {
#pragma unroll
        for (int t = 0; t < 4; t++) {
            const int g = t * 256 + tid, r = g >> 3, kb = (g & 7) ^ (r & 7);
            gload16(AG + (size_t)r * ldA + k0 + kb * 8, As + (size_t)g * 8);
        }
#pragma unroll
        for (int t = 0; t < 4; t++) {
            const int g = t * 256 + tid, r = g >> 3, kb = (g & 7) ^ (r & 7);
            gload16(BG + (size_t)r * ldB + k0 + kb * 8, Bs + (size_t)g * 8);
        }
        __syncthreads();
#pragma unroll
        for (int ks = 0; ks < 2; ks++) {
            bf16x8 af[4], bfr[4];
#pragma unroll
            for (int i = 0; i < 4; i++) {
                af[i]  = frag8(As, wm + i * 16 + c, ks * 4 + q);
                bfr[i] = frag8(Bs, wn + i * 16 + c, ks * 4 + q);
            }
#pragma unroll
            for (int i = 0; i < 4; i++)
#pragma unroll
                for (int j = 0; j < 4; j++)
                    acc[i][j] = __builtin_amdgcn_mfma_f32_16x16x32_bf16(
                        af[i], bfr[j], acc[i][j], 0, 0, 0);
        }
        __syncthreads();
    }
}

// =====================================================================
// QKV projection: z=0 -> qb, z=1 -> kb (+ fused key-feature max), z=2 -> vTb.
// =====================================================================
__global__ __launch_bounds__(256)
void gemm_qkv(const ushort_t* __restrict__ xb,
              const ushort_t* __restrict__ Wtq, const ushort_t* __restrict__ Wtk,
              const ushort_t* __restrict__ Wtv, const ushort_t* __restrict__ projb,
              ushort_t* __restrict__ qb, ushort_t* __restrict__ kb,
              ushort_t* __restrict__ vTb, unsigned* __restrict__ mk_u)
{
    __shared__ alignas(16) ushort_t SM[25600];   // staging As/Bs; tile[128][136]; PS proj half
    __shared__ float red[256];
    ushort_t* As = SM;
    ushort_t* Bs = SM + 8192;
    ushort_t* PS = SM + 17408;                   // 8192 ushorts: 128f x 64k proj half
    const int tid = threadIdx.x;
    const int n0 = blockIdx.x * 128, m0 = blockIdx.y * 128, z = blockIdx.z;
    const ushort_t* Bt = (z == 0) ? Wtq : ((z == 1) ? Wtk : Wtv);

    floatx4 zero = {0.f, 0.f, 0.f, 0.f};
    floatx4 acc[4][4];
#pragma unroll
    for (int i = 0; i < 4; i++)
#pragma unroll
        for (int j = 0; j < 4; j++) acc[i][j] = zero;

    mfma_mainloop(xb + (size_t)m0 * DIMM, Bt + (size_t)n0 * DIMM, As, Bs,
                  DIMM, DIMM, DIMM, acc, tid);

    const int lane = tid & 63, wid = tid >> 6;
    const int q = lane >> 4, cl = lane & 15;
    const int wm = (wid >> 1) * 64, wn = (wid & 1) * 64;

    // C tile -> LDS (stride 136: 16B-aligned rows)
#pragma unroll
    for (int i = 0; i < 4; i++)
#pragma unroll
        for (int j = 0; j < 4; j++) {
            const int col = wn + j * 16 + cl;
#pragma unroll
            for (int r = 0; r < 4; r++) {
                const int row = wm + i * 16 + q * 4 + r;
                SM[row * 136 + col] = f2bf(acc[i][j][r]);
            }
        }
    __syncthreads();

    if (z < 2) {
        ushort_t* ob = (z == 0) ? qb : kb;
        if (z == 1) {
#pragma unroll
            for (int t = 0; t < 4; t++) {
                const int g = t * 256 + tid, f = g >> 3, kbg = (g & 7) ^ (f & 7);
                gload16(projb + (size_t)f * 64 + kbg * 8, PS + (size_t)g * 8);
            }
        }
#pragma unroll
        for (int p = 0; p < 16; p++) {
            const int idx = p * 256 + tid;
            const int row = idx >> 5, c4 = idx & 31;
            ushort4 o = *(const ushort4*)&SM[row * 136 + c4 * 4];
            *(ushort4*)(ob + (size_t)(m0 + row) * DIMM + n0 + c4 * 4) = o;
        }
        if (z == 1) {
            const int bb = m0 >> 11;
            const int h0 = n0 >> 6;
            float mx[2] = {-3.0e38f, -3.0e38f};
#pragma unroll
            for (int half = 0; half < 2; half++) {
                __syncthreads();   // PS DMA drained; prior-half frag reads done
#pragma unroll
                for (int hh = 0; hh < 2; hh++) {
                    floatx4 a2[4][4];
#pragma unroll
                    for (int i = 0; i < 4; i++)
#pragma unroll
                        for (int j = 0; j < 4; j++) a2[i][j] = zero;
#pragma unroll
                    for (int ks = 0; ks < 2; ks++) {
                        bf16x8 af[4], bfr[4];
#pragma unroll
                        for (int i = 0; i < 4; i++)
                            af[i] = *(const bf16x8*)&SM[(wm + i * 16 + cl) * 136 + hh * 64 + (ks * 4 + q) * 8];
#pragma unroll
                        for (int j = 0; j < 4; j++)
                            bfr[j] = frag8(PS, wn + j * 16 + cl, ks * 4 + q);
#pragma unroll
                        for (int i = 0; i < 4; i++)
#pragma unroll
                            for (int j = 0; j < 4; j++)
                                a2[i][j] = __builtin_amdgcn_mfma_f32_16x16x32_bf16(
                                    af[i], bfr[j], a2[i][j], 0, 0, 0);
                    }
#pragma unroll
                    for (int i = 0; i < 4; i++)
#pragma unroll
                        for (int j = 0; j < 4; j++)
#pragma unroll
                            for (int r = 0; r < 4; r++) mx[hh] = fmaxf(mx[hh], a2[i][j][r]);
                }
                if (half == 0) {
                    __syncthreads();
#pragma unroll
                    for (int t = 0; t < 4; t++) {
                        const int g = t * 256 + tid, f = g >> 3, kbg = (g & 7) ^ (f & 7);
                        gload16(projb + (size_t)(128 + f) * 64 + kbg * 8, PS + (size_t)g * 8);
                    }
                }
            }
#pragma unroll
            for (int hh = 0; hh < 2; hh++) {
                __syncthreads();
                red[tid] = mx[hh];
                __syncthreads();
                for (int s = 128; s > 0; s >>= 1) {
                    if (tid < s) red[tid] = fmaxf(red[tid], red[tid + s]);
                    __syncthreads();
                }
                if (tid == 0) atomicMax(&mk_u[bb * NH + h0 + hh], enc_f(red[0]));
            }
        }
    } else {
        const int bb = m0 >> 11, nbase = m0 & 2047;
#pragma unroll
        for (int p = 0; p < 16; p++) {
            const int idx = p * 256 + tid;
            const int cl2 = idx >> 5, n4 = idx & 31;
            const int C = n0 + cl2;
            const int h = C >> 6, e = C & 63;
            union { ushort4 v4; unsigned short s[4]; } pk;
#pragma unroll
            for (int k = 0; k < 4; k++) pk.s[k] = SM[(n4 * 4 + k) * 136 + cl2];
            *(ushort4*)(vTb + (((size_t)(bb * NH + h) * 64 + e)) * NSEQ + nbase + n4 * 4) = pk.v4;
        }
    }
}

// ---------- output projection ----------
__global__ __launch_bounds__(256)
void gemm_out(const ushort_t* __restrict__ attnb, const ushort_t* __restrict__ Wto,
              float* __restrict__ out, const float* __restrict__ bias)
{
    __shared__ alignas(16) ushort_t As[8192];
    __shared__ alignas(16) ushort_t Bs[8192];
    const int tid = threadIdx.x;
    const int n0 = blockIdx.x * 128, m0 = blockIdx.y * 128;

    floatx4 zero = {0.f, 0.f, 0.f, 0.f};
    floatx4 acc[4][4];
#pragma unroll
    for (int i = 0; i < 4; i++)
#pragma unroll
        for (int j = 0; j < 4; j++) acc[i][j] = zero;

    mfma_mainloop(attnb + (size_t)m0 * DIMM, Wto + (size_t)n0 * DIMM, As, Bs,
                  DIMM, DIMM, DIMM, acc, tid);

    const int lane = tid & 63, wid = tid >> 6;
    const int q = lane >> 4, c = lane & 15;
    const int wm = (wid >> 1) * 64, wn = (wid & 1) * 64;
#pragma unroll
    for (int i = 0; i < 4; i++)
#pragma unroll
        for (int j = 0; j < 4; j++) {
            const int col = n0 + wn + j * 16 + c;
            const float bv = bias[col];
#pragma unroll
            for (int r = 0; r < 4; r++) {
                const int row = m0 + wm + i * 16 + q * 4 + r;
                out[(size_t)row * DIMM + col] = acc[i][j][r] + bv;
            }
        }
}

// =====================================================================
// featk: key features + exp -> kfb + Ksum + fused CTXT (m-tile == chunk).
// (query path removed — chunk_out recomputes qf locally)
// =====================================================================
__global__ __launch_bounds__(256)
void featk(const ushort_t* __restrict__ kb_, const ushort_t* __restrict__ projb,
           const unsigned* __restrict__ mk_u, const ushort_t* __restrict__ vTb,
           ushort_t* __restrict__ kfb, float* __restrict__ CTXT,
           float* __restrict__ Ksum)
{
    __shared__ alignas(16) ushort_t SM[24576];   // staging As(8192)+Bs(16384); reused
    __shared__ float dtmp[256];
    __shared__ float diag_l[128];
    __shared__ float colp[2][256];
    ushort_t* As = SM;
    ushort_t* Bs = SM + 8192;
    const int tid = threadIdx.x, lane = tid & 63, wid = tid >> 6;
    const int q = lane >> 4, cl = lane & 15;
    const int m0 = blockIdx.x * 128, h = blockIdx.y;
    const int bb = m0 >> 11, nloc = m0 & 2047;
    const int bh = bb * NH + h;
    const int cidx = nloc >> 7;
    const ushort_t* Aq = kb_ + (size_t)m0 * DIMM + h * 64;

    // diag[row] = sum(k^2)/16
    {
        const int row = tid >> 1, half = tid & 1;
        float s = 0.f;
        const ushort_t* p = Aq + (size_t)row * DIMM + half * 32;
#pragma unroll
        for (int d = 0; d < 32; d += 4) {
            ushort4 w = *(const ushort4*)(p + d);
            float a = bf2f(w.x), b2 = bf2f(w.y), c2 = bf2f(w.z), d2 = bf2f(w.w);
            s += a * a + b2 * b2 + c2 * c2 + d2 * d2;
        }
        dtmp[tid] = s;
    }
    __syncthreads();
    if (tid < 128) diag_l[tid] = (dtmp[2 * tid] + dtmp[2 * tid + 1]) * 0.0625f;

#pragma unroll
    for (int t = 0; t < 4; t++) {
        const int g = t * 256 + tid, r = g >> 3, kb = (g & 7) ^ (r & 7);
        gload16(Aq + (size_t)r * DIMM + kb * 8, As + (size_t)g * 8);
    }
#pragma unroll
    for (int t = 0; t < 8; t++) {
        const int g = t * 256 + tid, r = g >> 3, kb = (g & 7) ^ (r & 7);
        gload16(projb + (size_t)r * 64 + kb * 8, Bs + (size_t)g * 8);
    }
    __syncthreads();

    floatx4 zero = {0.f, 0.f, 0.f, 0.f};
    floatx4 acc[4][8];
#pragma unroll
    for (int i = 0; i < 4; i++)
#pragma unroll
        for (int j = 0; j < 8; j++) acc[i][j] = zero;
    const int wm = (wid >> 1) * 64, wn = (wid & 1) * 128;
#pragma unroll
    for (int ks = 0; ks < 2; ks++) {
        bf16x8 af[4], bfr[8];
#pragma unroll
        for (int i = 0; i < 4; i++) af[i] = frag8(As, wm + i * 16 + cl, ks * 4 + q);
#pragma unroll
        for (int j = 0; j < 8; j++) bfr[j] = frag8(Bs, wn + j * 16 + cl, ks * 4 + q);
#pragma unroll
        for (int i = 0; i < 4; i++)
#pragma unroll
            for (int j = 0; j < 8; j++)
                acc[i][j] = __builtin_amdgcn_mfma_f32_16x16x32_bf16(
                    af[i], bfr[j], acc[i][j], 0, 0, 0);
    }
    __syncthreads();   // frag ds_reads complete (SM reusable); diag visible

    const float mk = dec_f(mk_u[bh]);
#pragma unroll
    for (int i = 0; i < 4; i++)
#pragma unroll
        for (int r = 0; r < 4; r++) {
            const int row = wm + i * 16 + q * 4 + r;
            const float cc = diag_l[row] + mk;
#pragma unroll
            for (int j = 0; j < 8; j++)
                acc[i][j][r] = 0.0625f * (__expf(acc[i][j][r] - cc) + 1.0e-4f);
        }

    // column sums from registers (quad shuffles)
#pragma unroll
    for (int j = 0; j < 8; j++) {
        float s = 0.f;
#pragma unroll
        for (int i = 0; i < 4; i++)
            s += acc[i][j][0] + acc[i][j][1] + acc[i][j][2] + acc[i][j][3];
        s += __shfl_xor(s, 16);
        s += __shfl_xor(s, 32);
        if (q == 0) colp[wid >> 1][wn + j * 16 + cl] = s;
    }

    const size_t frow = (size_t)bh * NSEQ + nloc;
#pragma unroll
    for (int hf = 0; hf < 2; hf++) {
        __syncthreads();   // colp visible (hf=0); prior reads done (hf=1)
        if ((wid & 1) == hf) {
#pragma unroll
            for (int i = 0; i < 4; i++)
#pragma unroll
                for (int j = 0; j < 8; j++) {
                    const int col = j * 16 + cl;
#pragma unroll
                    for (int r = 0; r < 4; r++) {
                        const int row = wm + i * 16 + q * 4 + r;
                        SM[row * 132 + col] = f2bf(acc[i][j][r]);
                    }
                }
        }
        if (hf == 0) {
            Ksum[((size_t)bh * NCHK + cidx) * FF + tid] = colp[0][tid] + colp[1][tid];
        }
        __syncthreads();
#pragma unroll
        for (int p = 0; p < 16; p++) {
            const int idx = p * 256 + tid;
            const int row = idx >> 5, c4 = idx & 31;
            ushort4 o = *(const ushort4*)&SM[row * 132 + c4 * 4];
            *(ushort4*)(kfb + (frow + row) * FF + hf * 128 + c4 * 4) = o;
        }
    }

    // fused ctx: CTXT[bh][cidx][e][f] = sum_n vT[e][n] * kf[n][f]
    __syncthreads();   // all kfb-store reads of SM done before overwrite
    ushort_t* Vs = SM;
    ushort_t* T  = SM + 8192;
    const ushort_t* Vg = vTb + ((size_t)bh * 64) * NSEQ + nloc;
#pragma unroll
    for (int t = 0; t < 4; t++) {
        const int g = t * 256 + tid, r = g >> 4, kb = (g & 15) ^ (r & 15);
        gload16(Vg + (size_t)r * NSEQ + kb * 8, Vs + (size_t)g * 8);
    }

    const size_t cbase = ((size_t)bh * NCHK + cidx) * 64;
#pragma unroll
    for (int fq = 0; fq < 4; fq++) {
        if ((wid & 1) == (fq >> 1)) {
#pragma unroll
            for (int jj = 0; jj < 4; jj++) {
                const int j = (fq & 1) * 4 + jj;
#pragma unroll
                for (int i = 0; i < 4; i++)
#pragma unroll
                    for (int r = 0; r < 4; r++) {
                        const int n = wm + i * 16 + q * 4 + r;
                        T[(jj * 16 + cl) * 136 + n] = f2bf(acc[i][j][r]);
                    }
            }
        }
        __syncthreads();   // T ready; (fq=0) also drains Vs DMA
        floatx4 accc[4];
#pragma unroll
        for (int jj = 0; jj < 4; jj++) accc[jj] = zero;
#pragma unroll
        for (int kt = 0; kt < 4; kt++) {
            const bf16x8 av = fragS(Vs, wid * 16 + cl, kt * 4 + q);
#pragma unroll
            for (int jj = 0; jj < 4; jj++) {
                const bf16x8 bv = *(const bf16x8*)(T + (jj * 16 + cl) * 136 + (kt * 4 + q) * 8);
                accc[jj] = __builtin_amdgcn_mfma_f32_16x16x32_bf16(av, bv, accc[jj], 0, 0, 0);
            }
        }
#pragma unroll
        for (int jj = 0; jj < 4; jj++) {
            const int f = fq * 64 + jj * 16 + cl;
#pragma unroll
            for (int r = 0; r < 4; r++) {
                const int e = wid * 16 + q * 4 + r;
                CTXT[(cbase + e) * FF + f] = accc[jj][r];
            }
        }
        __syncthreads();
    }
}

// ---------- merged exclusive prefixes: blocks [0,1024) S-path, [1024,1040) Z-path ----------
__global__ void prefix_zs(float* __restrict__ Ksum, float* __restrict__ Zout,
                          const float* __restrict__ CTXT, ushort_t* __restrict__ ctxp,
                          float* __restrict__ Sout)
{
    const int b = blockIdx.x;
    if (b < 1024) {
        const int idx = b * 256 + threadIdx.x;
        const int bh = idx >> 14, ef = idx & 16383;
        const int e = ef >> 8, f = ef & 255;
        float run = 0.f;
#pragma unroll
        for (int c = 0; c < NCHK; c++) {
            const size_t o = (((size_t)bh * NCHK + c) * 64 + e) * FF + f;
            const float t = CTXT[o];
            ctxp[o] = f2bf(run);
            run += t;
        }
        Sout[((size_t)bh * FF + f) * 64 + e] = run;   // S[b,h,f,e]
    } else {
        const int idx = (b - 1024) * 256 + threadIdx.x;
        const int bh = idx >> 8, f = idx & 255;
        float run = 0.f;
#pragma unroll
        for (int c = 0; c < NCHK; c++) {
            const size_t o = ((size_t)(bh * NCHK + c)) * FF + f;
            const float t = Ksum[o];
            Ksum[o] = run;
            run += t;
        }
        Zout[(size_t)bh * FF + f] = run;
    }
}

// =====================================================================
// chunk output, full MFMA. qf recomputed in-block into QF (LDS, 4 frag8
// slices); qfb global surface eliminated.
// =====================================================================
__global__ __launch_bounds__(256)
void chunk_out_mfma(const ushort_t* __restrict__ qb_, const ushort_t* __restrict__ projb,
                    const ushort_t* __restrict__ kfb, const ushort_t* __restrict__ vTb,
                    const float* __restrict__ Zex, const ushort_t* __restrict__ ctxp,
                    ushort_t* __restrict__ attnb)
{
    __shared__ alignas(16) ushort_t QF[32768];   // 64 KB: qf, 4 slices of [128][8 gran]
    __shared__ alignas(16) ushort_t Sld[16384];  // 32 KB: proj staging / S / out-tile
    __shared__ alignas(16) ushort_t As[8192];    // 16 KB
    __shared__ alignas(16) ushort_t Bs[8192];    // 16 KB
    __shared__ float zeps[256];
    __shared__ float rows_part[2][128];
    __shared__ float denp[256];
    __shared__ float den_l[128];
    __shared__ float dtmp[256];
    __shared__ float diag_l[128];
    __shared__ float mx2[2][128];

    const int tid = threadIdx.x, lane = tid & 63, wid = tid >> 6;
    const int q = lane >> 4, cl = lane & 15;
    const int bh = blockIdx.x >> 4, c = blockIdx.x & 15;
    const int bb = bh >> 3, h = bh & 7;
    const int n0 = c * CHK;
    const ushort_t* Kf = kfb + ((size_t)bh * NSEQ + n0) * FF;
    const ushort_t* Aq = qb_ + ((size_t)(bb * NSEQ + n0)) * DIMM + h * 64;

    zeps[tid] = Zex[((size_t)bh * NCHK + c) * FF + tid] + 1.0e-6f;

    // ---- phase 0: recompute qf chunk into QF ----
    {
        const int row = tid >> 1, half = tid & 1;
        float s = 0.f;
        const ushort_t* p = Aq + (size_t)row * DIMM + half * 32;
#pragma unroll
        for (int d = 0; d < 32; d += 4) {
            ushort4 w = *(const ushort4*)(p + d);
            float a = bf2f(w.x), b2 = bf2f(w.y), c2 = bf2f(w.z), d2 = bf2f(w.w);
            s += a * a + b2 * b2 + c2 * c2 + d2 * d2;
        }
        dtmp[tid] = s;
    }
    __syncthreads();
    if (tid < 128) diag_l[tid] = (dtmp[2 * tid] + dtmp[2 * tid + 1]) * 0.0625f;

#pragma unroll
    for (int t = 0; t < 4; t++) {
        const int g = t * 256 + tid, r = g >> 3, kb = (g & 7) ^ (r & 7);
        gload16(Aq + (size_t)r * DIMM + kb * 8, As + (size_t)g * 8);
    }
#pragma unroll
    for (int t = 0; t < 8; t++) {
        const int g = t * 256 + tid, r = g >> 3, kb = (g & 7) ^ (r & 7);
        gload16(projb + (size_t)r * 64 + kb * 8, Sld + (size_t)g * 8);
    }
    __syncthreads();

    floatx4 zero = {0.f, 0.f, 0.f, 0.f};
    {
        floatx4 accq[4][8];
#pragma unroll
        for (int i = 0; i < 4; i++)
#pragma unroll
            for (int j = 0; j < 8; j++) accq[i][j] = zero;
        const int wmF = (wid >> 1) * 64, wnF = (wid & 1) * 128;
#pragma unroll
        for (int ks = 0; ks < 2; ks++) {
            bf16x8 af[4], bfr[8];
#pragma unroll
            for (int i = 0; i < 4; i++) af[i] = frag8(As, wmF + i * 16 + cl, ks * 4 + q);
#pragma unroll
            for (int j = 0; j < 8; j++) bfr[j] = frag8(Sld, wnF + j * 16 + cl, ks * 4 + q);
#pragma unroll
            for (int i = 0; i < 4; i++)
#pragma unroll
                for (int j = 0; j < 8; j++)
                    accq[i][j] = __builtin_amdgcn_mfma_f32_16x16x32_bf16(
                        af[i], bfr[j], accq[i][j], 0, 0, 0);
        }
        // per-row max
#pragma unroll
        for (int i = 0; i < 4; i++)
#pragma unroll
            for (int r = 0; r < 4; r++) {
                const int row = wmF + i * 16 + q * 4 + r;
                float mx = -3.0e38f;
#pragma unroll
                for (int j = 0; j < 8; j++) mx = fmaxf(mx, accq[i][j][r]);
                mx = fmaxf(mx, __shfl_xor(mx, 1)); mx = fmaxf(mx, __shfl_xor(mx, 2));
                mx = fmaxf(mx, __shfl_xor(mx, 4)); mx = fmaxf(mx, __shfl_xor(mx, 8));
                if (cl == 0) mx2[wid & 1][row] = mx;
            }
        __syncthreads();
        // exp + write to QF slices (frag8 layout per 64-f slice)
#pragma unroll
        for (int i = 0; i < 4; i++)
#pragma unroll
            for (int r = 0; r < 4; r++) {
                const int row = wmF + i * 16 + q * 4 + r;
                const float cc = diag_l[row] + fmaxf(mx2[0][row], mx2[1][row]);
#pragma unroll
                for (int j = 0; j < 8; j++) {
                    const int col = wnF + j * 16 + cl;
                    const float v = 0.0625f * (__expf(accq[i][j][r] - cc) + 1.0e-4f);
                    const int s = col >> 6, fp = col & 63;
                    QF[s * 8192 + (row * 8 + ((fp >> 3) ^ (row & 7))) * 8 + (fp & 7)] = f2bf(v);
                }
            }
    }
    __syncthreads();   // QF complete (and Sld/As frag reads done)

    // ---- stage 1: S = Q @ Kf^T (K=256); Q from QF, Kf streamed ----
    floatx4 acc1[4][4];
#pragma unroll
    for (int i = 0; i < 4; i++)
#pragma unroll
        for (int j = 0; j < 4; j++) acc1[i][j] = zero;
    const int wm = (wid >> 1) * 64, wn = (wid & 1) * 64;
    for (int k0 = 0; k0 < FF; k0 += 64) {
#pragma unroll
        for (int t = 0; t < 4; t++) {
            const int g = t * 256 + tid, r = g >> 3, kb = (g & 7) ^ (r & 7);
            gload16(Kf + (size_t)r * FF + k0 + kb * 8, Bs + (size_t)g * 8);
        }
        __syncthreads();
        const ushort_t* QFs = QF + (k0 >> 6) * 8192;
#pragma unroll
        for (int ks = 0; ks < 2; ks++) {
            bf16x8 af[4], bfr[4];
#pragma unroll
            for (int i = 0; i < 4; i++) {
                af[i]  = frag8(QFs, wm + i * 16 + cl, ks * 4 + q);
                bfr[i] = frag8(Bs, wn + i * 16 + cl, ks * 4 + q);
            }
#pragma unroll
            for (int i = 0; i < 4; i++)
#pragma unroll
                for (int j = 0; j < 4; j++)
                    acc1[i][j] = __builtin_amdgcn_mfma_f32_16x16x32_bf16(
                        af[i], bfr[j], acc1[i][j], 0, 0, 0);
        }
        __syncthreads();
    }
    // ---- causal mask + rowsum(fp32) + S -> Sld (bf16, swizzled granules) ----
#pragma unroll
    for (int i = 0; i < 4; i++)
#pragma unroll
        for (int r = 0; r < 4; r++) {
            const int row = wm + i * 16 + q * 4 + r;
            float part = 0.f;
#pragma unroll
            for (int j = 0; j < 4; j++) {
                const int col = wn + j * 16 + cl;
                const float v = (col <= row) ? acc1[i][j][r] : 0.f;
                part += v;
                Sld[(row * 16 + ((col >> 3) ^ (row & 15))) * 8 + (col & 7)] = f2bf(v);
            }
            part += __shfl_xor(part, 1); part += __shfl_xor(part, 2);
            part += __shfl_xor(part, 4); part += __shfl_xor(part, 8);
            if (cl == 0) rows_part[wid & 1][row] = part;
        }
    __syncthreads();

    // ---- stage 3: acc2[e][row] += vT (x) S  (K = 128 seq) ----
    floatx4 acc2[4][2];
#pragma unroll
    for (int i = 0; i < 4; i++)
#pragma unroll
        for (int j = 0; j < 2; j++) acc2[i][j] = zero;
    const ushort_t* Vt = vTb + ((size_t)bh * 64) * NSEQ + n0;
    for (int k0 = 0; k0 < CHK; k0 += 64) {
#pragma unroll
        for (int t = 0; t < 2; t++) {
            const int g = t * 256 + tid, r = g >> 3, kb = (g & 7) ^ (r & 7);
            gload16(Vt + (size_t)r * NSEQ + k0 + kb * 8, As + (size_t)g * 8);
        }
        __syncthreads();
#pragma unroll
        for (int ks = 0; ks < 2; ks++) {
            bf16x8 af[4], bfr[2];
            const int kbS = (k0 >> 3) + ks * 4 + q;
#pragma unroll
            for (int i = 0; i < 4; i++) af[i] = frag8(As, i * 16 + cl, ks * 4 + q);
#pragma unroll
            for (int j = 0; j < 2; j++) bfr[j] = fragS(Sld, wid * 32 + j * 16 + cl, kbS);
#pragma unroll
            for (int i = 0; i < 4; i++)
#pragma unroll
                for (int j = 0; j < 2; j++)
                    acc2[i][j] = __builtin_amdgcn_mfma_f32_16x16x32_bf16(
                        af[i], bfr[j], acc2[i][j], 0, 0, 0);
        }
        __syncthreads();
    }

    // ---- stage 4: acc2 += ctxp (x) Q  (K = 256 features); Q/den from QF ----
    const ushort_t* Cp = ctxp + ((size_t)bh * NCHK + c) * 64 * FF;
    float dacc = 0.f;
    const int drow = tid & 127, dhalf = tid >> 7;
    for (int k0 = 0; k0 < FF; k0 += 64) {
#pragma unroll
        for (int t = 0; t < 2; t++) {
            const int g = t * 256 + tid, r = g >> 3, kb = (g & 7) ^ (r & 7);
            gload16(Cp + (size_t)r * FF + k0 + kb * 8, As + (size_t)g * 8);
        }
        __syncthreads();
        const ushort_t* QFs = QF + (k0 >> 6) * 8192;
#pragma unroll
        for (int ks = 0; ks < 2; ks++) {
            bf16x8 af[4], bfr[2];
#pragma unroll
            for (int i = 0; i < 4; i++) af[i] = frag8(As, i * 16 + cl, ks * 4 + q);
#pragma unroll
            for (int j = 0; j < 2; j++) bfr[j] = frag8(QFs, wid * 32 + j * 16 + cl, ks * 4 + q);
#pragma unroll
            for (int i = 0; i < 4; i++)
#pragma unroll
                for (int j = 0; j < 2; j++)
                    acc2[i][j] = __builtin_amdgcn_mfma_f32_16x16x32_bf16(
                        af[i], bfr[j], acc2[i][j], 0, 0, 0);
        }
        // den partial: this thread's row, its 32-feature half of this k-step
#pragma unroll
        for (int gi = 0; gi < 4; gi++) {
            const int kb = dhalf * 4 + gi;
            const ushort_t* gp = QFs + ((size_t)drow * 8 + (kb ^ (drow & 7))) * 8;
            const int kbase = k0 + kb * 8;
#pragma unroll
            for (int e2 = 0; e2 < 8; e2++)
                dacc = fmaf(bf2f(gp[e2]), zeps[kbase + e2], dacc);
        }
        __syncthreads();
    }
    denp[tid] = dacc;
    __syncthreads();
    if (tid < 128)
        den_l[tid] = rows_part[0][tid] + rows_part[1][tid] + denp[tid] + denp[tid + 128];
    __syncthreads();

    // ---- epilogue: divide, transpose via LDS, coalesced bf16 store ----
#pragma unroll
    for (int j = 0; j < 2; j++) {
        const int row = wid * 32 + j * 16 + cl;
        const float dinv = 1.0f / den_l[row];
#pragma unroll
        for (int i = 0; i < 4; i++)
#pragma unroll
            for (int r = 0; r < 4; r++) {
                const int e = i * 16 + q * 4 + r;
                Sld[row * 68 + e] = f2bf(acc2[i][j][r] * dinv);
            }
    }
    __syncthreads();
#pragma unroll
    for (int p = 0; p < 8; p++) {
        const int idx = p * 256 + tid;
        const int row = idx >> 4, e4 = idx & 15;
        ushort4 o = *(const ushort4*)&Sld[row * 68 + e4 * 4];
        *(ushort4*)(attnb + ((size_t)(bb * NSEQ + n0 + row)) * DIMM + h * 64 + e4 * 4) = o;
    }
}

extern "C" void kernel_launch(void* const* d_in, const int* in_sizes, int n_in,
                              void* d_out, int out_size, void* d_ws, size_t ws_size,
                              hipStream_t stream)
{
    (void)in_sizes; (void)n_in; (void)out_size; (void)ws_size;
    const float* x    = (const float*)d_in[0];
    const float* proj = (const float*)d_in[1];
    const float* Wq   = (const float*)d_in[2];
    const float* Wk   = (const float*)d_in[3];
    const float* Wv   = (const float*)d_in[4];
    const float* Wo   = (const float*)d_in[5];
    const float* bo   = (const float*)d_in[6];
    float* out = (float*)d_out;

    // ---- workspace carve (~61 MB) ----
    char* W = (char*)d_ws;
    float*    CTXT = (float*)W;              W += (size_t)16777216;   // [bh][c][e][f] fp32
    ushort_t* kfb  = (ushort_t*)W;           W += (size_t)16777216;   // [bh][n][f] bf16
    ushort_t* ctxp = (ushort_t*)W;           W += (size_t)8388608;    // [bh][c][e][f] bf16
    ushort_t* qb   = (ushort_t*)W;           W += (size_t)4194304;    // [n][dim] bf16 (live into chunk_out)
    ushort_t* kb   = (ushort_t*)W;           W += (size_t)4194304;
    ushort_t* xb   = (ushort_t*)W;           W += (size_t)4194304;    // reused as attnb
    ushort_t* vTb  = (ushort_t*)W;           W += (size_t)4194304;    // [bh][e][n]
    ushort_t* Wtq  = (ushort_t*)W;           W += (size_t)524288;
    ushort_t* Wtk  = (ushort_t*)W;           W += (size_t)524288;
    ushort_t* Wtv  = (ushort_t*)W;           W += (size_t)524288;
    ushort_t* Wto  = (ushort_t*)W;           W += (size_t)524288;
    ushort_t* projb = (ushort_t*)W;          W += (size_t)32768;
    float*    Ksum = (float*)W;              W += (size_t)262144;     // [bh][c][f]
    unsigned* mk_u = (unsigned*)W;           W += (size_t)256;

    ushort_t* attnb = xb;          // xb dead after gemm_qkv

    float* Zout = out + (size_t)4096 * 512;
    float* Sout = Zout + (size_t)NBH * FF;

    hipLaunchKernelGGL(prep, dim3(3089), dim3(256), 0, stream,
                       x, proj, Wq, Wk, Wv, Wo, xb, projb, Wtq, Wtk, Wtv, Wto, mk_u);
    hipLaunchKernelGGL(gemm_qkv, dim3(4, 32, 3), dim3(256), 0, stream,
                       xb, Wtq, Wtk, Wtv, projb, qb, kb, vTb, mk_u);
    hipLaunchKernelGGL(featk, dim3(32, 8), dim3(256), 0, stream,
                       kb, projb, mk_u, vTb, kfb, CTXT, Ksum);
    hipLaunchKernelGGL(prefix_zs, dim3(1040), dim3(256), 0, stream,
                       Ksum, Zout, CTXT, ctxp, Sout);
    hipLaunchKernelGGL(chunk_out_mfma, dim3(256), dim3(256), 0, stream,
                       qb, projb, kfb, vTb, Ksum, ctxp, attnb);
    hipLaunchKernelGGL(gemm_out, dim3(4, 32), dim3(256), 0, stream, attnb, Wto, out, bo);
}